// Round 1
// baseline (1762.870 us; speedup 1.0000x reference)
//
#include <hip/hip_runtime.h>
#include <math.h>

#define NEG_SLOPE 0.2f

// ---------------- CSR build ----------------
__global__ __launch_bounds__(256) void k_deg_init(int* deg, int N){
  int i = blockIdx.x*256 + threadIdx.x;
  if (i < N) deg[i] = 1;               // self-loop
}
__global__ __launch_bounds__(256) void k_deg_count(const int* __restrict__ dst, int E, int* __restrict__ deg){
  int i = blockIdx.x*256 + threadIdx.x;
  if (i < E) atomicAdd(&deg[dst[i]], 1);
}
__global__ __launch_bounds__(1024) void k_scan(const int* __restrict__ deg, int* __restrict__ rowptr, int N){
  __shared__ int buf[1024];
  __shared__ int carry_s;
  int tid = threadIdx.x;
  if (tid == 0) carry_s = 0;
  __syncthreads();
  for (int base = 0; base < N; base += 1024){
    int v = (base+tid < N) ? deg[base+tid] : 0;
    int val = v;
    buf[tid] = v;
    __syncthreads();
    for (int off = 1; off < 1024; off <<= 1){
      int add = (tid >= off) ? buf[tid-off] : 0;
      __syncthreads();
      val += add;
      buf[tid] = val;
      __syncthreads();
    }
    int carry = carry_s;
    if (base+tid < N) rowptr[base+tid] = carry + val - v;  // exclusive
    __syncthreads();
    if (tid == 1023) carry_s = carry + val;
    __syncthreads();
  }
  if (tid == 0) rowptr[N] = carry_s;
}
__global__ __launch_bounds__(256) void k_pos_copy(const int* __restrict__ rowptr, int* __restrict__ pos, int N){
  int i = blockIdx.x*256 + threadIdx.x;
  if (i < N) pos[i] = rowptr[i];
}
__global__ __launch_bounds__(256) void k_fill_self(int* __restrict__ pos, int* __restrict__ colidx, int N){
  int i = blockIdx.x*256 + threadIdx.x;
  if (i < N) colidx[atomicAdd(&pos[i],1)] = i;
}
__global__ __launch_bounds__(256) void k_fill_edges(const int* __restrict__ src, const int* __restrict__ dst,
                                                    int E, int* __restrict__ pos, int* __restrict__ colidx){
  int i = blockIdx.x*256 + threadIdx.x;
  if (i < E){
    int d = dst[i];
    colidx[atomicAdd(&pos[d],1)] = src[i];
  }
}

// ---------------- GEMM (fp32 VALU): C[MxP] = A[MxK]@B[KxP] (+bias) ----------------
template<int K, int P, bool BIAS>
__global__ __launch_bounds__(256) void k_gemm(const float* __restrict__ A, int strideA,
                                              const float* __restrict__ B,
                                              const float* __restrict__ bias,
                                              float* __restrict__ C, int M){
  constexpr int CPT = P / 64;   // columns per thread
  __shared__ float As[32][K];
  int m0 = blockIdx.x * 32;
  int tid = threadIdx.x;
  for (int idx = tid; idx < 32*K; idx += 256){
    int r = idx / K, c = idx % K;
    int row = m0 + r;
    As[r][c] = (row < M) ? A[(size_t)row*strideA + c] : 0.f;
  }
  __syncthreads();
  int j0 = tid & 63;
  int rg = tid >> 6;            // 4 row-groups x 8 rows
  float acc[8][CPT];
  #pragma unroll
  for (int r=0;r<8;r++)
    #pragma unroll
    for (int c=0;c<CPT;c++) acc[r][c] = 0.f;
  for (int k=0;k<K;++k){
    float b[CPT];
    #pragma unroll
    for (int c=0;c<CPT;c++) b[c] = B[k*P + j0 + 64*c];
    #pragma unroll
    for (int r=0;r<8;r++){
      float a = As[rg*8+r][k];
      #pragma unroll
      for (int c=0;c<CPT;c++) acc[r][c] += a*b[c];
    }
  }
  #pragma unroll
  for (int r=0;r<8;r++){
    int row = m0 + rg*8 + r;
    if (row < M){
      #pragma unroll
      for (int c=0;c<CPT;c++){
        int col = j0 + 64*c;
        float v = acc[r][c];
        if (BIAS) v += bias[col];
        C[(size_t)row*P + col] = v;
      }
    }
  }
}

// ---------------- per-node attention logits ----------------
__global__ __launch_bounds__(256) void k_esd(const float* __restrict__ hp,
                                             const float* __restrict__ a_s, const float* __restrict__ a_d,
                                             float* __restrict__ e_s, float* __restrict__ e_d, int N){
  int n = blockIdx.x*4 + (threadIdx.x >> 6);
  int lane = threadIdx.x & 63;
  if (n >= N) return;
  const float* row = hp + (size_t)n*256;
  #pragma unroll
  for (int h=0; h<4; ++h){
    float v = row[h*64 + lane];
    float ps = v * a_s[h*64 + lane];
    float pd = v * a_d[h*64 + lane];
    #pragma unroll
    for (int off=32; off>0; off>>=1){
      ps += __shfl_xor(ps, off);
      pd += __shfl_xor(pd, off);
    }
    if (lane == 0){ e_s[n*4+h] = ps; e_d[n*4+h] = pd; }
  }
}

// ---------------- GAT aggregation: out = elu(softmax-agg + bias) ----------------
__global__ __launch_bounds__(256) void k_agg(const float* __restrict__ hp,
                                             const float* __restrict__ e_s, const float* __restrict__ e_d,
                                             const int* __restrict__ rowptr, const int* __restrict__ colidx,
                                             const float* __restrict__ bias, float* __restrict__ out, int N){
  int n = blockIdx.x;
  int h = threadIdx.x >> 6, lane = threadIdx.x & 63;
  int s0 = rowptr[n], s1 = rowptr[n+1];
  float ed = e_d[n*4 + h];
  float z = 0.f;
  for (int i = s0 + lane; i < s1; i += 64){
    int s = colidx[i];
    float e = e_s[s*4 + h] + ed;
    e = (e > 0.f) ? e : NEG_SLOPE*e;
    z += expf(e);
  }
  #pragma unroll
  for (int off=32; off>0; off>>=1) z += __shfl_xor(z, off);
  float inv = 1.f / (z + 1e-16f);
  float acc = 0.f;
  for (int i = s0; i < s1; ++i){
    int s = colidx[i];
    float e = e_s[s*4 + h] + ed;
    e = (e > 0.f) ? e : NEG_SLOPE*e;
    float alpha = expf(e) * inv;
    acc += alpha * hp[(size_t)s*256 + h*64 + lane];
  }
  float v = acc + bias[h*64 + lane];
  v = (v > 0.f) ? v : (expf(v) - 1.f);   // ELU
  out[(size_t)n*256 + h*64 + lane] = v;
}

// ---------------- column sums (for mean over nodes) ----------------
__global__ __launch_bounds__(256) void k_colsum(const float* __restrict__ emb, float* __restrict__ sums, int N){
  int j = threadIdx.x;
  int nb = gridDim.x;
  int rows_per = (N + nb - 1) / nb;
  int r0 = blockIdx.x * rows_per;
  int r1 = min(N, r0 + rows_per);
  float s = 0.f;
  for (int r = r0; r < r1; ++r) s += emb[(size_t)r*256 + j];
  atomicAdd(&sums[j], s);
}

// ---------------- temporal attention weights (tiny) ----------------
__global__ __launch_bounds__(256) void k_attn(const float* __restrict__ sum_emb,
                                              const float* __restrict__ Wq, const float* __restrict__ bq,
                                              const float* __restrict__ Wk, const float* __restrict__ bk,
                                              float* __restrict__ aw, int N){
  __shared__ float mean_s[4][256];
  __shared__ float red[256];
  __shared__ float scores_s[4];
  int j = threadIdx.x;
  float invN = 1.0f/(float)N;
  #pragma unroll
  for (int t=0;t<4;t++) mean_s[t][j] = sum_emb[t*256+j]*invN;
  __syncthreads();
  float q3 = bq[j];
  float kt0=bk[j], kt1=bk[j], kt2=bk[j], kt3=bk[j];
  for (int m=0;m<256;m++){
    float wq = Wq[m*256+j];
    float wk = Wk[m*256+j];
    float m0 = mean_s[0][m], m1 = mean_s[1][m], m2 = mean_s[2][m], m3 = mean_s[3][m];
    q3  += m3*wq;
    kt0 += m0*wk; kt1 += m1*wk; kt2 += m2*wk; kt3 += m3*wk;
  }
  float kts0=kt0, kts1=kt1, kts2=kt2, kts3=kt3;
  #pragma unroll
  for (int t=0;t<4;t++){
    float ktv = (t==0)?kts0:((t==1)?kts1:((t==2)?kts2:kts3));
    red[j] = q3*ktv;
    __syncthreads();
    for (int off=128; off>0; off>>=1){
      if (j < off) red[j] += red[j+off];
      __syncthreads();
    }
    if (j==0) scores_s[t] = red[0]*(1.0f/16.0f);   // /sqrt(256)
    __syncthreads();
  }
  if (j==0){
    float mx = fmaxf(fmaxf(scores_s[0],scores_s[1]),fmaxf(scores_s[2],scores_s[3]));
    float w0 = expf(scores_s[0]-mx), w1 = expf(scores_s[1]-mx),
          w2 = expf(scores_s[2]-mx), w3 = expf(scores_s[3]-mx);
    float s = w0+w1+w2+w3;
    aw[0]=w0/s; aw[1]=w1/s; aw[2]=w2/s; aw[3]=w3/s;
  }
}

// ---------------- final: out = (sum_t aw[t]*embs[t]) @ Wv + bv ----------------
__global__ __launch_bounds__(256) void k_final(const float* __restrict__ embs, const float* __restrict__ awp,
                                               const float* __restrict__ B, const float* __restrict__ bias,
                                               float* __restrict__ C, int M){
  __shared__ float As[32][256];
  float a0=awp[0], a1=awp[1], a2=awp[2], a3=awp[3];
  size_t sl = (size_t)M*256;
  int m0 = blockIdx.x*32;
  int tid = threadIdx.x;
  for (int idx = tid; idx < 32*256; idx += 256){
    int r = idx >> 8, c = idx & 255;
    int row = m0 + r;
    float v = 0.f;
    if (row < M){
      size_t o = (size_t)row*256 + c;
      v = a0*embs[o] + a1*embs[o+sl] + a2*embs[o+2*sl] + a3*embs[o+3*sl];
    }
    As[r][c] = v;
  }
  __syncthreads();
  int j0 = tid & 63, rg = tid >> 6;
  float acc[8][4];
  #pragma unroll
  for (int r=0;r<8;r++)
    #pragma unroll
    for (int c=0;c<4;c++) acc[r][c] = 0.f;
  for (int k=0;k<256;++k){
    float b[4];
    #pragma unroll
    for (int c=0;c<4;c++) b[c] = B[k*256 + j0 + 64*c];
    #pragma unroll
    for (int r=0;r<8;r++){
      float a = As[rg*8+r][k];
      #pragma unroll
      for (int c=0;c<4;c++) acc[r][c] += a*b[c];
    }
  }
  #pragma unroll
  for (int r=0;r<8;r++){
    int row = m0 + rg*8 + r;
    if (row < M){
      #pragma unroll
      for (int c=0;c<4;c++){
        int col = j0 + 64*c;
        C[(size_t)row*256 + col] = acc[r][c] + bias[col];
      }
    }
  }
}

extern "C" void kernel_launch(void* const* d_in, const int* in_sizes, int n_in,
                              void* d_out, int out_size, void* d_ws, size_t ws_size,
                              hipStream_t stream){
  (void)n_in; (void)out_size; (void)ws_size;
  const float* x   = (const float*)d_in[0];
  const int*   ei  = (const int*)d_in[1];
  const float* Wp  = (const float*)d_in[2];
  const float* bp  = (const float*)d_in[3];
  const float* W0  = (const float*)d_in[4];
  const float* as0 = (const float*)d_in[5];
  const float* ad0 = (const float*)d_in[6];
  const float* b0  = (const float*)d_in[7];
  const float* W1  = (const float*)d_in[8];
  const float* as1 = (const float*)d_in[9];
  const float* ad1 = (const float*)d_in[10];
  const float* b1  = (const float*)d_in[11];
  const float* Wq  = (const float*)d_in[12];
  const float* bq  = (const float*)d_in[13];
  const float* Wk  = (const float*)d_in[14];
  const float* bk  = (const float*)d_in[15];
  const float* Wv  = (const float*)d_in[16];
  const float* bv  = (const float*)d_in[17];
  float* out = (float*)d_out;

  const int T = 4, FIN = 256;
  const int N = in_sizes[0] / (T*FIN);
  const int E = in_sizes[1] / 2;
  const int* src = ei;
  const int* dst = ei + E;

  char* ws = (char*)d_ws;
  size_t cur = 0;
  auto alloc = [&](size_t bytes)->void*{
    void* p = ws + cur;
    cur += (bytes + 255) & ~(size_t)255;
    return p;
  };
  float* h0     = (float*)alloc((size_t)N*64*4);
  float* hp     = (float*)alloc((size_t)N*256*4);
  float* h1     = (float*)alloc((size_t)N*256*4);
  float* e_s    = (float*)alloc((size_t)N*4*4);
  float* e_d    = (float*)alloc((size_t)N*4*4);
  float* embs   = (float*)alloc((size_t)T*N*256*4);
  float* sume   = (float*)alloc(4*256*4);
  float* aw     = (float*)alloc(256);
  int*   rowptr = (int*)alloc((size_t)(N+1)*4);
  int*   deg    = (int*)alloc((size_t)N*4);
  int*   pos    = (int*)alloc((size_t)N*4);
  int*   colidx = (int*)alloc((size_t)(E+N)*4);

  int nb256 = (N+255)/256;
  int nbE   = (E+255)/256;
  int gblk  = (N+31)/32;

  // CSR build (graph is static across t and layers -> build once)
  k_deg_init<<<nb256,256,0,stream>>>(deg, N);
  k_deg_count<<<nbE,256,0,stream>>>(dst, E, deg);
  k_scan<<<1,1024,0,stream>>>(deg, rowptr, N);
  k_pos_copy<<<nb256,256,0,stream>>>(rowptr, pos, N);
  k_fill_self<<<nb256,256,0,stream>>>(pos, colidx, N);
  k_fill_edges<<<nbE,256,0,stream>>>(src, dst, E, pos, colidx);
  hipMemsetAsync(sume, 0, 4*256*4, stream);

  for (int t=0;t<T;t++){
    // h0 = x[:,t,:] @ Wp + bp      (N,256)@(256,64)
    k_gemm<256,64,true><<<gblk,256,0,stream>>>(x + t*FIN, T*FIN, Wp, bp, h0, N);
    // GAT layer 0
    k_gemm<64,256,false><<<gblk,256,0,stream>>>(h0, 64, W0, nullptr, hp, N);
    k_esd<<<(N+3)/4,256,0,stream>>>(hp, as0, ad0, e_s, e_d, N);
    k_agg<<<N,256,0,stream>>>(hp, e_s, e_d, rowptr, colidx, b0, h1, N);
    // GAT layer 1
    k_gemm<256,256,false><<<gblk,256,0,stream>>>(h1, 256, W1, nullptr, hp, N);
    k_esd<<<(N+3)/4,256,0,stream>>>(hp, as1, ad1, e_s, e_d, N);
    k_agg<<<N,256,0,stream>>>(hp, e_s, e_d, rowptr, colidx, b1, embs + (size_t)t*N*256, N);
    // accumulate node-mean numerator for temporal attention
    k_colsum<<<128,256,0,stream>>>(embs + (size_t)t*N*256, sume + t*256, N);
  }
  // temporal attention weights for the last row (T-1), then fused V-projection
  k_attn<<<1,256,0,stream>>>(sume, Wq, bq, Wk, bk, aw, N);
  k_final<<<gblk,256,0,stream>>>(embs, aw, Wv, bv, out, N);
}

// Round 2
// 1359.815 us; speedup vs baseline: 1.2964x; 1.2964x over previous
//
#include <hip/hip_runtime.h>
#include <math.h>

#define NEG_SLOPE 0.2f

typedef __attribute__((ext_vector_type(8))) short short8;
typedef __attribute__((ext_vector_type(4))) float f32x4;

__device__ inline unsigned short f2bf(float f){
  union { float f; unsigned u; } v; v.f = f;
  unsigned r = v.u + 0x7fffu + ((v.u >> 16) & 1u);
  return (unsigned short)(r >> 16);
}

// ---------------- CSR build ----------------
__global__ __launch_bounds__(256) void k_deg_init(int* deg, int N){
  int i = blockIdx.x*256 + threadIdx.x;
  if (i < N) deg[i] = 1;               // self-loop
}
__global__ __launch_bounds__(256) void k_deg_count(const int* __restrict__ dst, int E, int* __restrict__ deg){
  int i = blockIdx.x*256 + threadIdx.x;
  if (i < E) atomicAdd(&deg[dst[i]], 1);
}
__global__ __launch_bounds__(1024) void k_scan(const int* __restrict__ deg, int* __restrict__ rowptr, int N){
  __shared__ int buf[1024];
  __shared__ int carry_s;
  int tid = threadIdx.x;
  if (tid == 0) carry_s = 0;
  __syncthreads();
  for (int base = 0; base < N; base += 1024){
    int v = (base+tid < N) ? deg[base+tid] : 0;
    int val = v;
    buf[tid] = v;
    __syncthreads();
    for (int off = 1; off < 1024; off <<= 1){
      int add = (tid >= off) ? buf[tid-off] : 0;
      __syncthreads();
      val += add;
      buf[tid] = val;
      __syncthreads();
    }
    int carry = carry_s;
    if (base+tid < N) rowptr[base+tid] = carry + val - v;  // exclusive
    __syncthreads();
    if (tid == 1023) carry_s = carry + val;
    __syncthreads();
  }
  if (tid == 0) rowptr[N] = carry_s;
}
__global__ __launch_bounds__(256) void k_pos_copy(const int* __restrict__ rowptr, int* __restrict__ pos, int N){
  int i = blockIdx.x*256 + threadIdx.x;
  if (i < N) pos[i] = rowptr[i];
}
__global__ __launch_bounds__(256) void k_fill_self(int* __restrict__ pos, int* __restrict__ colidx, int N){
  int i = blockIdx.x*256 + threadIdx.x;
  if (i < N) colidx[atomicAdd(&pos[i],1)] = i;
}
__global__ __launch_bounds__(256) void k_fill_edges(const int* __restrict__ src, const int* __restrict__ dst,
                                                    int E, int* __restrict__ pos, int* __restrict__ colidx){
  int i = blockIdx.x*256 + threadIdx.x;
  if (i < E){
    int d = dst[i];
    colidx[atomicAdd(&pos[d],1)] = src[i];
  }
}

// ---------------- weight transpose+convert: W[K][P] f32 -> Wt[P][K] bf16 ----------------
__global__ __launch_bounds__(256) void k_w2bt(const float* __restrict__ W, unsigned short* __restrict__ Wt,
                                              int K, int P){
  int idx = blockIdx.x*256 + threadIdx.x;
  if (idx < K*P){
    int k = idx / P, p = idx % P;
    Wt[(size_t)p*K + k] = f2bf(W[idx]);
  }
}

// ---------------- MFMA bf16 GEMM: C[M x P] = A[M x K] @ B + bias ----------------
// Bt is B transposed, bf16 [P][K]. A fp32, converted to bf16 during staging.
// BM=128, BN=64, BK=64. 256 threads = 4 waves (2x2), wave tile 64x32.
template<int K, bool BIAS>
__global__ __launch_bounds__(256) void k_gemm_mfma(const float* __restrict__ A, int strideA,
                                                   const unsigned short* __restrict__ Bt,
                                                   const float* __restrict__ bias,
                                                   float* __restrict__ C, int M, int P){
  constexpr int BK = 64, PAD = 8;
  __shared__ unsigned short Als[128][BK+PAD];
  __shared__ unsigned short Bls[64][BK+PAD];
  int tid = threadIdx.x;
  int m0  = blockIdx.x * 128;
  int bn0 = blockIdx.y * 64;
  int wave = tid >> 6, lane = tid & 63;
  int wr = wave >> 1, wc = wave & 1;
  int lr = lane & 15, lk = (lane >> 4) * 8;
  f32x4 acc[4][2];
  #pragma unroll
  for (int m=0;m<4;m++)
    #pragma unroll
    for (int n=0;n<2;n++)
      #pragma unroll
      for (int j=0;j<4;j++) acc[m][n][j] = 0.f;

  for (int k0 = 0; k0 < K; k0 += BK){
    // stage A: 128 x 64 fp32 -> bf16, 8 float4 per thread
    #pragma unroll
    for (int i=0;i<8;i++){
      int idx = tid + i*256;
      int r = idx >> 4, c4 = (idx & 15)*4;
      int row = m0 + r;
      float4 v = make_float4(0.f,0.f,0.f,0.f);
      if (row < M) v = *(const float4*)(A + (size_t)row*strideA + k0 + c4);
      unsigned short* dp = &Als[r][c4];
      dp[0]=f2bf(v.x); dp[1]=f2bf(v.y); dp[2]=f2bf(v.z); dp[3]=f2bf(v.w);
    }
    // stage B: 64 x 64 bf16, 2 x 16B per thread
    #pragma unroll
    for (int i=0;i<2;i++){
      int idx = tid + i*256;
      int r = idx >> 3, ch = (idx & 7)*8;
      *(uint4*)(&Bls[r][ch]) = *(const uint4*)(Bt + (size_t)(bn0 + r)*K + k0 + ch);
    }
    __syncthreads();
    #pragma unroll
    for (int ks=0; ks<2; ks++){
      short8 afr[4], bfr[2];
      #pragma unroll
      for (int m=0;m<4;m++)
        afr[m] = *(const short8*)(&Als[wr*64 + m*16 + lr][ks*32 + lk]);
      #pragma unroll
      for (int n=0;n<2;n++)
        bfr[n] = *(const short8*)(&Bls[wc*32 + n*16 + lr][ks*32 + lk]);
      #pragma unroll
      for (int m=0;m<4;m++)
        #pragma unroll
        for (int n=0;n<2;n++)
          acc[m][n] = __builtin_amdgcn_mfma_f32_16x16x32_bf16(afr[m], bfr[n], acc[m][n], 0,0,0);
    }
    __syncthreads();
  }
  #pragma unroll
  for (int m=0;m<4;m++){
    #pragma unroll
    for (int n=0;n<2;n++){
      int col = bn0 + wc*32 + n*16 + lr;
      #pragma unroll
      for (int j=0;j<4;j++){
        int row = m0 + wr*64 + m*16 + (lane>>4)*4 + j;
        if (row < M){
          float v = acc[m][n][j];
          if (BIAS) v += bias[col];
          C[(size_t)row*P + col] = v;
        }
      }
    }
  }
}

// ---------------- final GEMM with fused temporal combine: C = (sum_t aw[t]*embs[t]) @ Wv + bv ----------------
__global__ __launch_bounds__(256) void k_final_mfma(const float* __restrict__ embs, const float* __restrict__ awp,
                                                    const unsigned short* __restrict__ Bt,
                                                    const float* __restrict__ bias,
                                                    float* __restrict__ C, int M){
  constexpr int K = 256, BK = 64, PAD = 8;
  __shared__ unsigned short Als[128][BK+PAD];
  __shared__ unsigned short Bls[64][BK+PAD];
  int tid = threadIdx.x;
  int m0  = blockIdx.x * 128;
  int bn0 = blockIdx.y * 64;
  int wave = tid >> 6, lane = tid & 63;
  int wr = wave >> 1, wc = wave & 1;
  int lr = lane & 15, lk = (lane >> 4) * 8;
  float a0=awp[0], a1=awp[1], a2=awp[2], a3=awp[3];
  size_t sl = (size_t)M*256;
  f32x4 acc[4][2];
  #pragma unroll
  for (int m=0;m<4;m++)
    #pragma unroll
    for (int n=0;n<2;n++)
      #pragma unroll
      for (int j=0;j<4;j++) acc[m][n][j] = 0.f;

  for (int k0 = 0; k0 < K; k0 += BK){
    #pragma unroll
    for (int i=0;i<8;i++){
      int idx = tid + i*256;
      int r = idx >> 4, c4 = (idx & 15)*4;
      int row = m0 + r;
      float4 v = make_float4(0.f,0.f,0.f,0.f);
      if (row < M){
        size_t o = (size_t)row*256 + k0 + c4;
        float4 v0 = *(const float4*)(embs + o);
        float4 v1 = *(const float4*)(embs + o + sl);
        float4 v2 = *(const float4*)(embs + o + 2*sl);
        float4 v3 = *(const float4*)(embs + o + 3*sl);
        v.x = a0*v0.x + a1*v1.x + a2*v2.x + a3*v3.x;
        v.y = a0*v0.y + a1*v1.y + a2*v2.y + a3*v3.y;
        v.z = a0*v0.z + a1*v1.z + a2*v2.z + a3*v3.z;
        v.w = a0*v0.w + a1*v1.w + a2*v2.w + a3*v3.w;
      }
      unsigned short* dp = &Als[r][c4];
      dp[0]=f2bf(v.x); dp[1]=f2bf(v.y); dp[2]=f2bf(v.z); dp[3]=f2bf(v.w);
    }
    #pragma unroll
    for (int i=0;i<2;i++){
      int idx = tid + i*256;
      int r = idx >> 3, ch = (idx & 7)*8;
      *(uint4*)(&Bls[r][ch]) = *(const uint4*)(Bt + (size_t)(bn0 + r)*K + k0 + ch);
    }
    __syncthreads();
    #pragma unroll
    for (int ks=0; ks<2; ks++){
      short8 afr[4], bfr[2];
      #pragma unroll
      for (int m=0;m<4;m++)
        afr[m] = *(const short8*)(&Als[wr*64 + m*16 + lr][ks*32 + lk]);
      #pragma unroll
      for (int n=0;n<2;n++)
        bfr[n] = *(const short8*)(&Bls[wc*32 + n*16 + lr][ks*32 + lk]);
      #pragma unroll
      for (int m=0;m<4;m++)
        #pragma unroll
        for (int n=0;n<2;n++)
          acc[m][n] = __builtin_amdgcn_mfma_f32_16x16x32_bf16(afr[m], bfr[n], acc[m][n], 0,0,0);
    }
    __syncthreads();
  }
  #pragma unroll
  for (int m=0;m<4;m++){
    #pragma unroll
    for (int n=0;n<2;n++){
      int col = bn0 + wc*32 + n*16 + lr;
      #pragma unroll
      for (int j=0;j<4;j++){
        int row = m0 + wr*64 + m*16 + (lane>>4)*4 + j;
        if (row < M)
          C[(size_t)row*256 + col] = acc[m][n][j] + bias[col];
      }
    }
  }
}

// ---------------- per-node attention logits (float4-wide) ----------------
__global__ __launch_bounds__(256) void k_esd(const float* __restrict__ hp,
                                             const float* __restrict__ a_s, const float* __restrict__ a_d,
                                             float* __restrict__ e_s, float* __restrict__ e_d, int N){
  int n = blockIdx.x*4 + (threadIdx.x >> 6);
  if (n >= N) return;
  int lane = threadIdx.x & 63;
  float4 v  = *(const float4*)(hp + (size_t)n*256 + lane*4);
  float4 as = *(const float4*)(a_s + lane*4);
  float4 ad = *(const float4*)(a_d + lane*4);
  float ps = v.x*as.x + v.y*as.y + v.z*as.z + v.w*as.w;
  float pd = v.x*ad.x + v.y*ad.y + v.z*ad.z + v.w*ad.w;
  #pragma unroll
  for (int off=1; off<16; off<<=1){ ps += __shfl_xor(ps,off); pd += __shfl_xor(pd,off); }
  if ((lane & 15) == 0){
    int h = lane >> 4;
    e_s[n*4+h] = ps; e_d[n*4+h] = pd;
  }
}

// ---------------- GAT aggregation, single pass: out = elu(softmax-agg + bias) ----------------
__global__ __launch_bounds__(256) void k_agg(const float* __restrict__ hp,
                                             const float* __restrict__ e_s, const float* __restrict__ e_d,
                                             const int* __restrict__ rowptr, const int* __restrict__ colidx,
                                             const float* __restrict__ bias, float* __restrict__ out, int N){
  int n = blockIdx.x;
  int h = threadIdx.x >> 6, lane = threadIdx.x & 63;
  int s0 = rowptr[n], s1 = rowptr[n+1];
  float ed = e_d[n*4 + h];
  float z = 0.f, acc = 0.f;
  for (int i = s0; i < s1; ++i){
    int s = colidx[i];
    float e = e_s[s*4 + h] + ed;
    e = (e > 0.f) ? e : NEG_SLOPE*e;
    float w = expf(e);
    z += w;
    acc += w * hp[(size_t)s*256 + h*64 + lane];
  }
  float v = acc / (z + 1e-16f) + bias[h*64 + lane];
  v = (v > 0.f) ? v : (expf(v) - 1.f);   // ELU
  out[(size_t)n*256 + h*64 + lane] = v;
}

// ---------------- column sums (for mean over nodes) ----------------
__global__ __launch_bounds__(256) void k_colsum(const float* __restrict__ emb, float* __restrict__ sums, int N){
  int j = threadIdx.x;
  int nb = gridDim.x;
  int rows_per = (N + nb - 1) / nb;
  int r0 = blockIdx.x * rows_per;
  int r1 = min(N, r0 + rows_per);
  float s = 0.f;
  for (int r = r0; r < r1; ++r) s += emb[(size_t)r*256 + j];
  atomicAdd(&sums[j], s);
}

// ---------------- temporal attention weights (tiny) ----------------
__global__ __launch_bounds__(256) void k_attn(const float* __restrict__ sum_emb,
                                              const float* __restrict__ Wq, const float* __restrict__ bq,
                                              const float* __restrict__ Wk, const float* __restrict__ bk,
                                              float* __restrict__ aw, int N){
  __shared__ float mean_s[4][256];
  __shared__ float red[256];
  __shared__ float scores_s[4];
  int j = threadIdx.x;
  float invN = 1.0f/(float)N;
  #pragma unroll
  for (int t=0;t<4;t++) mean_s[t][j] = sum_emb[t*256+j]*invN;
  __syncthreads();
  float q3 = bq[j];
  float kt0=bk[j], kt1=bk[j], kt2=bk[j], kt3=bk[j];
  for (int m=0;m<256;m++){
    float wq = Wq[m*256+j];
    float wk = Wk[m*256+j];
    float m0 = mean_s[0][m], m1 = mean_s[1][m], m2 = mean_s[2][m], m3 = mean_s[3][m];
    q3  += m3*wq;
    kt0 += m0*wk; kt1 += m1*wk; kt2 += m2*wk; kt3 += m3*wk;
  }
  float kts0=kt0, kts1=kt1, kts2=kt2, kts3=kt3;
  #pragma unroll
  for (int t=0;t<4;t++){
    float ktv = (t==0)?kts0:((t==1)?kts1:((t==2)?kts2:kts3));
    red[j] = q3*ktv;
    __syncthreads();
    for (int off=128; off>0; off>>=1){
      if (j < off) red[j] += red[j+off];
      __syncthreads();
    }
    if (j==0) scores_s[t] = red[0]*(1.0f/16.0f);   // /sqrt(256)
    __syncthreads();
  }
  if (j==0){
    float mx = fmaxf(fmaxf(scores_s[0],scores_s[1]),fmaxf(scores_s[2],scores_s[3]));
    float w0 = expf(scores_s[0]-mx), w1 = expf(scores_s[1]-mx),
          w2 = expf(scores_s[2]-mx), w3 = expf(scores_s[3]-mx);
    float s = w0+w1+w2+w3;
    aw[0]=w0/s; aw[1]=w1/s; aw[2]=w2/s; aw[3]=w3/s;
  }
}

extern "C" void kernel_launch(void* const* d_in, const int* in_sizes, int n_in,
                              void* d_out, int out_size, void* d_ws, size_t ws_size,
                              hipStream_t stream){
  (void)n_in; (void)out_size; (void)ws_size;
  const float* x   = (const float*)d_in[0];
  const int*   ei  = (const int*)d_in[1];
  const float* Wp  = (const float*)d_in[2];
  const float* bp  = (const float*)d_in[3];
  const float* W0  = (const float*)d_in[4];
  const float* as0 = (const float*)d_in[5];
  const float* ad0 = (const float*)d_in[6];
  const float* b0  = (const float*)d_in[7];
  const float* W1  = (const float*)d_in[8];
  const float* as1 = (const float*)d_in[9];
  const float* ad1 = (const float*)d_in[10];
  const float* b1  = (const float*)d_in[11];
  const float* Wq  = (const float*)d_in[12];
  const float* bq  = (const float*)d_in[13];
  const float* Wk  = (const float*)d_in[14];
  const float* bk  = (const float*)d_in[15];
  const float* Wv  = (const float*)d_in[16];
  const float* bv  = (const float*)d_in[17];
  float* out = (float*)d_out;

  const int T = 4, FIN = 256;
  const int N = in_sizes[0] / (T*FIN);
  const int E = in_sizes[1] / 2;
  const int* src = ei;
  const int* dst = ei + E;

  char* ws = (char*)d_ws;
  size_t cur = 0;
  auto alloc = [&](size_t bytes)->void*{
    void* p = ws + cur;
    cur += (bytes + 255) & ~(size_t)255;
    return p;
  };
  float* h0     = (float*)alloc((size_t)N*64*4);
  float* hp     = (float*)alloc((size_t)N*256*4);
  float* h1     = (float*)alloc((size_t)N*256*4);
  float* e_s    = (float*)alloc((size_t)N*4*4);
  float* e_d    = (float*)alloc((size_t)N*4*4);
  float* embs   = (float*)alloc((size_t)T*N*256*4);
  float* sume   = (float*)alloc(4*256*4);
  float* aw     = (float*)alloc(256);
  int*   rowptr = (int*)alloc((size_t)(N+1)*4);
  int*   deg    = (int*)alloc((size_t)N*4);
  int*   pos    = (int*)alloc((size_t)N*4);
  int*   colidx = (int*)alloc((size_t)(E+N)*4);
  unsigned short* WpT = (unsigned short*)alloc((size_t)64*256*2);    // [64][256]
  unsigned short* W0T = (unsigned short*)alloc((size_t)256*64*2);    // [256][64]
  unsigned short* W1T = (unsigned short*)alloc((size_t)256*256*2);   // [256][256]
  unsigned short* WvT = (unsigned short*)alloc((size_t)256*256*2);   // [256][256]

  int nb256 = (N+255)/256;
  int nbE   = (E+255)/256;
  dim3 g1((N+127)/128, 1);    // P=64
  dim3 g4((N+127)/128, 4);    // P=256

  // CSR build (graph is static across t and layers -> build once)
  k_deg_init<<<nb256,256,0,stream>>>(deg, N);
  k_deg_count<<<nbE,256,0,stream>>>(dst, E, deg);
  k_scan<<<1,1024,0,stream>>>(deg, rowptr, N);
  k_pos_copy<<<nb256,256,0,stream>>>(rowptr, pos, N);
  k_fill_self<<<nb256,256,0,stream>>>(pos, colidx, N);
  k_fill_edges<<<nbE,256,0,stream>>>(src, dst, E, pos, colidx);
  hipMemsetAsync(sume, 0, 4*256*4, stream);

  // weight conversions (once)
  k_w2bt<<<(256*64+255)/256,256,0,stream>>>(Wp, WpT, 256, 64);
  k_w2bt<<<(64*256+255)/256,256,0,stream>>>(W0, W0T, 64, 256);
  k_w2bt<<<(256*256+255)/256,256,0,stream>>>(W1, W1T, 256, 256);
  k_w2bt<<<(256*256+255)/256,256,0,stream>>>(Wv, WvT, 256, 256);

  for (int t=0;t<T;t++){
    // h0 = x[:,t,:] @ Wp + bp      (N,256)@(256,64)
    k_gemm_mfma<256,true><<<g1,256,0,stream>>>(x + t*FIN, T*FIN, WpT, bp, h0, N, 64);
    // GAT layer 0
    k_gemm_mfma<64,false><<<g4,256,0,stream>>>(h0, 64, W0T, nullptr, hp, N, 256);
    k_esd<<<(N+3)/4,256,0,stream>>>(hp, as0, ad0, e_s, e_d, N);
    k_agg<<<N,256,0,stream>>>(hp, e_s, e_d, rowptr, colidx, b0, h1, N);
    // GAT layer 1
    k_gemm_mfma<256,false><<<g4,256,0,stream>>>(h1, 256, W1T, nullptr, hp, N, 256);
    k_esd<<<(N+3)/4,256,0,stream>>>(hp, as1, ad1, e_s, e_d, N);
    k_agg<<<N,256,0,stream>>>(hp, e_s, e_d, rowptr, colidx, b1, embs + (size_t)t*N*256, N);
    // accumulate node-mean numerator for temporal attention
    k_colsum<<<128,256,0,stream>>>(embs + (size_t)t*N*256, sume + t*256, N);
  }
  // temporal attention weights for the last row (T-1), then fused V-projection
  k_attn<<<1,256,0,stream>>>(sume, Wq, bq, Wk, bk, aw, N);
  k_final_mfma<<<g4,256,0,stream>>>(embs, aw, WvT, bv, out, N);
}

// Round 3
// 767.067 us; speedup vs baseline: 2.2982x; 1.7727x over previous
//
#include <hip/hip_runtime.h>
#include <math.h>

#define NEG_SLOPE 0.2f

typedef __attribute__((ext_vector_type(8))) short short8;
typedef __attribute__((ext_vector_type(4))) float f32x4;

__device__ inline unsigned short f2bf(float f){
  union { float f; unsigned u; } v; v.f = f;
  unsigned r = v.u + 0x7fffu + ((v.u >> 16) & 1u);
  return (unsigned short)(r >> 16);
}
__device__ inline float bf2f(unsigned u){
  union { unsigned u; float f; } v; v.u = u << 16; return v.f;
}

// ---------------- CSR build ----------------
__global__ __launch_bounds__(256) void k_deg_init(int* deg, int N){
  int i = blockIdx.x*256 + threadIdx.x;
  if (i < N) deg[i] = 1;               // self-loop
}
__global__ __launch_bounds__(256) void k_deg_count(const int* __restrict__ dst, int E, int* __restrict__ deg){
  int i = blockIdx.x*256 + threadIdx.x;
  if (i < E) atomicAdd(&deg[dst[i]], 1);
}
__global__ __launch_bounds__(1024) void k_scan(const int* __restrict__ deg, int* __restrict__ rowptr, int N){
  __shared__ int buf[1024];
  __shared__ int carry_s;
  int tid = threadIdx.x;
  if (tid == 0) carry_s = 0;
  __syncthreads();
  for (int base = 0; base < N; base += 1024){
    int v = (base+tid < N) ? deg[base+tid] : 0;
    int val = v;
    buf[tid] = v;
    __syncthreads();
    for (int off = 1; off < 1024; off <<= 1){
      int add = (tid >= off) ? buf[tid-off] : 0;
      __syncthreads();
      val += add;
      buf[tid] = val;
      __syncthreads();
    }
    int carry = carry_s;
    if (base+tid < N) rowptr[base+tid] = carry + val - v;  // exclusive
    __syncthreads();
    if (tid == 1023) carry_s = carry + val;
    __syncthreads();
  }
  if (tid == 0) rowptr[N] = carry_s;
}
__global__ __launch_bounds__(256) void k_pos_copy(const int* __restrict__ rowptr, int* __restrict__ pos, int N){
  int i = blockIdx.x*256 + threadIdx.x;
  if (i < N) pos[i] = rowptr[i];
}
__global__ __launch_bounds__(256) void k_fill_self(int* __restrict__ pos, int* __restrict__ colidx, int N){
  int i = blockIdx.x*256 + threadIdx.x;
  if (i < N) colidx[atomicAdd(&pos[i],1)] = i;
}
__global__ __launch_bounds__(256) void k_fill_edges(const int* __restrict__ src, const int* __restrict__ dst,
                                                    int E, int* __restrict__ pos, int* __restrict__ colidx){
  int i = blockIdx.x*256 + threadIdx.x;
  if (i < E){
    int d = dst[i];
    colidx[atomicAdd(&pos[d],1)] = src[i];
  }
}

// ---------------- weight transpose+convert: W[K][P] f32 -> Wt[P][K] bf16 ----------------
__global__ __launch_bounds__(256) void k_w2bt(const float* __restrict__ W, unsigned short* __restrict__ Wt,
                                              int K, int P){
  int idx = blockIdx.x*256 + threadIdx.x;
  if (idx < K*P){
    int k = idx / P, p = idx % P;
    Wt[(size_t)p*K + k] = f2bf(W[idx]);
  }
}

// ---------------- MFMA GEMM, P=64: C_bf16[M x 64] = A_f32[M x K(strided)] @ B + bias ----------------
// 256 threads = 4 waves (2x2), BM=128, BN=64.
template<int K>
__global__ __launch_bounds__(256) void k_gemm_p64(const float* __restrict__ A, int strideA,
                                                  const unsigned short* __restrict__ Bt,
                                                  const float* __restrict__ bias,
                                                  unsigned short* __restrict__ C, int M){
  constexpr int BK = 64, PAD = 8;
  __shared__ unsigned short Als[128][BK+PAD];
  __shared__ unsigned short Bls[64][BK+PAD];
  int tid = threadIdx.x;
  int m0  = blockIdx.x * 128;
  int wave = tid >> 6, lane = tid & 63;
  int wr = wave >> 1, wc = wave & 1;
  int lr = lane & 15, lk = (lane >> 4) * 8;
  f32x4 acc[4][2];
  #pragma unroll
  for (int m=0;m<4;m++)
    #pragma unroll
    for (int n=0;n<2;n++)
      #pragma unroll
      for (int j=0;j<4;j++) acc[m][n][j] = 0.f;

  for (int k0 = 0; k0 < K; k0 += BK){
    #pragma unroll
    for (int i=0;i<8;i++){
      int idx = tid + i*256;
      int r = idx >> 4, c4 = (idx & 15)*4;
      int row = m0 + r;
      float4 v = make_float4(0.f,0.f,0.f,0.f);
      if (row < M) v = *(const float4*)(A + (size_t)row*strideA + k0 + c4);
      unsigned lo = (unsigned)f2bf(v.x) | ((unsigned)f2bf(v.y) << 16);
      unsigned hi = (unsigned)f2bf(v.z) | ((unsigned)f2bf(v.w) << 16);
      *(uint2*)(&Als[r][c4]) = make_uint2(lo, hi);
    }
    #pragma unroll
    for (int i=0;i<2;i++){
      int idx = tid + i*256;
      int r = idx >> 3, ch = (idx & 7)*8;
      *(uint4*)(&Bls[r][ch]) = *(const uint4*)(Bt + (size_t)r*K + k0 + ch);
    }
    __syncthreads();
    #pragma unroll
    for (int ks=0; ks<2; ks++){
      short8 afr[4], bfr[2];
      #pragma unroll
      for (int m=0;m<4;m++)
        afr[m] = *(const short8*)(&Als[wr*64 + m*16 + lr][ks*32 + lk]);
      #pragma unroll
      for (int n=0;n<2;n++)
        bfr[n] = *(const short8*)(&Bls[wc*32 + n*16 + lr][ks*32 + lk]);
      #pragma unroll
      for (int m=0;m<4;m++)
        #pragma unroll
        for (int n=0;n<2;n++)
          acc[m][n] = __builtin_amdgcn_mfma_f32_16x16x32_bf16(afr[m], bfr[n], acc[m][n], 0,0,0);
    }
    __syncthreads();
  }
  #pragma unroll
  for (int m=0;m<4;m++){
    #pragma unroll
    for (int n=0;n<2;n++){
      int col = wc*32 + n*16 + lr;
      float bcol = bias[col];
      #pragma unroll
      for (int j=0;j<4;j++){
        int row = m0 + wr*64 + m*16 + (lane>>4)*4 + j;
        if (row < M)
          C[(size_t)row*64 + col] = f2bf(acc[m][n][j] + bcol);
      }
    }
  }
}

// ---------------- MFMA GEMM, P=256 full-width: 512 threads, BM=128, BN=256 ----------------
// A bf16 [M][K]; C bf16 or f32. One block covers all 256 output cols (A read once).
template<int K, bool BIAS, bool CF32>
__global__ __launch_bounds__(512) void k_gemm_p256(const unsigned short* __restrict__ A,
                                                   const unsigned short* __restrict__ Bt,
                                                   const float* __restrict__ bias,
                                                   void* __restrict__ Cv, int M){
  constexpr int BK = 64, PAD = 8;
  __shared__ unsigned short Als[128][BK+PAD];
  __shared__ unsigned short Bls[256][BK+PAD];
  int tid = threadIdx.x;
  int m0  = blockIdx.x * 128;
  int wave = tid >> 6, lane = tid & 63;
  int wr = wave & 3, wc = wave >> 2;      // 4 row-groups x 2 col-groups
  int lr = lane & 15, lk = (lane >> 4) * 8;
  f32x4 acc[2][8];
  #pragma unroll
  for (int m=0;m<2;m++)
    #pragma unroll
    for (int n=0;n<8;n++)
      #pragma unroll
      for (int j=0;j<4;j++) acc[m][n][j] = 0.f;

  for (int k0 = 0; k0 < K; k0 += BK){
    // stage A: 128 x 64 bf16 (16KB) in 2 rounds of uint4
    #pragma unroll
    for (int i=0;i<2;i++){
      int idx = tid + i*512;
      int r = idx >> 3, ch = (idx & 7)*8;
      int row = m0 + r;
      uint4 v = make_uint4(0,0,0,0);
      if (row < M) v = *(const uint4*)(A + (size_t)row*K + k0 + ch);
      *(uint4*)(&Als[r][ch]) = v;
    }
    // stage B: 256 x 64 bf16 (32KB) in 4 rounds
    #pragma unroll
    for (int i=0;i<4;i++){
      int idx = tid + i*512;
      int r = idx >> 3, ch = (idx & 7)*8;
      *(uint4*)(&Bls[r][ch]) = *(const uint4*)(Bt + (size_t)r*K + k0 + ch);
    }
    __syncthreads();
    #pragma unroll
    for (int ks=0; ks<2; ks++){
      short8 afr[2], bfr[8];
      #pragma unroll
      for (int m=0;m<2;m++)
        afr[m] = *(const short8*)(&Als[wr*32 + m*16 + lr][ks*32 + lk]);
      #pragma unroll
      for (int n=0;n<8;n++)
        bfr[n] = *(const short8*)(&Bls[wc*128 + n*16 + lr][ks*32 + lk]);
      #pragma unroll
      for (int m=0;m<2;m++)
        #pragma unroll
        for (int n=0;n<8;n++)
          acc[m][n] = __builtin_amdgcn_mfma_f32_16x16x32_bf16(afr[m], bfr[n], acc[m][n], 0,0,0);
    }
    __syncthreads();
  }
  #pragma unroll
  for (int m=0;m<2;m++){
    #pragma unroll
    for (int n=0;n<8;n++){
      int col = wc*128 + n*16 + lr;
      float bcol = BIAS ? bias[col] : 0.f;
      #pragma unroll
      for (int j=0;j<4;j++){
        int row = m0 + wr*32 + m*16 + (lane>>4)*4 + j;
        if (row < M){
          float v = acc[m][n][j] + bcol;
          if (CF32) ((float*)Cv)[(size_t)row*256 + col] = v;
          else      ((unsigned short*)Cv)[(size_t)row*256 + col] = f2bf(v);
        }
      }
    }
  }
}

// ---------------- per-node attention logits (bf16 hp, wave per node) ----------------
__global__ __launch_bounds__(256) void k_esd(const unsigned short* __restrict__ hp,
                                             const float* __restrict__ a_s, const float* __restrict__ a_d,
                                             float* __restrict__ e_s, float* __restrict__ e_d, int N){
  int n = blockIdx.x*4 + (threadIdx.x >> 6);
  if (n >= N) return;
  int lane = threadIdx.x & 63;
  uint2 v = *(const uint2*)(hp + (size_t)n*256 + lane*4);
  float v0 = bf2f(v.x & 0xffffu), v1 = bf2f(v.x >> 16);
  float v2 = bf2f(v.y & 0xffffu), v3 = bf2f(v.y >> 16);
  float4 as = *(const float4*)(a_s + lane*4);
  float4 ad = *(const float4*)(a_d + lane*4);
  float ps = v0*as.x + v1*as.y + v2*as.z + v3*as.w;
  float pd = v0*ad.x + v1*ad.y + v2*ad.z + v3*ad.w;
  #pragma unroll
  for (int off=1; off<16; off<<=1){ ps += __shfl_xor(ps,off); pd += __shfl_xor(pd,off); }
  if ((lane & 15) == 0){
    int h = lane >> 4;
    e_s[n*4+h] = ps; e_d[n*4+h] = pd;
  }
}

// ---------------- GAT aggregation, single pass, wave per node ----------------
__global__ __launch_bounds__(256) void k_agg(const unsigned short* __restrict__ hp,
                                             const float* __restrict__ e_s, const float* __restrict__ e_d,
                                             const int* __restrict__ rowptr, const int* __restrict__ colidx,
                                             const float* __restrict__ bias, unsigned short* __restrict__ outb, int N){
  int n = blockIdx.x*4 + (threadIdx.x >> 6);
  if (n >= N) return;
  int lane = threadIdx.x & 63;
  int h = lane >> 4;
  int s0 = rowptr[n], s1 = rowptr[n+1];
  float ed = e_d[n*4 + h];
  float z = 0.f;
  float a0=0.f, a1=0.f, a2=0.f, a3=0.f;
  for (int i = s0; i < s1; ++i){
    int s = colidx[i];
    float e = e_s[s*4 + h] + ed;
    e = (e > 0.f) ? e : NEG_SLOPE*e;
    float w = expf(e);
    z += w;
    uint2 v = *(const uint2*)(hp + (size_t)s*256 + lane*4);
    a0 += w * bf2f(v.x & 0xffffu);
    a1 += w * bf2f(v.x >> 16);
    a2 += w * bf2f(v.y & 0xffffu);
    a3 += w * bf2f(v.y >> 16);
  }
  float inv = 1.f / (z + 1e-16f);
  float4 b = *(const float4*)(bias + lane*4);
  float o0 = a0*inv + b.x, o1 = a1*inv + b.y, o2 = a2*inv + b.z, o3 = a3*inv + b.w;
  o0 = (o0 > 0.f) ? o0 : (expf(o0) - 1.f);
  o1 = (o1 > 0.f) ? o1 : (expf(o1) - 1.f);
  o2 = (o2 > 0.f) ? o2 : (expf(o2) - 1.f);
  o3 = (o3 > 0.f) ? o3 : (expf(o3) - 1.f);
  unsigned lo = (unsigned)f2bf(o0) | ((unsigned)f2bf(o1) << 16);
  unsigned hi = (unsigned)f2bf(o2) | ((unsigned)f2bf(o3) << 16);
  *(uint2*)(outb + (size_t)n*256 + lane*4) = make_uint2(lo, hi);
}

// ---------------- column sums (bf16 input) ----------------
__global__ __launch_bounds__(256) void k_colsum(const unsigned short* __restrict__ emb, float* __restrict__ sums, int N){
  __shared__ float red[8][256];
  int tid = threadIdx.x;
  int rows_per = (N + gridDim.x - 1) / gridDim.x;
  int r0 = blockIdx.x * rows_per;
  int r1 = min(N, r0 + rows_per);
  int c0 = (tid & 31)*8, rg = tid >> 5;
  float s[8] = {0,0,0,0,0,0,0,0};
  for (int r = r0 + rg; r < r1; r += 8){
    uint4 v = *(const uint4*)(emb + (size_t)r*256 + c0);
    s[0] += bf2f(v.x & 0xffffu); s[1] += bf2f(v.x >> 16);
    s[2] += bf2f(v.y & 0xffffu); s[3] += bf2f(v.y >> 16);
    s[4] += bf2f(v.z & 0xffffu); s[5] += bf2f(v.z >> 16);
    s[6] += bf2f(v.w & 0xffffu); s[7] += bf2f(v.w >> 16);
  }
  #pragma unroll
  for (int j=0;j<8;j++) red[rg][c0+j] = s[j];
  __syncthreads();
  float tot = 0.f;
  #pragma unroll
  for (int g=0;g<8;g++) tot += red[g][tid];
  atomicAdd(&sums[tid], tot);
}

// ---------------- temporal attention weights (tiny) ----------------
__global__ __launch_bounds__(256) void k_attn(const float* __restrict__ sum_emb,
                                              const float* __restrict__ Wq, const float* __restrict__ bq,
                                              const float* __restrict__ Wk, const float* __restrict__ bk,
                                              float* __restrict__ aw, int N){
  __shared__ float mean_s[4][256];
  __shared__ float red[256];
  __shared__ float scores_s[4];
  int j = threadIdx.x;
  float invN = 1.0f/(float)N;
  #pragma unroll
  for (int t=0;t<4;t++) mean_s[t][j] = sum_emb[t*256+j]*invN;
  __syncthreads();
  float q3 = bq[j];
  float kt0=bk[j], kt1=bk[j], kt2=bk[j], kt3=bk[j];
  for (int m=0;m<256;m++){
    float wq = Wq[m*256+j];
    float wk = Wk[m*256+j];
    float m0 = mean_s[0][m], m1 = mean_s[1][m], m2 = mean_s[2][m], m3 = mean_s[3][m];
    q3  += m3*wq;
    kt0 += m0*wk; kt1 += m1*wk; kt2 += m2*wk; kt3 += m3*wk;
  }
  float kts0=kt0, kts1=kt1, kts2=kt2, kts3=kt3;
  #pragma unroll
  for (int t=0;t<4;t++){
    float ktv = (t==0)?kts0:((t==1)?kts1:((t==2)?kts2:kts3));
    red[j] = q3*ktv;
    __syncthreads();
    for (int off=128; off>0; off>>=1){
      if (j < off) red[j] += red[j+off];
      __syncthreads();
    }
    if (j==0) scores_s[t] = red[0]*(1.0f/16.0f);   // /sqrt(256)
    __syncthreads();
  }
  if (j==0){
    float mx = fmaxf(fmaxf(scores_s[0],scores_s[1]),fmaxf(scores_s[2],scores_s[3]));
    float w0 = expf(scores_s[0]-mx), w1 = expf(scores_s[1]-mx),
          w2 = expf(scores_s[2]-mx), w3 = expf(scores_s[3]-mx);
    float s = w0+w1+w2+w3;
    aw[0]=w0/s; aw[1]=w1/s; aw[2]=w2/s; aw[3]=w3/s;
  }
}

// ---------------- temporal combine: comb = sum_t aw[t]*embs[t] (bf16 in/out) ----------------
__global__ __launch_bounds__(256) void k_combine(const unsigned short* __restrict__ embs,
                                                 const float* __restrict__ awp,
                                                 unsigned short* __restrict__ comb, int N){
  int i = blockIdx.x*256 + threadIdx.x;          // 8 elements per thread
  int total = N*32;
  if (i >= total) return;
  size_t o = (size_t)i*8;
  size_t sl = (size_t)N*256;
  float a0=awp[0], a1=awp[1], a2=awp[2], a3=awp[3];
  uint4 v0 = *(const uint4*)(embs + o);
  uint4 v1 = *(const uint4*)(embs + o + sl);
  uint4 v2 = *(const uint4*)(embs + o + 2*sl);
  uint4 v3 = *(const uint4*)(embs + o + 3*sl);
  uint4 r;
  unsigned w[4];
  const unsigned* p0=&v0.x; const unsigned* p1=&v1.x; const unsigned* p2=&v2.x; const unsigned* p3=&v3.x;
  #pragma unroll
  for (int k=0;k<4;k++){
    float lo = a0*bf2f(p0[k]&0xffffu) + a1*bf2f(p1[k]&0xffffu) + a2*bf2f(p2[k]&0xffffu) + a3*bf2f(p3[k]&0xffffu);
    float hi = a0*bf2f(p0[k]>>16)     + a1*bf2f(p1[k]>>16)     + a2*bf2f(p2[k]>>16)     + a3*bf2f(p3[k]>>16);
    w[k] = (unsigned)f2bf(lo) | ((unsigned)f2bf(hi) << 16);
  }
  r.x=w[0]; r.y=w[1]; r.z=w[2]; r.w=w[3];
  *(uint4*)(comb + o) = r;
}

extern "C" void kernel_launch(void* const* d_in, const int* in_sizes, int n_in,
                              void* d_out, int out_size, void* d_ws, size_t ws_size,
                              hipStream_t stream){
  (void)n_in; (void)out_size; (void)ws_size;
  const float* x   = (const float*)d_in[0];
  const int*   ei  = (const int*)d_in[1];
  const float* Wp  = (const float*)d_in[2];
  const float* bp  = (const float*)d_in[3];
  const float* W0  = (const float*)d_in[4];
  const float* as0 = (const float*)d_in[5];
  const float* ad0 = (const float*)d_in[6];
  const float* b0  = (const float*)d_in[7];
  const float* W1  = (const float*)d_in[8];
  const float* as1 = (const float*)d_in[9];
  const float* ad1 = (const float*)d_in[10];
  const float* b1  = (const float*)d_in[11];
  const float* Wq  = (const float*)d_in[12];
  const float* bq  = (const float*)d_in[13];
  const float* Wk  = (const float*)d_in[14];
  const float* bk  = (const float*)d_in[15];
  const float* Wv  = (const float*)d_in[16];
  const float* bv  = (const float*)d_in[17];
  float* out = (float*)d_out;

  const int T = 4, FIN = 256;
  const int N = in_sizes[0] / (T*FIN);
  const int E = in_sizes[1] / 2;
  const int* src = ei;
  const int* dst = ei + E;

  char* ws = (char*)d_ws;
  size_t cur = 0;
  auto alloc = [&](size_t bytes)->void*{
    void* p = ws + cur;
    cur += (bytes + 255) & ~(size_t)255;
    return p;
  };
  unsigned short* h0     = (unsigned short*)alloc((size_t)N*64*2);
  unsigned short* hp     = (unsigned short*)alloc((size_t)N*256*2);
  unsigned short* h1     = (unsigned short*)alloc((size_t)N*256*2);
  unsigned short* embs   = (unsigned short*)alloc((size_t)T*N*256*2);
  unsigned short* comb   = (unsigned short*)alloc((size_t)N*256*2);
  float* e_s    = (float*)alloc((size_t)N*4*4);
  float* e_d    = (float*)alloc((size_t)N*4*4);
  float* sume   = (float*)alloc(4*256*4);
  float* aw     = (float*)alloc(256);
  int*   rowptr = (int*)alloc((size_t)(N+1)*4);
  int*   deg    = (int*)alloc((size_t)N*4);
  int*   pos    = (int*)alloc((size_t)N*4);
  int*   colidx = (int*)alloc((size_t)(E+N)*4);
  unsigned short* WpT = (unsigned short*)alloc((size_t)64*256*2);    // [64][256]
  unsigned short* W0T = (unsigned short*)alloc((size_t)256*64*2);    // [256][64]
  unsigned short* W1T = (unsigned short*)alloc((size_t)256*256*2);   // [256][256]
  unsigned short* WvT = (unsigned short*)alloc((size_t)256*256*2);   // [256][256]

  int nb256 = (N+255)/256;
  int nbE   = (E+255)/256;
  int gm    = (N+127)/128;

  // CSR build (graph is static across t and layers -> build once)
  k_deg_init<<<nb256,256,0,stream>>>(deg, N);
  k_deg_count<<<nbE,256,0,stream>>>(dst, E, deg);
  k_scan<<<1,1024,0,stream>>>(deg, rowptr, N);
  k_pos_copy<<<nb256,256,0,stream>>>(rowptr, pos, N);
  k_fill_self<<<nb256,256,0,stream>>>(pos, colidx, N);
  k_fill_edges<<<nbE,256,0,stream>>>(src, dst, E, pos, colidx);
  hipMemsetAsync(sume, 0, 4*256*4, stream);

  // weight conversions (once)
  k_w2bt<<<(256*64+255)/256,256,0,stream>>>(Wp, WpT, 256, 64);
  k_w2bt<<<(64*256+255)/256,256,0,stream>>>(W0, W0T, 64, 256);
  k_w2bt<<<(256*256+255)/256,256,0,stream>>>(W1, W1T, 256, 256);
  k_w2bt<<<(256*256+255)/256,256,0,stream>>>(Wv, WvT, 256, 256);

  for (int t=0;t<T;t++){
    // h0 = x[:,t,:] @ Wp + bp      (N,256)@(256,64), bf16 out
    k_gemm_p64<256><<<gm,256,0,stream>>>(x + t*FIN, T*FIN, WpT, bp, h0, N);
    // GAT layer 0
    k_gemm_p256<64,false,false><<<gm,512,0,stream>>>(h0, W0T, nullptr, hp, N);
    k_esd<<<(N+3)/4,256,0,stream>>>(hp, as0, ad0, e_s, e_d, N);
    k_agg<<<(N+3)/4,256,0,stream>>>(hp, e_s, e_d, rowptr, colidx, b0, h1, N);
    // GAT layer 1
    k_gemm_p256<256,false,false><<<gm,512,0,stream>>>(h1, W1T, nullptr, hp, N);
    k_esd<<<(N+3)/4,256,0,stream>>>(hp, as1, ad1, e_s, e_d, N);
    k_agg<<<(N+3)/4,256,0,stream>>>(hp, e_s, e_d, rowptr, colidx, b1, embs + (size_t)t*N*256, N);
    // accumulate node-mean numerator for temporal attention
    k_colsum<<<128,256,0,stream>>>(embs + (size_t)t*N*256, sume + t*256, N);
  }
  // temporal attention weights for the last row (T-1), then combine + V-projection
  k_attn<<<1,256,0,stream>>>(sume, Wq, bq, Wk, bk, aw, N);
  k_combine<<<(N*32+255)/256,256,0,stream>>>(embs, aw, comb, N);
  k_gemm_p256<256,true,true><<<gm,512,0,stream>>>(comb, WvT, bv, out, N);
}

// Round 4
// 735.882 us; speedup vs baseline: 2.3956x; 1.0424x over previous
//
#include <hip/hip_runtime.h>
#include <math.h>

#define NEG_SLOPE 0.2f

typedef __attribute__((ext_vector_type(8))) short short8;
typedef __attribute__((ext_vector_type(4))) float f32x4;

__device__ inline unsigned short f2bf(float f){
  union { float f; unsigned u; } v; v.f = f;
  unsigned r = v.u + 0x7fffu + ((v.u >> 16) & 1u);
  return (unsigned short)(r >> 16);
}
__device__ inline float bf2f(unsigned u){
  union { unsigned u; float f; } v; v.u = u << 16; return v.f;
}

// ---------------- CSR build ----------------
__global__ __launch_bounds__(256) void k_deg_init(int* deg, int N){
  int i = blockIdx.x*256 + threadIdx.x;
  if (i < N) deg[i] = 1;               // self-loop
}
__global__ __launch_bounds__(256) void k_deg_count(const int* __restrict__ dst, int E, int* __restrict__ deg){
  int i = blockIdx.x*256 + threadIdx.x;
  if (i < E) atomicAdd(&deg[dst[i]], 1);
}
__global__ __launch_bounds__(1024) void k_scan(const int* __restrict__ deg, int* __restrict__ rowptr, int N){
  __shared__ int buf[1024];
  __shared__ int carry_s;
  int tid = threadIdx.x;
  if (tid == 0) carry_s = 0;
  __syncthreads();
  for (int base = 0; base < N; base += 1024){
    int v = (base+tid < N) ? deg[base+tid] : 0;
    int val = v;
    buf[tid] = v;
    __syncthreads();
    for (int off = 1; off < 1024; off <<= 1){
      int add = (tid >= off) ? buf[tid-off] : 0;
      __syncthreads();
      val += add;
      buf[tid] = val;
      __syncthreads();
    }
    int carry = carry_s;
    if (base+tid < N) rowptr[base+tid] = carry + val - v;  // exclusive
    __syncthreads();
    if (tid == 1023) carry_s = carry + val;
    __syncthreads();
  }
  if (tid == 0) rowptr[N] = carry_s;
}
__global__ __launch_bounds__(256) void k_pos_copy(const int* __restrict__ rowptr, int* __restrict__ pos, int N){
  int i = blockIdx.x*256 + threadIdx.x;
  if (i < N) pos[i] = rowptr[i];
}
__global__ __launch_bounds__(256) void k_fill_self(int* __restrict__ pos, int* __restrict__ colidx, int N){
  int i = blockIdx.x*256 + threadIdx.x;
  if (i < N) colidx[atomicAdd(&pos[i],1)] = i;
}
__global__ __launch_bounds__(256) void k_fill_edges(const int* __restrict__ src, const int* __restrict__ dst,
                                                    int E, int* __restrict__ pos, int* __restrict__ colidx){
  int i = blockIdx.x*256 + threadIdx.x;
  if (i < E){
    int d = dst[i];
    colidx[atomicAdd(&pos[d],1)] = src[i];
  }
}

// ---------------- weight transpose+convert: W[K][P] f32 -> Wt[P][K] bf16 ----------------
__global__ __launch_bounds__(256) void k_w2bt(const float* __restrict__ W, unsigned short* __restrict__ Wt,
                                              int K, int P){
  int idx = blockIdx.x*256 + threadIdx.x;
  if (idx < K*P){
    int k = idx / P, p = idx % P;
    Wt[(size_t)p*K + k] = f2bf(W[idx]);
  }
}

// ---------------- fold a into W0: ahat[h*64+d] = sum_j W0[d][h*64+j]*a[h][j] ----------------
__global__ __launch_bounds__(256) void k_fold_a(const float* __restrict__ W0,
                                                const float* __restrict__ a_s, const float* __restrict__ a_d,
                                                float* __restrict__ ahs, float* __restrict__ ahd){
  int tid = threadIdx.x;                 // 256 = (h,d)
  int h = tid >> 6, d = tid & 63;
  float ss = 0.f, sd = 0.f;
  for (int j=0;j<64;j++){
    float w = W0[d*256 + h*64 + j];
    ss += w * a_s[h*64 + j];
    sd += w * a_d[h*64 + j];
  }
  ahs[tid] = ss; ahd[tid] = sd;
}

// ---------------- densified block-diag W0: Bt[p][k] = (p>>6==k>>6) ? W0[k&63][p] : 0 ----------------
__global__ __launch_bounds__(256) void k_w0bd(const float* __restrict__ W0, unsigned short* __restrict__ Bt){
  int idx = blockIdx.x*256 + threadIdx.x;
  if (idx < 256*256){
    int p = idx >> 8, k = idx & 255;
    float v = ((p>>6) == (k>>6)) ? W0[(k&63)*256 + p] : 0.f;
    Bt[idx] = f2bf(v);
  }
}

// ---------------- MFMA GEMM, P=64: 4-timestep merged Wp projection ----------------
// A f32 (M=4N, 256) row-major (x as-is). C bf16 de-interleaved: row r=(n*4+t) -> h0[t*N64 + n*64].
template<int K>
__global__ __launch_bounds__(256) void k_gemm_p64(const float* __restrict__ A,
                                                  const unsigned short* __restrict__ Bt,
                                                  const float* __restrict__ bias,
                                                  unsigned short* __restrict__ C, int M, int Nn){
  constexpr int BK = 64, PAD = 8;
  __shared__ unsigned short Als[128][BK+PAD];
  __shared__ unsigned short Bls[64][BK+PAD];
  int tid = threadIdx.x;
  int m0  = blockIdx.x * 128;
  int wave = tid >> 6, lane = tid & 63;
  int wr = wave >> 1, wc = wave & 1;
  int lr = lane & 15, lk = (lane >> 4) * 8;
  f32x4 acc[4][2];
  #pragma unroll
  for (int m=0;m<4;m++)
    #pragma unroll
    for (int n=0;n<2;n++)
      #pragma unroll
      for (int j=0;j<4;j++) acc[m][n][j] = 0.f;

  for (int k0 = 0; k0 < K; k0 += BK){
    #pragma unroll
    for (int i=0;i<8;i++){
      int idx = tid + i*256;
      int r = idx >> 4, c4 = (idx & 15)*4;
      int row = m0 + r;
      float4 v = make_float4(0.f,0.f,0.f,0.f);
      if (row < M) v = *(const float4*)(A + (size_t)row*K + k0 + c4);
      unsigned lo = (unsigned)f2bf(v.x) | ((unsigned)f2bf(v.y) << 16);
      unsigned hi = (unsigned)f2bf(v.z) | ((unsigned)f2bf(v.w) << 16);
      *(uint2*)(&Als[r][c4]) = make_uint2(lo, hi);
    }
    #pragma unroll
    for (int i=0;i<2;i++){
      int idx = tid + i*256;
      int r = idx >> 3, ch = (idx & 7)*8;
      *(uint4*)(&Bls[r][ch]) = *(const uint4*)(Bt + (size_t)r*K + k0 + ch);
    }
    __syncthreads();
    #pragma unroll
    for (int ks=0; ks<2; ks++){
      short8 afr[4], bfr[2];
      #pragma unroll
      for (int m=0;m<4;m++)
        afr[m] = *(const short8*)(&Als[wr*64 + m*16 + lr][ks*32 + lk]);
      #pragma unroll
      for (int n=0;n<2;n++)
        bfr[n] = *(const short8*)(&Bls[wc*32 + n*16 + lr][ks*32 + lk]);
      #pragma unroll
      for (int m=0;m<4;m++)
        #pragma unroll
        for (int n=0;n<2;n++)
          acc[m][n] = __builtin_amdgcn_mfma_f32_16x16x32_bf16(afr[m], bfr[n], acc[m][n], 0,0,0);
    }
    __syncthreads();
  }
  #pragma unroll
  for (int m=0;m<4;m++){
    #pragma unroll
    for (int n=0;n<2;n++){
      int col = wc*32 + n*16 + lr;
      float bcol = bias[col];
      #pragma unroll
      for (int j=0;j<4;j++){
        int row = m0 + wr*64 + m*16 + (lane>>4)*4 + j;
        if (row < M){
          int t = row & 3, nn = row >> 2;
          C[(size_t)t*Nn*64 + (size_t)nn*64 + col] = f2bf(acc[m][n][j] + bcol);
        }
      }
    }
  }
}

// ---------------- MFMA GEMM, P=256 full-width: 512 threads, BM=128, BN=256 ----------------
template<int K, bool BIAS, bool CF32, bool ELU>
__global__ __launch_bounds__(512) void k_gemm_p256(const unsigned short* __restrict__ A,
                                                   const unsigned short* __restrict__ Bt,
                                                   const float* __restrict__ bias,
                                                   void* __restrict__ Cv, int M){
  constexpr int BK = 64, PAD = 8;
  __shared__ unsigned short Als[128][BK+PAD];
  __shared__ unsigned short Bls[256][BK+PAD];
  int tid = threadIdx.x;
  int m0  = blockIdx.x * 128;
  int wave = tid >> 6, lane = tid & 63;
  int wr = wave & 3, wc = wave >> 2;      // 4 row-groups x 2 col-groups
  int lr = lane & 15, lk = (lane >> 4) * 8;
  f32x4 acc[2][8];
  #pragma unroll
  for (int m=0;m<2;m++)
    #pragma unroll
    for (int n=0;n<8;n++)
      #pragma unroll
      for (int j=0;j<4;j++) acc[m][n][j] = 0.f;

  for (int k0 = 0; k0 < K; k0 += BK){
    #pragma unroll
    for (int i=0;i<2;i++){
      int idx = tid + i*512;
      int r = idx >> 3, ch = (idx & 7)*8;
      int row = m0 + r;
      uint4 v = make_uint4(0,0,0,0);
      if (row < M) v = *(const uint4*)(A + (size_t)row*K + k0 + ch);
      *(uint4*)(&Als[r][ch]) = v;
    }
    #pragma unroll
    for (int i=0;i<4;i++){
      int idx = tid + i*512;
      int r = idx >> 3, ch = (idx & 7)*8;
      *(uint4*)(&Bls[r][ch]) = *(const uint4*)(Bt + (size_t)r*K + k0 + ch);
    }
    __syncthreads();
    #pragma unroll
    for (int ks=0; ks<2; ks++){
      short8 afr[2], bfr[8];
      #pragma unroll
      for (int m=0;m<2;m++)
        afr[m] = *(const short8*)(&Als[wr*32 + m*16 + lr][ks*32 + lk]);
      #pragma unroll
      for (int n=0;n<8;n++)
        bfr[n] = *(const short8*)(&Bls[wc*128 + n*16 + lr][ks*32 + lk]);
      #pragma unroll
      for (int m=0;m<2;m++)
        #pragma unroll
        for (int n=0;n<8;n++)
          acc[m][n] = __builtin_amdgcn_mfma_f32_16x16x32_bf16(afr[m], bfr[n], acc[m][n], 0,0,0);
    }
    __syncthreads();
  }
  #pragma unroll
  for (int m=0;m<2;m++){
    #pragma unroll
    for (int n=0;n<8;n++){
      int col = wc*128 + n*16 + lr;
      float bcol = BIAS ? bias[col] : 0.f;
      #pragma unroll
      for (int j=0;j<4;j++){
        int row = m0 + wr*32 + m*16 + (lane>>4)*4 + j;
        if (row < M){
          float v = acc[m][n][j] + bcol;
          if (ELU) v = (v > 0.f) ? v : (expf(v) - 1.f);
          if (CF32) ((float*)Cv)[(size_t)row*256 + col] = v;
          else      ((unsigned short*)Cv)[(size_t)row*256 + col] = f2bf(v);
        }
      }
    }
  }
}

// ---------------- layer-0 logits from h0 (64-dim) with folded a-hat ----------------
__global__ __launch_bounds__(256) void k_esd0(const unsigned short* __restrict__ h0,
                                              const float* __restrict__ ahs, const float* __restrict__ ahd,
                                              float* __restrict__ e_s, float* __restrict__ e_d, int N){
  int n = blockIdx.x*4 + (threadIdx.x >> 6);
  if (n >= N) return;
  int lane = threadIdx.x & 63;
  int h = lane >> 4, l4 = (lane & 15)*4;
  uint2 v = *(const uint2*)(h0 + (size_t)n*64 + l4);
  float v0 = bf2f(v.x & 0xffffu), v1 = bf2f(v.x >> 16);
  float v2 = bf2f(v.y & 0xffffu), v3 = bf2f(v.y >> 16);
  float4 as = *(const float4*)(ahs + h*64 + l4);
  float4 ad = *(const float4*)(ahd + h*64 + l4);
  float ps = v0*as.x + v1*as.y + v2*as.z + v3*as.w;
  float pd = v0*ad.x + v1*ad.y + v2*ad.z + v3*ad.w;
  #pragma unroll
  for (int off=1; off<16; off<<=1){ ps += __shfl_xor(ps,off); pd += __shfl_xor(pd,off); }
  if ((lane & 15) == 0){
    e_s[n*4+h] = ps; e_d[n*4+h] = pd;
  }
}

// ---------------- layer-0 aggregation: agg0[n, h*64+d] = sum_s alpha_h * h0[s,d] ----------------
// 128B gather per edge (4-head lanes broadcast the same 128B row).
__global__ __launch_bounds__(256) void k_agg0(const unsigned short* __restrict__ h0,
                                              const float* __restrict__ e_s, const float* __restrict__ e_d,
                                              const int* __restrict__ rowptr, const int* __restrict__ colidx,
                                              unsigned short* __restrict__ agg, int N){
  int n = blockIdx.x*4 + (threadIdx.x >> 6);
  if (n >= N) return;
  int lane = threadIdx.x & 63;
  int h = lane >> 4, l4 = (lane & 15)*4;
  int s0 = rowptr[n], s1 = rowptr[n+1];
  float ed = e_d[n*4 + h];
  float z = 0.f;
  float a0=0.f, a1=0.f, a2=0.f, a3=0.f;
  for (int i = s0; i < s1; ++i){
    int s = colidx[i];
    float e = e_s[s*4 + h] + ed;
    e = (e > 0.f) ? e : NEG_SLOPE*e;
    float w = expf(e);
    z += w;
    uint2 v = *(const uint2*)(h0 + (size_t)s*64 + l4);
    a0 += w * bf2f(v.x & 0xffffu);
    a1 += w * bf2f(v.x >> 16);
    a2 += w * bf2f(v.y & 0xffffu);
    a3 += w * bf2f(v.y >> 16);
  }
  float inv = 1.f / (z + 1e-16f);
  unsigned lo = (unsigned)f2bf(a0*inv) | ((unsigned)f2bf(a1*inv) << 16);
  unsigned hi = (unsigned)f2bf(a2*inv) | ((unsigned)f2bf(a3*inv) << 16);
  *(uint2*)(agg + (size_t)n*256 + h*64 + l4) = make_uint2(lo, hi);
}

// ---------------- per-node attention logits (256-dim hp) ----------------
__global__ __launch_bounds__(256) void k_esd(const unsigned short* __restrict__ hp,
                                             const float* __restrict__ a_s, const float* __restrict__ a_d,
                                             float* __restrict__ e_s, float* __restrict__ e_d, int N){
  int n = blockIdx.x*4 + (threadIdx.x >> 6);
  if (n >= N) return;
  int lane = threadIdx.x & 63;
  uint2 v = *(const uint2*)(hp + (size_t)n*256 + lane*4);
  float v0 = bf2f(v.x & 0xffffu), v1 = bf2f(v.x >> 16);
  float v2 = bf2f(v.y & 0xffffu), v3 = bf2f(v.y >> 16);
  float4 as = *(const float4*)(a_s + lane*4);
  float4 ad = *(const float4*)(a_d + lane*4);
  float ps = v0*as.x + v1*as.y + v2*as.z + v3*as.w;
  float pd = v0*ad.x + v1*ad.y + v2*ad.z + v3*ad.w;
  #pragma unroll
  for (int off=1; off<16; off<<=1){ ps += __shfl_xor(ps,off); pd += __shfl_xor(pd,off); }
  if ((lane & 15) == 0){
    int h = lane >> 4;
    e_s[n*4+h] = ps; e_d[n*4+h] = pd;
  }
}

// ---------------- layer-1 aggregation (512B gather) + bias + ELU ----------------
__global__ __launch_bounds__(256) void k_agg(const unsigned short* __restrict__ hp,
                                             const float* __restrict__ e_s, const float* __restrict__ e_d,
                                             const int* __restrict__ rowptr, const int* __restrict__ colidx,
                                             const float* __restrict__ bias, unsigned short* __restrict__ outb, int N){
  int n = blockIdx.x*4 + (threadIdx.x >> 6);
  if (n >= N) return;
  int lane = threadIdx.x & 63;
  int h = lane >> 4;
  int s0 = rowptr[n], s1 = rowptr[n+1];
  float ed = e_d[n*4 + h];
  float z = 0.f;
  float a0=0.f, a1=0.f, a2=0.f, a3=0.f;
  for (int i = s0; i < s1; ++i){
    int s = colidx[i];
    float e = e_s[s*4 + h] + ed;
    e = (e > 0.f) ? e : NEG_SLOPE*e;
    float w = expf(e);
    z += w;
    uint2 v = *(const uint2*)(hp + (size_t)s*256 + lane*4);
    a0 += w * bf2f(v.x & 0xffffu);
    a1 += w * bf2f(v.x >> 16);
    a2 += w * bf2f(v.y & 0xffffu);
    a3 += w * bf2f(v.y >> 16);
  }
  float inv = 1.f / (z + 1e-16f);
  float4 b = *(const float4*)(bias + lane*4);
  float o0 = a0*inv + b.x, o1 = a1*inv + b.y, o2 = a2*inv + b.z, o3 = a3*inv + b.w;
  o0 = (o0 > 0.f) ? o0 : (expf(o0) - 1.f);
  o1 = (o1 > 0.f) ? o1 : (expf(o1) - 1.f);
  o2 = (o2 > 0.f) ? o2 : (expf(o2) - 1.f);
  o3 = (o3 > 0.f) ? o3 : (expf(o3) - 1.f);
  unsigned lo = (unsigned)f2bf(o0) | ((unsigned)f2bf(o1) << 16);
  unsigned hi = (unsigned)f2bf(o2) | ((unsigned)f2bf(o3) << 16);
  *(uint2*)(outb + (size_t)n*256 + lane*4) = make_uint2(lo, hi);
}

// ---------------- column sums (bf16 input) ----------------
__global__ __launch_bounds__(256) void k_colsum(const unsigned short* __restrict__ emb, float* __restrict__ sums, int N){
  __shared__ float red[8][256];
  int tid = threadIdx.x;
  int rows_per = (N + gridDim.x - 1) / gridDim.x;
  int r0 = blockIdx.x * rows_per;
  int r1 = min(N, r0 + rows_per);
  int c0 = (tid & 31)*8, rg = tid >> 5;
  float s[8] = {0,0,0,0,0,0,0,0};
  for (int r = r0 + rg; r < r1; r += 8){
    uint4 v = *(const uint4*)(emb + (size_t)r*256 + c0);
    s[0] += bf2f(v.x & 0xffffu); s[1] += bf2f(v.x >> 16);
    s[2] += bf2f(v.y & 0xffffu); s[3] += bf2f(v.y >> 16);
    s[4] += bf2f(v.z & 0xffffu); s[5] += bf2f(v.z >> 16);
    s[6] += bf2f(v.w & 0xffffu); s[7] += bf2f(v.w >> 16);
  }
  #pragma unroll
  for (int j=0;j<8;j++) red[rg][c0+j] = s[j];
  __syncthreads();
  float tot = 0.f;
  #pragma unroll
  for (int g=0;g<8;g++) tot += red[g][tid];
  atomicAdd(&sums[tid], tot);
}

// ---------------- temporal attention weights (tiny) ----------------
__global__ __launch_bounds__(256) void k_attn(const float* __restrict__ sum_emb,
                                              const float* __restrict__ Wq, const float* __restrict__ bq,
                                              const float* __restrict__ Wk, const float* __restrict__ bk,
                                              float* __restrict__ aw, int N){
  __shared__ float mean_s[4][256];
  __shared__ float red[256];
  __shared__ float scores_s[4];
  int j = threadIdx.x;
  float invN = 1.0f/(float)N;
  #pragma unroll
  for (int t=0;t<4;t++) mean_s[t][j] = sum_emb[t*256+j]*invN;
  __syncthreads();
  float q3 = bq[j];
  float kt0=bk[j], kt1=bk[j], kt2=bk[j], kt3=bk[j];
  for (int m=0;m<256;m++){
    float wq = Wq[m*256+j];
    float wk = Wk[m*256+j];
    float m0 = mean_s[0][m], m1 = mean_s[1][m], m2 = mean_s[2][m], m3 = mean_s[3][m];
    q3  += m3*wq;
    kt0 += m0*wk; kt1 += m1*wk; kt2 += m2*wk; kt3 += m3*wk;
  }
  float kts0=kt0, kts1=kt1, kts2=kt2, kts3=kt3;
  #pragma unroll
  for (int t=0;t<4;t++){
    float ktv = (t==0)?kts0:((t==1)?kts1:((t==2)?kts2:kts3));
    red[j] = q3*ktv;
    __syncthreads();
    for (int off=128; off>0; off>>=1){
      if (j < off) red[j] += red[j+off];
      __syncthreads();
    }
    if (j==0) scores_s[t] = red[0]*(1.0f/16.0f);   // /sqrt(256)
    __syncthreads();
  }
  if (j==0){
    float mx = fmaxf(fmaxf(scores_s[0],scores_s[1]),fmaxf(scores_s[2],scores_s[3]));
    float w0 = expf(scores_s[0]-mx), w1 = expf(scores_s[1]-mx),
          w2 = expf(scores_s[2]-mx), w3 = expf(scores_s[3]-mx);
    float s = w0+w1+w2+w3;
    aw[0]=w0/s; aw[1]=w1/s; aw[2]=w2/s; aw[3]=w3/s;
  }
}

// ---------------- temporal combine: comb = sum_t aw[t]*embs[t] (bf16 in/out) ----------------
__global__ __launch_bounds__(256) void k_combine(const unsigned short* __restrict__ embs,
                                                 const float* __restrict__ awp,
                                                 unsigned short* __restrict__ comb, int N){
  int i = blockIdx.x*256 + threadIdx.x;          // 8 elements per thread
  int total = N*32;
  if (i >= total) return;
  size_t o = (size_t)i*8;
  size_t sl = (size_t)N*256;
  float a0=awp[0], a1=awp[1], a2=awp[2], a3=awp[3];
  uint4 v0 = *(const uint4*)(embs + o);
  uint4 v1 = *(const uint4*)(embs + o + sl);
  uint4 v2 = *(const uint4*)(embs + o + 2*sl);
  uint4 v3 = *(const uint4*)(embs + o + 3*sl);
  uint4 r;
  unsigned w[4];
  const unsigned* p0=&v0.x; const unsigned* p1=&v1.x; const unsigned* p2=&v2.x; const unsigned* p3=&v3.x;
  #pragma unroll
  for (int k=0;k<4;k++){
    float lo = a0*bf2f(p0[k]&0xffffu) + a1*bf2f(p1[k]&0xffffu) + a2*bf2f(p2[k]&0xffffu) + a3*bf2f(p3[k]&0xffffu);
    float hi = a0*bf2f(p0[k]>>16)     + a1*bf2f(p1[k]>>16)     + a2*bf2f(p2[k]>>16)     + a3*bf2f(p3[k]>>16);
    w[k] = (unsigned)f2bf(lo) | ((unsigned)f2bf(hi) << 16);
  }
  r.x=w[0]; r.y=w[1]; r.z=w[2]; r.w=w[3];
  *(uint4*)(comb + o) = r;
}

extern "C" void kernel_launch(void* const* d_in, const int* in_sizes, int n_in,
                              void* d_out, int out_size, void* d_ws, size_t ws_size,
                              hipStream_t stream){
  (void)n_in; (void)out_size; (void)ws_size;
  const float* x   = (const float*)d_in[0];
  const int*   ei  = (const int*)d_in[1];
  const float* Wp  = (const float*)d_in[2];
  const float* bp  = (const float*)d_in[3];
  const float* W0  = (const float*)d_in[4];
  const float* as0 = (const float*)d_in[5];
  const float* ad0 = (const float*)d_in[6];
  const float* b0  = (const float*)d_in[7];
  const float* W1  = (const float*)d_in[8];
  const float* as1 = (const float*)d_in[9];
  const float* ad1 = (const float*)d_in[10];
  const float* b1  = (const float*)d_in[11];
  const float* Wq  = (const float*)d_in[12];
  const float* bq  = (const float*)d_in[13];
  const float* Wk  = (const float*)d_in[14];
  const float* bk  = (const float*)d_in[15];
  const float* Wv  = (const float*)d_in[16];
  const float* bv  = (const float*)d_in[17];
  float* out = (float*)d_out;

  const int T = 4, FIN = 256;
  const int N = in_sizes[0] / (T*FIN);
  const int E = in_sizes[1] / 2;
  const int* src = ei;
  const int* dst = ei + E;

  char* ws = (char*)d_ws;
  size_t cur = 0;
  auto alloc = [&](size_t bytes)->void*{
    void* p = ws + cur;
    cur += (bytes + 255) & ~(size_t)255;
    return p;
  };
  unsigned short* h0all  = (unsigned short*)alloc((size_t)T*N*64*2);   // [T][N][64]
  unsigned short* hp     = (unsigned short*)alloc((size_t)N*256*2);    // also agg0 / comb (aliased, lifetimes disjoint)
  unsigned short* h1     = (unsigned short*)alloc((size_t)N*256*2);
  unsigned short* embs   = (unsigned short*)alloc((size_t)T*N*256*2);
  float* e_s    = (float*)alloc((size_t)N*4*4);
  float* e_d    = (float*)alloc((size_t)N*4*4);
  float* sume   = (float*)alloc(4*256*4);
  float* aw     = (float*)alloc(256);
  float* ah0s   = (float*)alloc(256*4);
  float* ah0d   = (float*)alloc(256*4);
  int*   rowptr = (int*)alloc((size_t)(N+1)*4);
  int*   deg    = (int*)alloc((size_t)N*4);
  int*   pos    = (int*)alloc((size_t)N*4);
  int*   colidx = (int*)alloc((size_t)(E+N)*4);
  unsigned short* WpT  = (unsigned short*)alloc((size_t)64*256*2);    // [64][256]
  unsigned short* W0BD = (unsigned short*)alloc((size_t)256*256*2);   // densified block-diag, transposed
  unsigned short* W1T  = (unsigned short*)alloc((size_t)256*256*2);   // [256][256]
  unsigned short* WvT  = (unsigned short*)alloc((size_t)256*256*2);   // [256][256]

  unsigned short* agg0 = hp;   // alias: dead before hp is written each timestep
  unsigned short* comb = hp;   // alias: used after the loop when hp is dead

  int nb256 = (N+255)/256;
  int nbE   = (E+255)/256;
  int gm    = (N+127)/128;

  // CSR build (graph is static across t and layers -> build once)
  k_deg_init<<<nb256,256,0,stream>>>(deg, N);
  k_deg_count<<<nbE,256,0,stream>>>(dst, E, deg);
  k_scan<<<1,1024,0,stream>>>(deg, rowptr, N);
  k_pos_copy<<<nb256,256,0,stream>>>(rowptr, pos, N);
  k_fill_self<<<nb256,256,0,stream>>>(pos, colidx, N);
  k_fill_edges<<<nbE,256,0,stream>>>(src, dst, E, pos, colidx);
  hipMemsetAsync(sume, 0, 4*256*4, stream);

  // weight prep (once)
  k_w2bt<<<(256*64+255)/256,256,0,stream>>>(Wp, WpT, 256, 64);
  k_w0bd<<<(256*256+255)/256,256,0,stream>>>(W0, W0BD);
  k_fold_a<<<1,256,0,stream>>>(W0, as0, ad0, ah0s, ah0d);
  k_w2bt<<<(256*256+255)/256,256,0,stream>>>(W1, W1T, 256, 256);
  k_w2bt<<<(256*256+255)/256,256,0,stream>>>(Wv, WvT, 256, 256);

  // merged Wp projection for all 4 timesteps: x is (N*T, 256) row-major
  k_gemm_p64<256><<<(4*N+127)/128,256,0,stream>>>(x, WpT, bp, h0all, 4*N, N);

  for (int t=0;t<T;t++){
    const unsigned short* h0 = h0all + (size_t)t*N*64;
    // GAT layer 0 (hp never materialized: logits + aggregation on 64-dim h0)
    k_esd0<<<(N+3)/4,256,0,stream>>>(h0, ah0s, ah0d, e_s, e_d, N);
    k_agg0<<<(N+3)/4,256,0,stream>>>(h0, e_s, e_d, rowptr, colidx, agg0, N);
    // h1 = ELU(agg0 @ W0_blockdiag + b0)
    k_gemm_p256<256,true,false,true><<<gm,512,0,stream>>>(agg0, W0BD, b0, h1, N);
    // GAT layer 1
    k_gemm_p256<256,false,false,false><<<gm,512,0,stream>>>(h1, W1T, nullptr, hp, N);
    k_esd<<<(N+3)/4,256,0,stream>>>(hp, as1, ad1, e_s, e_d, N);
    k_agg<<<(N+3)/4,256,0,stream>>>(hp, e_s, e_d, rowptr, colidx, b1, embs + (size_t)t*N*256, N);
    // accumulate node-mean numerator for temporal attention
    k_colsum<<<128,256,0,stream>>>(embs + (size_t)t*N*256, sume + t*256, N);
  }
  // temporal attention weights for the last row (T-1), then combine + V-projection
  k_attn<<<1,256,0,stream>>>(sume, Wq, bq, Wk, bk, aw, N);
  k_combine<<<(N*32+255)/256,256,0,stream>>>(embs, aw, comb, N);
  k_gemm_p256<256,true,true,false><<<gm,512,0,stream>>>(comb, WvT, bv, out, N);
}

// Round 5
// 640.893 us; speedup vs baseline: 2.7506x; 1.1482x over previous
//
#include <hip/hip_runtime.h>
#include <math.h>

#define NEG_SLOPE 0.2f

typedef __attribute__((ext_vector_type(8))) short short8;
typedef __attribute__((ext_vector_type(4))) float f32x4;

__device__ inline unsigned short f2bf(float f){
  union { float f; unsigned u; } v; v.f = f;
  unsigned r = v.u + 0x7fffu + ((v.u >> 16) & 1u);
  return (unsigned short)(r >> 16);
}
__device__ inline float bf2f(unsigned u){
  union { unsigned u; float f; } v; v.u = u << 16; return v.f;
}

// ---------------- CSR build ----------------
__global__ __launch_bounds__(256) void k_deg_init(int* deg, int N){
  int i = blockIdx.x*256 + threadIdx.x;
  if (i < N) deg[i] = 1;               // self-loop
}
__global__ __launch_bounds__(256) void k_deg_count(const int* __restrict__ dst, int E, int* __restrict__ deg){
  int i = blockIdx.x*256 + threadIdx.x;
  if (i < E) atomicAdd(&deg[dst[i]], 1);
}
__global__ __launch_bounds__(1024) void k_scan(const int* __restrict__ deg, int* __restrict__ rowptr, int N){
  __shared__ int buf[1024];
  __shared__ int carry_s;
  int tid = threadIdx.x;
  if (tid == 0) carry_s = 0;
  __syncthreads();
  for (int base = 0; base < N; base += 1024){
    int v = (base+tid < N) ? deg[base+tid] : 0;
    int val = v;
    buf[tid] = v;
    __syncthreads();
    for (int off = 1; off < 1024; off <<= 1){
      int add = (tid >= off) ? buf[tid-off] : 0;
      __syncthreads();
      val += add;
      buf[tid] = val;
      __syncthreads();
    }
    int carry = carry_s;
    if (base+tid < N) rowptr[base+tid] = carry + val - v;  // exclusive
    __syncthreads();
    if (tid == 1023) carry_s = carry + val;
    __syncthreads();
  }
  if (tid == 0) rowptr[N] = carry_s;
}
// pos = rowptr+1 and self-loop written deterministically first
__global__ __launch_bounds__(256) void k_pos_self(const int* __restrict__ rowptr, int* __restrict__ pos,
                                                  int* __restrict__ colidx, int N){
  int i = blockIdx.x*256 + threadIdx.x;
  if (i < N){
    int r = rowptr[i];
    colidx[r] = i;
    pos[i] = r + 1;
  }
}
__global__ __launch_bounds__(256) void k_fill_edges(const int* __restrict__ src, const int* __restrict__ dst,
                                                    int E, int* __restrict__ pos, int* __restrict__ colidx){
  int i = blockIdx.x*256 + threadIdx.x;
  if (i < E){
    int d = dst[i];
    colidx[atomicAdd(&pos[d],1)] = src[i];
  }
}

// ---------------- all weight prep in one launch ----------------
// seg0 [0,16384):        WpT[p*256+k]  = bf(Wp[k*64+p])          (Wp 256x64)
// seg1 [16384,81920):    W0BD[p*256+k] = blockdiag(W0) (W0 64x256)
// seg2 [81920,147456):   W1T[p*256+k]  = bf(W1[k*256+p])
// seg3 [147456,212992):  WvT[p*256+k]  = bf(Wv[k*256+p])
// seg4 [212992,213248):  fold a into W0: ahs/ahd[h*64+d]
__global__ __launch_bounds__(256) void k_prep(const float* __restrict__ Wp, const float* __restrict__ W0,
                                              const float* __restrict__ W1, const float* __restrict__ Wv,
                                              const float* __restrict__ as0, const float* __restrict__ ad0,
                                              unsigned short* __restrict__ WpT, unsigned short* __restrict__ W0BD,
                                              unsigned short* __restrict__ W1T, unsigned short* __restrict__ WvT,
                                              float* __restrict__ ahs, float* __restrict__ ahd){
  int idx = blockIdx.x*256 + threadIdx.x;
  if (idx < 16384){
    int k = idx >> 6, p = idx & 63;
    WpT[p*256 + k] = f2bf(Wp[idx]);
  } else if (idx < 81920){
    int i = idx - 16384;
    int p = i >> 8, k = i & 255;
    float v = ((p>>6)==(k>>6)) ? W0[(k&63)*256 + p] : 0.f;
    W0BD[i] = f2bf(v);
  } else if (idx < 147456){
    int i = idx - 81920; int k = i >> 8, p = i & 255;
    W1T[p*256 + k] = f2bf(W1[i]);
  } else if (idx < 212992){
    int i = idx - 147456; int k = i >> 8, p = i & 255;
    WvT[p*256 + k] = f2bf(Wv[i]);
  } else if (idx < 213248){
    int i = idx - 212992;
    int h = i >> 6, d = i & 63;
    float ss = 0.f, sd = 0.f;
    for (int j=0;j<64;j++){
      float w = W0[d*256 + h*64 + j];
      ss += w * as0[h*64 + j];
      sd += w * ad0[h*64 + j];
    }
    ahs[i] = ss; ahd[i] = sd;
  }
}

// ---------------- h0 = x @ Wp + bp : direct-fragment MFMA GEMM, no LDS, no barriers ----------------
// A f32 (M=4N,256); one wave owns 64 rows x full 64 cols. De-interleaves row=(n*4+t).
__global__ __launch_bounds__(256) void k_h0(const float* __restrict__ A,
                                            const unsigned short* __restrict__ Bt,
                                            const float* __restrict__ bias,
                                            unsigned short* __restrict__ C, int M, int Nn){
  int wid = blockIdx.x*4 + (threadIdx.x >> 6);
  int m0 = wid * 64;
  if (m0 >= M) return;
  int lane = threadIdx.x & 63;
  int lr = lane & 15, g = lane >> 4, lk = g*8;
  const float* Arow[4];
  #pragma unroll
  for (int m=0;m<4;m++){
    int row = m0 + m*16 + lr;
    if (row > M-1) row = M-1;
    Arow[m] = A + (size_t)row*256 + lk;
  }
  const unsigned short* Bb = Bt + (size_t)lr*256 + lk;
  f32x4 acc[4][4];
  #pragma unroll
  for (int m=0;m<4;m++)
    #pragma unroll
    for (int n=0;n<4;n++)
      #pragma unroll
      for (int j=0;j<4;j++) acc[m][n][j] = 0.f;

  #pragma unroll 2
  for (int ks=0; ks<8; ks++){
    int k0 = ks*32;
    short8 bfr[4];
    #pragma unroll
    for (int n=0;n<4;n++)
      bfr[n] = *(const short8*)(Bb + (size_t)n*16*256 + k0);
    short8 afr[4];
    #pragma unroll
    for (int m=0;m<4;m++){
      float4 u = *(const float4*)(Arow[m] + k0);
      float4 w = *(const float4*)(Arow[m] + k0 + 4);
      afr[m][0]=(short)f2bf(u.x); afr[m][1]=(short)f2bf(u.y);
      afr[m][2]=(short)f2bf(u.z); afr[m][3]=(short)f2bf(u.w);
      afr[m][4]=(short)f2bf(w.x); afr[m][5]=(short)f2bf(w.y);
      afr[m][6]=(short)f2bf(w.z); afr[m][7]=(short)f2bf(w.w);
    }
    #pragma unroll
    for (int m=0;m<4;m++)
      #pragma unroll
      for (int n=0;n<4;n++)
        acc[m][n] = __builtin_amdgcn_mfma_f32_16x16x32_bf16(afr[m], bfr[n], acc[m][n], 0,0,0);
  }
  #pragma unroll
  for (int n=0;n<4;n++){
    int col = n*16 + lr;
    float bcol = bias[col];
    #pragma unroll
    for (int m=0;m<4;m++){
      #pragma unroll
      for (int j=0;j<4;j++){
        int row = m0 + m*16 + g*4 + j;
        if (row < M){
          int t = row & 3, nn = row >> 2;
          C[(size_t)t*Nn*64 + (size_t)nn*64 + col] = f2bf(acc[m][n][j] + bcol);
        }
      }
    }
  }
}

// ---------------- MFMA GEMM, P=256 full-width: 512 threads, BM=128, BN=256 ----------------
template<int K, bool BIAS, bool CF32, bool ELU>
__global__ __launch_bounds__(512) void k_gemm_p256(const unsigned short* __restrict__ A,
                                                   const unsigned short* __restrict__ Bt,
                                                   const float* __restrict__ bias,
                                                   void* __restrict__ Cv, int M){
  constexpr int BK = 64, PAD = 8;
  __shared__ unsigned short Als[128][BK+PAD];
  __shared__ unsigned short Bls[256][BK+PAD];
  int tid = threadIdx.x;
  int m0  = blockIdx.x * 128;
  int wave = tid >> 6, lane = tid & 63;
  int wr = wave & 3, wc = wave >> 2;      // 4 row-groups x 2 col-groups
  int lr = lane & 15, lk = (lane >> 4) * 8;
  f32x4 acc[2][8];
  #pragma unroll
  for (int m=0;m<2;m++)
    #pragma unroll
    for (int n=0;n<8;n++)
      #pragma unroll
      for (int j=0;j<4;j++) acc[m][n][j] = 0.f;

  for (int k0 = 0; k0 < K; k0 += BK){
    #pragma unroll
    for (int i=0;i<2;i++){
      int idx = tid + i*512;
      int r = idx >> 3, ch = (idx & 7)*8;
      int row = m0 + r;
      uint4 v = make_uint4(0,0,0,0);
      if (row < M) v = *(const uint4*)(A + (size_t)row*K + k0 + ch);
      *(uint4*)(&Als[r][ch]) = v;
    }
    #pragma unroll
    for (int i=0;i<4;i++){
      int idx = tid + i*512;
      int r = idx >> 3, ch = (idx & 7)*8;
      *(uint4*)(&Bls[r][ch]) = *(const uint4*)(Bt + (size_t)r*K + k0 + ch);
    }
    __syncthreads();
    #pragma unroll
    for (int ks=0; ks<2; ks++){
      short8 afr[2], bfr[8];
      #pragma unroll
      for (int m=0;m<2;m++)
        afr[m] = *(const short8*)(&Als[wr*32 + m*16 + lr][ks*32 + lk]);
      #pragma unroll
      for (int n=0;n<8;n++)
        bfr[n] = *(const short8*)(&Bls[wc*128 + n*16 + lr][ks*32 + lk]);
      #pragma unroll
      for (int m=0;m<2;m++)
        #pragma unroll
        for (int n=0;n<8;n++)
          acc[m][n] = __builtin_amdgcn_mfma_f32_16x16x32_bf16(afr[m], bfr[n], acc[m][n], 0,0,0);
    }
    __syncthreads();
  }
  #pragma unroll
  for (int m=0;m<2;m++){
    #pragma unroll
    for (int n=0;n<8;n++){
      int col = wc*128 + n*16 + lr;
      float bcol = BIAS ? bias[col] : 0.f;
      #pragma unroll
      for (int j=0;j<4;j++){
        int row = m0 + wr*32 + m*16 + (lane>>4)*4 + j;
        if (row < M){
          float v = acc[m][n][j] + bcol;
          if (ELU) v = (v > 0.f) ? v : (expf(v) - 1.f);
          if (CF32) ((float*)Cv)[(size_t)row*256 + col] = v;
          else      ((unsigned short*)Cv)[(size_t)row*256 + col] = f2bf(v);
        }
      }
    }
  }
}

// ---------------- layer-0 logits from h0 (64-dim rows, batched over t via M=T*N) ----------------
__global__ __launch_bounds__(256) void k_esd0(const unsigned short* __restrict__ h0,
                                              const float* __restrict__ ahs, const float* __restrict__ ahd,
                                              float* __restrict__ e_s, float* __restrict__ e_d, int M){
  int n = blockIdx.x*4 + (threadIdx.x >> 6);
  if (n >= M) return;
  int lane = threadIdx.x & 63;
  int h = lane >> 4, l4 = (lane & 15)*4;
  uint2 v = *(const uint2*)(h0 + (size_t)n*64 + l4);
  float v0 = bf2f(v.x & 0xffffu), v1 = bf2f(v.x >> 16);
  float v2 = bf2f(v.y & 0xffffu), v3 = bf2f(v.y >> 16);
  float4 as = *(const float4*)(ahs + h*64 + l4);
  float4 ad = *(const float4*)(ahd + h*64 + l4);
  float ps = v0*as.x + v1*as.y + v2*as.z + v3*as.w;
  float pd = v0*ad.x + v1*ad.y + v2*ad.z + v3*ad.w;
  #pragma unroll
  for (int off=1; off<16; off<<=1){ ps += __shfl_xor(ps,off); pd += __shfl_xor(pd,off); }
  if ((lane & 15) == 0){
    e_s[n*4+h] = ps; e_d[n*4+h] = pd;
  }
}

// ---------------- layer-0 aggregation, batched over t (128B gathers on 64-dim h0) ----------------
__global__ __launch_bounds__(256) void k_agg0(const unsigned short* __restrict__ h0all,
                                              const float* __restrict__ e_s, const float* __restrict__ e_d,
                                              const int* __restrict__ rowptr, const int* __restrict__ colidx,
                                              unsigned short* __restrict__ agg, int N, int TN){
  int g = blockIdx.x*4 + (threadIdx.x >> 6);
  if (g >= TN) return;
  int t = g / N, n = g - t*N;
  int base = t * N;
  int lane = threadIdx.x & 63;
  int h = lane >> 4, l4 = (lane & 15)*4;
  int s0 = rowptr[n], s1 = rowptr[n+1];
  float ed = e_d[(size_t)g*4 + h];
  float z = 0.f;
  float a0=0.f, a1=0.f, a2=0.f, a3=0.f;
  const unsigned short* h0t = h0all + (size_t)base*64;
  const float* est = e_s + (size_t)base*4;
  for (int i = s0; i < s1; ++i){
    int s = colidx[i];
    float e = est[s*4 + h] + ed;
    e = (e > 0.f) ? e : NEG_SLOPE*e;
    float w = expf(e);
    z += w;
    uint2 v = *(const uint2*)(h0t + (size_t)s*64 + l4);
    a0 += w * bf2f(v.x & 0xffffu);
    a1 += w * bf2f(v.x >> 16);
    a2 += w * bf2f(v.y & 0xffffu);
    a3 += w * bf2f(v.y >> 16);
  }
  float inv = 1.f / (z + 1e-16f);
  unsigned lo = (unsigned)f2bf(a0*inv) | ((unsigned)f2bf(a1*inv) << 16);
  unsigned hi = (unsigned)f2bf(a2*inv) | ((unsigned)f2bf(a3*inv) << 16);
  *(uint2*)(agg + (size_t)g*256 + h*64 + l4) = make_uint2(lo, hi);
}

// ---------------- layer-1 logits (256-dim rows, batched via M=T*N) ----------------
__global__ __launch_bounds__(256) void k_esd(const unsigned short* __restrict__ hp,
                                             const float* __restrict__ a_s, const float* __restrict__ a_d,
                                             float* __restrict__ e_s, float* __restrict__ e_d, int M){
  int n = blockIdx.x*4 + (threadIdx.x >> 6);
  if (n >= M) return;
  int lane = threadIdx.x & 63;
  uint2 v = *(const uint2*)(hp + (size_t)n*256 + lane*4);
  float v0 = bf2f(v.x & 0xffffu), v1 = bf2f(v.x >> 16);
  float v2 = bf2f(v.y & 0xffffu), v3 = bf2f(v.y >> 16);
  float4 as = *(const float4*)(a_s + lane*4);
  float4 ad = *(const float4*)(a_d + lane*4);
  float ps = v0*as.x + v1*as.y + v2*as.z + v3*as.w;
  float pd = v0*ad.x + v1*ad.y + v2*ad.z + v3*ad.w;
  #pragma unroll
  for (int off=1; off<16; off<<=1){ ps += __shfl_xor(ps,off); pd += __shfl_xor(pd,off); }
  if ((lane & 15) == 0){
    int h = lane >> 4;
    e_s[n*4+h] = ps; e_d[n*4+h] = pd;
  }
}

// ---------------- layer-1 aggregation, batched over t (512B gathers) + bias + ELU ----------------
__global__ __launch_bounds__(256) void k_agg(const unsigned short* __restrict__ hpall,
                                             const float* __restrict__ e_s, const float* __restrict__ e_d,
                                             const int* __restrict__ rowptr, const int* __restrict__ colidx,
                                             const float* __restrict__ bias, unsigned short* __restrict__ outb,
                                             int N, int TN){
  int g = blockIdx.x*4 + (threadIdx.x >> 6);
  if (g >= TN) return;
  int t = g / N, n = g - t*N;
  int base = t * N;
  int lane = threadIdx.x & 63;
  int h = lane >> 4;
  int s0 = rowptr[n], s1 = rowptr[n+1];
  float ed = e_d[(size_t)g*4 + h];
  float z = 0.f;
  float a0=0.f, a1=0.f, a2=0.f, a3=0.f;
  const unsigned short* hpt = hpall + (size_t)base*256;
  const float* est = e_s + (size_t)base*4;
  for (int i = s0; i < s1; ++i){
    int s = colidx[i];
    float e = est[s*4 + h] + ed;
    e = (e > 0.f) ? e : NEG_SLOPE*e;
    float w = expf(e);
    z += w;
    uint2 v = *(const uint2*)(hpt + (size_t)s*256 + lane*4);
    a0 += w * bf2f(v.x & 0xffffu);
    a1 += w * bf2f(v.x >> 16);
    a2 += w * bf2f(v.y & 0xffffu);
    a3 += w * bf2f(v.y >> 16);
  }
  float inv = 1.f / (z + 1e-16f);
  float4 b = *(const float4*)(bias + lane*4);
  float o0 = a0*inv + b.x, o1 = a1*inv + b.y, o2 = a2*inv + b.z, o3 = a3*inv + b.w;
  o0 = (o0 > 0.f) ? o0 : (expf(o0) - 1.f);
  o1 = (o1 > 0.f) ? o1 : (expf(o1) - 1.f);
  o2 = (o2 > 0.f) ? o2 : (expf(o2) - 1.f);
  o3 = (o3 > 0.f) ? o3 : (expf(o3) - 1.f);
  unsigned lo = (unsigned)f2bf(o0) | ((unsigned)f2bf(o1) << 16);
  unsigned hi = (unsigned)f2bf(o2) | ((unsigned)f2bf(o3) << 16);
  *(uint2*)(outb + (size_t)g*256 + lane*4) = make_uint2(lo, hi);
}

// ---------------- column sums, batched: 64 chunks per t ----------------
__global__ __launch_bounds__(256) void k_colsum(const unsigned short* __restrict__ emb, float* __restrict__ sums, int N){
  __shared__ float red[8][256];
  int tid = threadIdx.x;
  int t = blockIdx.x >> 6, chunk = blockIdx.x & 63;
  int rows_per = (N + 63) / 64;
  int r0 = chunk * rows_per;
  int r1 = min(N, r0 + rows_per);
  const unsigned short* base = emb + (size_t)t*N*256;
  int c0 = (tid & 31)*8, rg = tid >> 5;
  float s[8] = {0,0,0,0,0,0,0,0};
  for (int r = r0 + rg; r < r1; r += 8){
    uint4 v = *(const uint4*)(base + (size_t)r*256 + c0);
    s[0] += bf2f(v.x & 0xffffu); s[1] += bf2f(v.x >> 16);
    s[2] += bf2f(v.y & 0xffffu); s[3] += bf2f(v.y >> 16);
    s[4] += bf2f(v.z & 0xffffu); s[5] += bf2f(v.z >> 16);
    s[6] += bf2f(v.w & 0xffffu); s[7] += bf2f(v.w >> 16);
  }
  #pragma unroll
  for (int j=0;j<8;j++) red[rg][c0+j] = s[j];
  __syncthreads();
  float tot = 0.f;
  #pragma unroll
  for (int g=0;g<8;g++) tot += red[g][tid];
  atomicAdd(&sums[t*256 + tid], tot);
}

// ---------------- temporal attention weights (tiny) ----------------
__global__ __launch_bounds__(256) void k_attn(const float* __restrict__ sum_emb,
                                              const float* __restrict__ Wq, const float* __restrict__ bq,
                                              const float* __restrict__ Wk, const float* __restrict__ bk,
                                              float* __restrict__ aw, int N){
  __shared__ float mean_s[4][256];
  __shared__ float red[256];
  __shared__ float scores_s[4];
  int j = threadIdx.x;
  float invN = 1.0f/(float)N;
  #pragma unroll
  for (int t=0;t<4;t++) mean_s[t][j] = sum_emb[t*256+j]*invN;
  __syncthreads();
  float q3 = bq[j];
  float kt0=bk[j], kt1=bk[j], kt2=bk[j], kt3=bk[j];
  for (int m=0;m<256;m++){
    float wq = Wq[m*256+j];
    float wk = Wk[m*256+j];
    float m0 = mean_s[0][m], m1 = mean_s[1][m], m2 = mean_s[2][m], m3 = mean_s[3][m];
    q3  += m3*wq;
    kt0 += m0*wk; kt1 += m1*wk; kt2 += m2*wk; kt3 += m3*wk;
  }
  float kts0=kt0, kts1=kt1, kts2=kt2, kts3=kt3;
  #pragma unroll
  for (int t=0;t<4;t++){
    float ktv = (t==0)?kts0:((t==1)?kts1:((t==2)?kts2:kts3));
    red[j] = q3*ktv;
    __syncthreads();
    for (int off=128; off>0; off>>=1){
      if (j < off) red[j] += red[j+off];
      __syncthreads();
    }
    if (j==0) scores_s[t] = red[0]*(1.0f/16.0f);   // /sqrt(256)
    __syncthreads();
  }
  if (j==0){
    float mx = fmaxf(fmaxf(scores_s[0],scores_s[1]),fmaxf(scores_s[2],scores_s[3]));
    float w0 = expf(scores_s[0]-mx), w1 = expf(scores_s[1]-mx),
          w2 = expf(scores_s[2]-mx), w3 = expf(scores_s[3]-mx);
    float s = w0+w1+w2+w3;
    aw[0]=w0/s; aw[1]=w1/s; aw[2]=w2/s; aw[3]=w3/s;
  }
}

// ---------------- temporal combine: comb = sum_t aw[t]*embs[t] (bf16 in/out) ----------------
__global__ __launch_bounds__(256) void k_combine(const unsigned short* __restrict__ embs,
                                                 const float* __restrict__ awp,
                                                 unsigned short* __restrict__ comb, int N){
  int i = blockIdx.x*256 + threadIdx.x;          // 8 elements per thread
  int total = N*32;
  if (i >= total) return;
  size_t o = (size_t)i*8;
  size_t sl = (size_t)N*256;
  float a0=awp[0], a1=awp[1], a2=awp[2], a3=awp[3];
  uint4 v0 = *(const uint4*)(embs + o);
  uint4 v1 = *(const uint4*)(embs + o + sl);
  uint4 v2 = *(const uint4*)(embs + o + 2*sl);
  uint4 v3 = *(const uint4*)(embs + o + 3*sl);
  uint4 r;
  unsigned w[4];
  const unsigned* p0=&v0.x; const unsigned* p1=&v1.x; const unsigned* p2=&v2.x; const unsigned* p3=&v3.x;
  #pragma unroll
  for (int k=0;k<4;k++){
    float lo = a0*bf2f(p0[k]&0xffffu) + a1*bf2f(p1[k]&0xffffu) + a2*bf2f(p2[k]&0xffffu) + a3*bf2f(p3[k]&0xffffu);
    float hi = a0*bf2f(p0[k]>>16)     + a1*bf2f(p1[k]>>16)     + a2*bf2f(p2[k]>>16)     + a3*bf2f(p3[k]>>16);
    w[k] = (unsigned)f2bf(lo) | ((unsigned)f2bf(hi) << 16);
  }
  r.x=w[0]; r.y=w[1]; r.z=w[2]; r.w=w[3];
  *(uint4*)(comb + o) = r;
}

extern "C" void kernel_launch(void* const* d_in, const int* in_sizes, int n_in,
                              void* d_out, int out_size, void* d_ws, size_t ws_size,
                              hipStream_t stream){
  (void)n_in; (void)out_size; (void)ws_size;
  const float* x   = (const float*)d_in[0];
  const int*   ei  = (const int*)d_in[1];
  const float* Wp  = (const float*)d_in[2];
  const float* bp  = (const float*)d_in[3];
  const float* W0  = (const float*)d_in[4];
  const float* as0 = (const float*)d_in[5];
  const float* ad0 = (const float*)d_in[6];
  const float* b0  = (const float*)d_in[7];
  const float* W1  = (const float*)d_in[8];
  const float* as1 = (const float*)d_in[9];
  const float* ad1 = (const float*)d_in[10];
  const float* b1  = (const float*)d_in[11];
  const float* Wq  = (const float*)d_in[12];
  const float* bq  = (const float*)d_in[13];
  const float* Wk  = (const float*)d_in[14];
  const float* bk  = (const float*)d_in[15];
  const float* Wv  = (const float*)d_in[16];
  const float* bv  = (const float*)d_in[17];
  float* out = (float*)d_out;

  const int T = 4, FIN = 256;
  const int N = in_sizes[0] / (T*FIN);
  const int E = in_sizes[1] / 2;
  const int TN = T*N;
  const int* src = ei;
  const int* dst = ei + E;

  char* ws = (char*)d_ws;
  size_t cur = 0;
  auto alloc = [&](size_t bytes)->void*{
    void* p = ws + cur;
    cur += (bytes + 255) & ~(size_t)255;
    return p;
  };
  unsigned short* h0all = (unsigned short*)alloc((size_t)TN*64*2);    // [T][N][64]
  unsigned short* bufA  = (unsigned short*)alloc((size_t)TN*256*2);   // agg0_all, then hp_all
  unsigned short* bufB  = (unsigned short*)alloc((size_t)TN*256*2);   // h1_all, then comb
  unsigned short* embs  = (unsigned short*)alloc((size_t)TN*256*2);   // [T][N][256]
  float* e_s    = (float*)alloc((size_t)TN*4*4);
  float* e_d    = (float*)alloc((size_t)TN*4*4);
  float* sume   = (float*)alloc(4*256*4);
  float* aw     = (float*)alloc(256);
  float* ah0s   = (float*)alloc(256*4);
  float* ah0d   = (float*)alloc(256*4);
  int*   rowptr = (int*)alloc((size_t)(N+1)*4);
  int*   deg    = (int*)alloc((size_t)N*4);
  int*   pos    = (int*)alloc((size_t)N*4);
  int*   colidx = (int*)alloc((size_t)(E+N)*4);
  unsigned short* WpT  = (unsigned short*)alloc((size_t)64*256*2);
  unsigned short* W0BD = (unsigned short*)alloc((size_t)256*256*2);
  unsigned short* W1T  = (unsigned short*)alloc((size_t)256*256*2);
  unsigned short* WvT  = (unsigned short*)alloc((size_t)256*256*2);

  int nb256 = (N+255)/256;
  int nbE   = (E+255)/256;
  int gm4   = (TN+127)/128;        // batched P=256 GEMM grid
  int gmN   = (N+127)/128;
  int gagg  = (TN+3)/4;

  // CSR build (graph static across t and layers)
  k_deg_init<<<nb256,256,0,stream>>>(deg, N);
  k_deg_count<<<nbE,256,0,stream>>>(dst, E, deg);
  k_scan<<<1,1024,0,stream>>>(deg, rowptr, N);
  k_pos_self<<<nb256,256,0,stream>>>(rowptr, pos, colidx, N);
  k_fill_edges<<<nbE,256,0,stream>>>(src, dst, E, pos, colidx);
  hipMemsetAsync(sume, 0, 4*256*4, stream);

  // all weight prep in one launch
  k_prep<<<833,256,0,stream>>>(Wp, W0, W1, Wv, as0, ad0, WpT, W0BD, W1T, WvT, ah0s, ah0d);

  // h0 for all 4 timesteps, direct-fragment GEMM (x rows are (n,t) interleaved)
  k_h0<<<(TN/64+3)/4 + 1,256,0,stream>>>(x, WpT, bp, h0all, TN, N);

  // GAT layer 0, batched over t (hp0 never materialized)
  k_esd0<<<gagg,256,0,stream>>>(h0all, ah0s, ah0d, e_s, e_d, TN);
  k_agg0<<<gagg,256,0,stream>>>(h0all, e_s, e_d, rowptr, colidx, bufA, N, TN);
  // h1 = ELU(agg0 @ W0_blockdiag + b0), batched
  k_gemm_p256<256,true,false,true><<<gm4,512,0,stream>>>(bufA, W0BD, b0, bufB, TN);
  // GAT layer 1, batched
  k_gemm_p256<256,false,false,false><<<gm4,512,0,stream>>>(bufB, W1T, nullptr, bufA, TN);
  k_esd<<<gagg,256,0,stream>>>(bufA, as1, ad1, e_s, e_d, TN);
  k_agg<<<gagg,256,0,stream>>>(bufA, e_s, e_d, rowptr, colidx, b1, embs, N, TN);
  // node-mean numerators for temporal attention (one launch, 64 chunks x 4 t)
  k_colsum<<<256,256,0,stream>>>(embs, sume, N);

  // temporal attention weights, combine, fused V-projection
  k_attn<<<1,256,0,stream>>>(sume, Wq, bq, Wk, bk, aw, N);
  k_combine<<<(N*32+255)/256,256,0,stream>>>(embs, aw, bufB, N);
  k_gemm_p256<256,true,true,false><<<gmN,512,0,stream>>>(bufB, WvT, bv, out, N);
}

// Round 6
// 561.017 us; speedup vs baseline: 3.1423x; 1.1424x over previous
//
#include <hip/hip_runtime.h>
#include <math.h>

#define NEG_SLOPE 0.2f

typedef __attribute__((ext_vector_type(8))) short short8;
typedef __attribute__((ext_vector_type(4))) float f32x4;

__device__ inline unsigned short f2bf(float f){
  union { float f; unsigned u; } v; v.f = f;
  unsigned r = v.u + 0x7fffu + ((v.u >> 16) & 1u);
  return (unsigned short)(r >> 16);
}
__device__ inline float bf2f(unsigned u){
  union { unsigned u; float f; } v; v.u = u << 16; return v.f;
}

// ---------------- CSR build ----------------
__global__ __launch_bounds__(256) void k_deg_init(int* deg, int N){
  int i = blockIdx.x*256 + threadIdx.x;
  if (i < N) deg[i] = 1;               // self-loop
}
__global__ __launch_bounds__(256) void k_deg_count(const int* __restrict__ dst, int E, int* __restrict__ deg){
  int i = blockIdx.x*256 + threadIdx.x;
  if (i < E) atomicAdd(&deg[dst[i]], 1);
}
// 3-phase scan: block scan -> top scan -> add back (replaces serial 700-barrier scan)
__global__ __launch_bounds__(256) void k_scan_blk(const int* __restrict__ deg, int* __restrict__ rowptr,
                                                  int* __restrict__ bsum, int N){
  __shared__ int ws[4];
  int tid = threadIdx.x;
  int i = blockIdx.x*256 + tid;
  int v = (i < N) ? deg[i] : 0;
  int lane = tid & 63, w = tid >> 6;
  int s = v;
  #pragma unroll
  for (int off=1; off<64; off<<=1){
    int u = __shfl_up(s, off);
    if (lane >= off) s += u;
  }
  if (lane == 63) ws[w] = s;
  __syncthreads();
  int woff = 0;
  #pragma unroll
  for (int k=0;k<4;k++) if (k < w) woff += ws[k];
  int incl = s + woff;
  if (i < N) rowptr[i] = incl - v;      // exclusive within block
  if (tid == 255) bsum[blockIdx.x] = incl;
}
__global__ __launch_bounds__(256) void k_scan_top(int* __restrict__ bsum, int nb, int* __restrict__ rowptrN){
  __shared__ int buf[256];
  int tid = threadIdx.x;
  int v = (tid < nb) ? bsum[tid] : 0;
  buf[tid] = v;
  __syncthreads();
  for (int off=1; off<256; off<<=1){
    int add = (tid >= off) ? buf[tid-off] : 0;
    __syncthreads();
    buf[tid] += add;
    __syncthreads();
  }
  if (tid < nb) bsum[tid] = buf[tid] - v;   // exclusive block offsets
  if (tid == 0) rowptrN[0] = buf[255];      // grand total
}
__global__ __launch_bounds__(256) void k_scan_add(int* __restrict__ rowptr, const int* __restrict__ bsum, int N){
  int i = blockIdx.x*256 + threadIdx.x;
  if (i < N) rowptr[i] += bsum[blockIdx.x];
}
__global__ __launch_bounds__(256) void k_pos_self(const int* __restrict__ rowptr, int* __restrict__ pos,
                                                  int* __restrict__ colidx, int N){
  int i = blockIdx.x*256 + threadIdx.x;
  if (i < N){
    int r = rowptr[i];
    colidx[r] = i;
    pos[i] = r + 1;
  }
}
__global__ __launch_bounds__(256) void k_fill_edges(const int* __restrict__ src, const int* __restrict__ dst,
                                                    int E, int* __restrict__ pos, int* __restrict__ colidx){
  int i = blockIdx.x*256 + threadIdx.x;
  if (i < E){
    int d = dst[i];
    colidx[atomicAdd(&pos[d],1)] = src[i];
  }
}

// ---------------- all weight prep in one launch ----------------
// seg0 [0,16384):       WpT[p*256+k]  = bf(Wp[k*64+p])
// seg1 [16384,32768):   W0T4[h][p][k] = bf(W0[k*256 + h*64 + p])   (per-head 64x64, transposed)
// seg2 [32768,98304):   W1T[p*256+k]  = bf(W1[k*256+p])
// seg3 [98304,163840):  WvT[p*256+k]  = bf(Wv[k*256+p])
// seg4 [163840,164096): fold a into W0: ahs/ahd[h*64+d]
__global__ __launch_bounds__(256) void k_prep(const float* __restrict__ Wp, const float* __restrict__ W0,
                                              const float* __restrict__ W1, const float* __restrict__ Wv,
                                              const float* __restrict__ as0, const float* __restrict__ ad0,
                                              unsigned short* __restrict__ WpT, unsigned short* __restrict__ W0T4,
                                              unsigned short* __restrict__ W1T, unsigned short* __restrict__ WvT,
                                              float* __restrict__ ahs, float* __restrict__ ahd){
  int idx = blockIdx.x*256 + threadIdx.x;
  if (idx < 16384){
    int k = idx >> 6, p = idx & 63;
    WpT[p*256 + k] = f2bf(Wp[idx]);
  } else if (idx < 32768){
    int i = idx - 16384;
    int h = i >> 12, r = i & 4095, p = r >> 6, k = r & 63;
    W0T4[i] = f2bf(W0[k*256 + h*64 + p]);
  } else if (idx < 98304){
    int i = idx - 32768; int k = i >> 8, p = i & 255;
    W1T[p*256 + k] = f2bf(W1[i]);
  } else if (idx < 163840){
    int i = idx - 98304; int k = i >> 8, p = i & 255;
    WvT[p*256 + k] = f2bf(Wv[i]);
  } else if (idx < 164096){
    int i = idx - 163840;
    int h = i >> 6, d = i & 63;
    float ss = 0.f, sd = 0.f;
    for (int j=0;j<64;j++){
      float w = W0[d*256 + h*64 + j];
      ss += w * as0[h*64 + j];
      sd += w * ad0[h*64 + j];
    }
    ahs[i] = ss; ahd[i] = sd;
  }
}

// ---------------- h0 = x @ Wp + bp : direct-fragment MFMA GEMM, no LDS, no barriers ----------------
__global__ __launch_bounds__(256) void k_h0(const float* __restrict__ A,
                                            const unsigned short* __restrict__ Bt,
                                            const float* __restrict__ bias,
                                            unsigned short* __restrict__ C, int M, int Nn){
  int wid = blockIdx.x*4 + (threadIdx.x >> 6);
  int m0 = wid * 64;
  if (m0 >= M) return;
  int lane = threadIdx.x & 63;
  int lr = lane & 15, g = lane >> 4, lk = g*8;
  const float* Arow[4];
  #pragma unroll
  for (int m=0;m<4;m++){
    int row = m0 + m*16 + lr;
    if (row > M-1) row = M-1;
    Arow[m] = A + (size_t)row*256 + lk;
  }
  const unsigned short* Bb = Bt + (size_t)lr*256 + lk;
  f32x4 acc[4][4];
  #pragma unroll
  for (int m=0;m<4;m++)
    #pragma unroll
    for (int n=0;n<4;n++)
      #pragma unroll
      for (int j=0;j<4;j++) acc[m][n][j] = 0.f;

  #pragma unroll 2
  for (int ks=0; ks<8; ks++){
    int k0 = ks*32;
    short8 bfr[4];
    #pragma unroll
    for (int n=0;n<4;n++)
      bfr[n] = *(const short8*)(Bb + (size_t)n*16*256 + k0);
    short8 afr[4];
    #pragma unroll
    for (int m=0;m<4;m++){
      float4 u = *(const float4*)(Arow[m] + k0);
      float4 w = *(const float4*)(Arow[m] + k0 + 4);
      afr[m][0]=(short)f2bf(u.x); afr[m][1]=(short)f2bf(u.y);
      afr[m][2]=(short)f2bf(u.z); afr[m][3]=(short)f2bf(u.w);
      afr[m][4]=(short)f2bf(w.x); afr[m][5]=(short)f2bf(w.y);
      afr[m][6]=(short)f2bf(w.z); afr[m][7]=(short)f2bf(w.w);
    }
    #pragma unroll
    for (int m=0;m<4;m++)
      #pragma unroll
      for (int n=0;n<4;n++)
        acc[m][n] = __builtin_amdgcn_mfma_f32_16x16x32_bf16(afr[m], bfr[n], acc[m][n], 0,0,0);
  }
  #pragma unroll
  for (int n=0;n<4;n++){
    int col = n*16 + lr;
    float bcol = bias[col];
    #pragma unroll
    for (int m=0;m<4;m++){
      #pragma unroll
      for (int j=0;j<4;j++){
        int row = m0 + m*16 + g*4 + j;
        if (row < M){
          int t = row & 3, nn = row >> 2;
          C[(size_t)t*Nn*64 + (size_t)nn*64 + col] = f2bf(acc[m][n][j] + bcol);
        }
      }
    }
  }
}

// ---------------- layer-0 per-head GEMM: h1 = ELU(agg0 @ blockdiag(W0) + b0), K=64, no LDS ----------------
__global__ __launch_bounds__(256) void k_gat0(const unsigned short* __restrict__ A,
                                              const unsigned short* __restrict__ W0T4,
                                              const float* __restrict__ b0,
                                              unsigned short* __restrict__ C, int M){
  int h = blockIdx.y;
  int wid = blockIdx.x*4 + (threadIdx.x >> 6);
  int m0 = wid * 64;
  if (m0 >= M) return;
  int lane = threadIdx.x & 63;
  int lr = lane & 15, g = lane >> 4, lk = g*8;
  const unsigned short* Wh = W0T4 + (size_t)h*64*64;
  f32x4 acc[4][4];
  #pragma unroll
  for (int m=0;m<4;m++)
    #pragma unroll
    for (int n=0;n<4;n++)
      #pragma unroll
      for (int j=0;j<4;j++) acc[m][n][j] = 0.f;

  #pragma unroll
  for (int ks=0; ks<2; ks++){
    short8 bfr[4], afr[4];
    #pragma unroll
    for (int n=0;n<4;n++)
      bfr[n] = *(const short8*)(Wh + (size_t)(n*16+lr)*64 + ks*32 + lk);
    #pragma unroll
    for (int m=0;m<4;m++){
      int row = m0 + m*16 + lr;
      if (row > M-1) row = M-1;
      afr[m] = *(const short8*)(A + (size_t)row*256 + h*64 + ks*32 + lk);
    }
    #pragma unroll
    for (int m=0;m<4;m++)
      #pragma unroll
      for (int n=0;n<4;n++)
        acc[m][n] = __builtin_amdgcn_mfma_f32_16x16x32_bf16(afr[m], bfr[n], acc[m][n], 0,0,0);
  }
  #pragma unroll
  for (int n=0;n<4;n++){
    int col = h*64 + n*16 + lr;
    float bcol = b0[col];
    #pragma unroll
    for (int m=0;m<4;m++){
      #pragma unroll
      for (int j=0;j<4;j++){
        int row = m0 + m*16 + g*4 + j;
        if (row < M){
          float v = acc[m][n][j] + bcol;
          v = (v > 0.f) ? v : (__expf(v) - 1.f);
          C[(size_t)row*256 + col] = f2bf(v);
        }
      }
    }
  }
}

// ---------------- MFMA GEMM, P=256 full-width: 512 threads, BM=128, BN=256 ----------------
template<int K, bool BIAS, bool CF32>
__global__ __launch_bounds__(512) void k_gemm_p256(const unsigned short* __restrict__ A,
                                                   const unsigned short* __restrict__ Bt,
                                                   const float* __restrict__ bias,
                                                   void* __restrict__ Cv, int M){
  constexpr int BK = 64, PAD = 8;
  __shared__ unsigned short Als[128][BK+PAD];
  __shared__ unsigned short Bls[256][BK+PAD];
  int tid = threadIdx.x;
  int m0  = blockIdx.x * 128;
  int wave = tid >> 6, lane = tid & 63;
  int wr = wave & 3, wc = wave >> 2;
  int lr = lane & 15, lk = (lane >> 4) * 8;
  f32x4 acc[2][8];
  #pragma unroll
  for (int m=0;m<2;m++)
    #pragma unroll
    for (int n=0;n<8;n++)
      #pragma unroll
      for (int j=0;j<4;j++) acc[m][n][j] = 0.f;

  for (int k0 = 0; k0 < K; k0 += BK){
    #pragma unroll
    for (int i=0;i<2;i++){
      int idx = tid + i*512;
      int r = idx >> 3, ch = (idx & 7)*8;
      int row = m0 + r;
      uint4 v = make_uint4(0,0,0,0);
      if (row < M) v = *(const uint4*)(A + (size_t)row*K + k0 + ch);
      *(uint4*)(&Als[r][ch]) = v;
    }
    #pragma unroll
    for (int i=0;i<4;i++){
      int idx = tid + i*512;
      int r = idx >> 3, ch = (idx & 7)*8;
      *(uint4*)(&Bls[r][ch]) = *(const uint4*)(Bt + (size_t)r*K + k0 + ch);
    }
    __syncthreads();
    #pragma unroll
    for (int ks=0; ks<2; ks++){
      short8 afr[2], bfr[8];
      #pragma unroll
      for (int m=0;m<2;m++)
        afr[m] = *(const short8*)(&Als[wr*32 + m*16 + lr][ks*32 + lk]);
      #pragma unroll
      for (int n=0;n<8;n++)
        bfr[n] = *(const short8*)(&Bls[wc*128 + n*16 + lr][ks*32 + lk]);
      #pragma unroll
      for (int m=0;m<2;m++)
        #pragma unroll
        for (int n=0;n<8;n++)
          acc[m][n] = __builtin_amdgcn_mfma_f32_16x16x32_bf16(afr[m], bfr[n], acc[m][n], 0,0,0);
    }
    __syncthreads();
  }
  #pragma unroll
  for (int m=0;m<2;m++){
    #pragma unroll
    for (int n=0;n<8;n++){
      int col = wc*128 + n*16 + lr;
      float bcol = BIAS ? bias[col] : 0.f;
      #pragma unroll
      for (int j=0;j<4;j++){
        int row = m0 + wr*32 + m*16 + (lane>>4)*4 + j;
        if (row < M){
          float v = acc[m][n][j] + bcol;
          if (CF32) ((float*)Cv)[(size_t)row*256 + col] = v;
          else      ((unsigned short*)Cv)[(size_t)row*256 + col] = f2bf(v);
        }
      }
    }
  }
}

// ---------------- layer-0 logits from h0 (batched over t via M=T*N) ----------------
__global__ __launch_bounds__(256) void k_esd0(const unsigned short* __restrict__ h0,
                                              const float* __restrict__ ahs, const float* __restrict__ ahd,
                                              float* __restrict__ e_s, float* __restrict__ e_d, int M){
  int n = blockIdx.x*4 + (threadIdx.x >> 6);
  if (n >= M) return;
  int lane = threadIdx.x & 63;
  int h = lane >> 4, l4 = (lane & 15)*4;
  uint2 v = *(const uint2*)(h0 + (size_t)n*64 + l4);
  float v0 = bf2f(v.x & 0xffffu), v1 = bf2f(v.x >> 16);
  float v2 = bf2f(v.y & 0xffffu), v3 = bf2f(v.y >> 16);
  float4 as = *(const float4*)(ahs + h*64 + l4);
  float4 ad = *(const float4*)(ahd + h*64 + l4);
  float ps = v0*as.x + v1*as.y + v2*as.z + v3*as.w;
  float pd = v0*ad.x + v1*ad.y + v2*ad.z + v3*ad.w;
  #pragma unroll
  for (int off=1; off<16; off<<=1){ ps += __shfl_xor(ps,off); pd += __shfl_xor(pd,off); }
  if ((lane & 15) == 0){
    e_s[n*4+h] = ps; e_d[n*4+h] = pd;
  }
}

// ---------------- layer-0 aggregation (128B gathers), grid (N/4, T) ----------------
__global__ __launch_bounds__(256) void k_agg0(const unsigned short* __restrict__ h0all,
                                              const float* __restrict__ e_s, const float* __restrict__ e_d,
                                              const int* __restrict__ rowptr, const int* __restrict__ colidx,
                                              unsigned short* __restrict__ agg, int N){
  int n = blockIdx.x*4 + (threadIdx.x >> 6);
  if (n >= N) return;
  int t = blockIdx.y;
  int g = t*N + n;
  int lane = threadIdx.x & 63;
  int h = lane >> 4, l4 = (lane & 15)*4;
  int s0 = rowptr[n], s1 = rowptr[n+1];
  float ed = e_d[(size_t)g*4 + h];
  float z = 0.f;
  float a0=0.f, a1=0.f, a2=0.f, a3=0.f;
  const unsigned short* h0t = h0all + (size_t)t*N*64;
  const float* est = e_s + (size_t)t*N*4;
  for (int i = s0; i < s1; ++i){
    int s = colidx[i];
    float e = est[s*4 + h] + ed;
    e = (e > 0.f) ? e : NEG_SLOPE*e;
    float w = __expf(e);
    z += w;
    uint2 v = *(const uint2*)(h0t + (size_t)s*64 + l4);
    a0 += w * bf2f(v.x & 0xffffu);
    a1 += w * bf2f(v.x >> 16);
    a2 += w * bf2f(v.y & 0xffffu);
    a3 += w * bf2f(v.y >> 16);
  }
  float inv = 1.f / (z + 1e-16f);
  unsigned lo = (unsigned)f2bf(a0*inv) | ((unsigned)f2bf(a1*inv) << 16);
  unsigned hi = (unsigned)f2bf(a2*inv) | ((unsigned)f2bf(a3*inv) << 16);
  *(uint2*)(agg + (size_t)g*256 + h*64 + l4) = make_uint2(lo, hi);
}

// ---------------- layer-1 logits (batched via M=T*N) ----------------
__global__ __launch_bounds__(256) void k_esd(const unsigned short* __restrict__ hp,
                                             const float* __restrict__ a_s, const float* __restrict__ a_d,
                                             float* __restrict__ e_s, float* __restrict__ e_d, int M){
  int n = blockIdx.x*4 + (threadIdx.x >> 6);
  if (n >= M) return;
  int lane = threadIdx.x & 63;
  uint2 v = *(const uint2*)(hp + (size_t)n*256 + lane*4);
  float v0 = bf2f(v.x & 0xffffu), v1 = bf2f(v.x >> 16);
  float v2 = bf2f(v.y & 0xffffu), v3 = bf2f(v.y >> 16);
  float4 as = *(const float4*)(a_s + lane*4);
  float4 ad = *(const float4*)(a_d + lane*4);
  float ps = v0*as.x + v1*as.y + v2*as.z + v3*as.w;
  float pd = v0*ad.x + v1*ad.y + v2*ad.z + v3*ad.w;
  #pragma unroll
  for (int off=1; off<16; off<<=1){ ps += __shfl_xor(ps,off); pd += __shfl_xor(pd,off); }
  if ((lane & 15) == 0){
    int h = lane >> 4;
    e_s[n*4+h] = ps; e_d[n*4+h] = pd;
  }
}

// ---------------- layer-1 aggregation (512B gathers) + bias + ELU, grid (N/4, T) ----------------
__global__ __launch_bounds__(256) void k_agg(const unsigned short* __restrict__ hpall,
                                             const float* __restrict__ e_s, const float* __restrict__ e_d,
                                             const int* __restrict__ rowptr, const int* __restrict__ colidx,
                                             const float* __restrict__ bias, unsigned short* __restrict__ outb,
                                             int N){
  int n = blockIdx.x*4 + (threadIdx.x >> 6);
  if (n >= N) return;
  int t = blockIdx.y;
  int g = t*N + n;
  int lane = threadIdx.x & 63;
  int h = lane >> 4;
  int s0 = rowptr[n], s1 = rowptr[n+1];
  float ed = e_d[(size_t)g*4 + h];
  float z = 0.f;
  float a0=0.f, a1=0.f, a2=0.f, a3=0.f;
  const unsigned short* hpt = hpall + (size_t)t*N*256;
  const float* est = e_s + (size_t)t*N*4;
  for (int i = s0; i < s1; ++i){
    int s = colidx[i];
    float e = est[s*4 + h] + ed;
    e = (e > 0.f) ? e : NEG_SLOPE*e;
    float w = __expf(e);
    z += w;
    uint2 v = *(const uint2*)(hpt + (size_t)s*256 + lane*4);
    a0 += w * bf2f(v.x & 0xffffu);
    a1 += w * bf2f(v.x >> 16);
    a2 += w * bf2f(v.y & 0xffffu);
    a3 += w * bf2f(v.y >> 16);
  }
  float inv = 1.f / (z + 1e-16f);
  float4 b = *(const float4*)(bias + lane*4);
  float o0 = a0*inv + b.x, o1 = a1*inv + b.y, o2 = a2*inv + b.z, o3 = a3*inv + b.w;
  o0 = (o0 > 0.f) ? o0 : (__expf(o0) - 1.f);
  o1 = (o1 > 0.f) ? o1 : (__expf(o1) - 1.f);
  o2 = (o2 > 0.f) ? o2 : (__expf(o2) - 1.f);
  o3 = (o3 > 0.f) ? o3 : (__expf(o3) - 1.f);
  unsigned lo = (unsigned)f2bf(o0) | ((unsigned)f2bf(o1) << 16);
  unsigned hi = (unsigned)f2bf(o2) | ((unsigned)f2bf(o3) << 16);
  *(uint2*)(outb + (size_t)g*256 + lane*4) = make_uint2(lo, hi);
}

// ---------------- column sums, batched: 64 chunks per t ----------------
__global__ __launch_bounds__(256) void k_colsum(const unsigned short* __restrict__ emb, float* __restrict__ sums, int N){
  __shared__ float red[8][256];
  int tid = threadIdx.x;
  int t = blockIdx.x >> 6, chunk = blockIdx.x & 63;
  int rows_per = (N + 63) / 64;
  int r0 = chunk * rows_per;
  int r1 = min(N, r0 + rows_per);
  const unsigned short* base = emb + (size_t)t*N*256;
  int c0 = (tid & 31)*8, rg = tid >> 5;
  float s[8] = {0,0,0,0,0,0,0,0};
  for (int r = r0 + rg; r < r1; r += 8){
    uint4 v = *(const uint4*)(base + (size_t)r*256 + c0);
    s[0] += bf2f(v.x & 0xffffu); s[1] += bf2f(v.x >> 16);
    s[2] += bf2f(v.y & 0xffffu); s[3] += bf2f(v.y >> 16);
    s[4] += bf2f(v.z & 0xffffu); s[5] += bf2f(v.z >> 16);
    s[6] += bf2f(v.w & 0xffffu); s[7] += bf2f(v.w >> 16);
  }
  #pragma unroll
  for (int j=0;j<8;j++) red[rg][c0+j] = s[j];
  __syncthreads();
  float tot = 0.f;
  #pragma unroll
  for (int g=0;g<8;g++) tot += red[g][tid];
  atomicAdd(&sums[t*256 + tid], tot);
}

// ---------------- temporal attention weights (tiny) ----------------
__global__ __launch_bounds__(256) void k_attn(const float* __restrict__ sum_emb,
                                              const float* __restrict__ Wq, const float* __restrict__ bq,
                                              const float* __restrict__ Wk, const float* __restrict__ bk,
                                              float* __restrict__ aw, int N){
  __shared__ float mean_s[4][256];
  __shared__ float red[256];
  __shared__ float scores_s[4];
  int j = threadIdx.x;
  float invN = 1.0f/(float)N;
  #pragma unroll
  for (int t=0;t<4;t++) mean_s[t][j] = sum_emb[t*256+j]*invN;
  __syncthreads();
  float q3 = bq[j];
  float kt0=bk[j], kt1=bk[j], kt2=bk[j], kt3=bk[j];
  for (int m=0;m<256;m++){
    float wq = Wq[m*256+j];
    float wk = Wk[m*256+j];
    float m0 = mean_s[0][m], m1 = mean_s[1][m], m2 = mean_s[2][m], m3 = mean_s[3][m];
    q3  += m3*wq;
    kt0 += m0*wk; kt1 += m1*wk; kt2 += m2*wk; kt3 += m3*wk;
  }
  float kts0=kt0, kts1=kt1, kts2=kt2, kts3=kt3;
  #pragma unroll
  for (int t=0;t<4;t++){
    float ktv = (t==0)?kts0:((t==1)?kts1:((t==2)?kts2:kts3));
    red[j] = q3*ktv;
    __syncthreads();
    for (int off=128; off>0; off>>=1){
      if (j < off) red[j] += red[j+off];
      __syncthreads();
    }
    if (j==0) scores_s[t] = red[0]*(1.0f/16.0f);
    __syncthreads();
  }
  if (j==0){
    float mx = fmaxf(fmaxf(scores_s[0],scores_s[1]),fmaxf(scores_s[2],scores_s[3]));
    float w0 = __expf(scores_s[0]-mx), w1 = __expf(scores_s[1]-mx),
          w2 = __expf(scores_s[2]-mx), w3 = __expf(scores_s[3]-mx);
    float s = w0+w1+w2+w3;
    aw[0]=w0/s; aw[1]=w1/s; aw[2]=w2/s; aw[3]=w3/s;
  }
}

// ---------------- temporal combine: comb = sum_t aw[t]*embs[t] ----------------
__global__ __launch_bounds__(256) void k_combine(const unsigned short* __restrict__ embs,
                                                 const float* __restrict__ awp,
                                                 unsigned short* __restrict__ comb, int N){
  int i = blockIdx.x*256 + threadIdx.x;
  int total = N*32;
  if (i >= total) return;
  size_t o = (size_t)i*8;
  size_t sl = (size_t)N*256;
  float a0=awp[0], a1=awp[1], a2=awp[2], a3=awp[3];
  uint4 v0 = *(const uint4*)(embs + o);
  uint4 v1 = *(const uint4*)(embs + o + sl);
  uint4 v2 = *(const uint4*)(embs + o + 2*sl);
  uint4 v3 = *(const uint4*)(embs + o + 3*sl);
  uint4 r;
  unsigned w[4];
  const unsigned* p0=&v0.x; const unsigned* p1=&v1.x; const unsigned* p2=&v2.x; const unsigned* p3=&v3.x;
  #pragma unroll
  for (int k=0;k<4;k++){
    float lo = a0*bf2f(p0[k]&0xffffu) + a1*bf2f(p1[k]&0xffffu) + a2*bf2f(p2[k]&0xffffu) + a3*bf2f(p3[k]&0xffffu);
    float hi = a0*bf2f(p0[k]>>16)     + a1*bf2f(p1[k]>>16)     + a2*bf2f(p2[k]>>16)     + a3*bf2f(p3[k]>>16);
    w[k] = (unsigned)f2bf(lo) | ((unsigned)f2bf(hi) << 16);
  }
  r.x=w[0]; r.y=w[1]; r.z=w[2]; r.w=w[3];
  *(uint4*)(comb + o) = r;
}

extern "C" void kernel_launch(void* const* d_in, const int* in_sizes, int n_in,
                              void* d_out, int out_size, void* d_ws, size_t ws_size,
                              hipStream_t stream){
  (void)n_in; (void)out_size; (void)ws_size;
  const float* x   = (const float*)d_in[0];
  const int*   ei  = (const int*)d_in[1];
  const float* Wp  = (const float*)d_in[2];
  const float* bp  = (const float*)d_in[3];
  const float* W0  = (const float*)d_in[4];
  const float* as0 = (const float*)d_in[5];
  const float* ad0 = (const float*)d_in[6];
  const float* b0  = (const float*)d_in[7];
  const float* W1  = (const float*)d_in[8];
  const float* as1 = (const float*)d_in[9];
  const float* ad1 = (const float*)d_in[10];
  const float* b1  = (const float*)d_in[11];
  const float* Wq  = (const float*)d_in[12];
  const float* bq  = (const float*)d_in[13];
  const float* Wk  = (const float*)d_in[14];
  const float* bk  = (const float*)d_in[15];
  const float* Wv  = (const float*)d_in[16];
  const float* bv  = (const float*)d_in[17];
  float* out = (float*)d_out;

  const int T = 4, FIN = 256;
  const int N = in_sizes[0] / (T*FIN);
  const int E = in_sizes[1] / 2;
  const int TN = T*N;
  const int* src = ei;
  const int* dst = ei + E;

  char* ws = (char*)d_ws;
  size_t cur = 0;
  auto alloc = [&](size_t bytes)->void*{
    void* p = ws + cur;
    cur += (bytes + 255) & ~(size_t)255;
    return p;
  };
  unsigned short* h0all = (unsigned short*)alloc((size_t)TN*64*2);
  unsigned short* bufA  = (unsigned short*)alloc((size_t)TN*256*2);   // agg0_all, then hp_all
  unsigned short* bufB  = (unsigned short*)alloc((size_t)TN*256*2);   // h1_all, then comb
  unsigned short* embs  = (unsigned short*)alloc((size_t)TN*256*2);
  float* e_s    = (float*)alloc((size_t)TN*4*4);
  float* e_d    = (float*)alloc((size_t)TN*4*4);
  float* sume   = (float*)alloc(4*256*4);
  float* aw     = (float*)alloc(256);
  float* ah0s   = (float*)alloc(256*4);
  float* ah0d   = (float*)alloc(256*4);
  int*   rowptr = (int*)alloc((size_t)(N+1)*4);
  int*   deg    = (int*)alloc((size_t)N*4);
  int*   pos    = (int*)alloc((size_t)N*4);
  int*   bsum   = (int*)alloc((size_t)256*4);
  int*   colidx = (int*)alloc((size_t)(E+N)*4);
  unsigned short* WpT  = (unsigned short*)alloc((size_t)64*256*2);
  unsigned short* W0T4 = (unsigned short*)alloc((size_t)4*64*64*2);
  unsigned short* W1T  = (unsigned short*)alloc((size_t)256*256*2);
  unsigned short* WvT  = (unsigned short*)alloc((size_t)256*256*2);

  int nb256 = (N+255)/256;
  int nbE   = (E+255)/256;
  int gm4   = (TN+127)/128;
  int gmN   = (N+127)/128;
  int gagg  = (TN+3)/4;

  // CSR build (graph static across t and layers); multi-block scan
  k_deg_init<<<nb256,256,0,stream>>>(deg, N);
  k_deg_count<<<nbE,256,0,stream>>>(dst, E, deg);
  k_scan_blk<<<nb256,256,0,stream>>>(deg, rowptr, bsum, N);
  k_scan_top<<<1,256,0,stream>>>(bsum, nb256, rowptr + N);
  k_scan_add<<<nb256,256,0,stream>>>(rowptr, bsum, N);
  k_pos_self<<<nb256,256,0,stream>>>(rowptr, pos, colidx, N);
  k_fill_edges<<<nbE,256,0,stream>>>(src, dst, E, pos, colidx);
  hipMemsetAsync(sume, 0, 4*256*4, stream);

  // all weight prep in one launch
  k_prep<<<641,256,0,stream>>>(Wp, W0, W1, Wv, as0, ad0, WpT, W0T4, W1T, WvT, ah0s, ah0d);

  // h0 for all 4 timesteps (direct-fragment GEMM)
  k_h0<<<(TN/64+3)/4 + 1,256,0,stream>>>(x, WpT, bp, h0all, TN, N);

  // GAT layer 0, batched over t
  k_esd0<<<gagg,256,0,stream>>>(h0all, ah0s, ah0d, e_s, e_d, TN);
  k_agg0<<<dim3((N+3)/4, T),256,0,stream>>>(h0all, e_s, e_d, rowptr, colidx, bufA, N);
  // h1 = ELU(agg0 @ blockdiag(W0) + b0), per-head K=64 GEMM
  k_gat0<<<dim3((TN+255)/256, 4),256,0,stream>>>(bufA, W0T4, b0, bufB, TN);
  // GAT layer 1, batched
  k_gemm_p256<256,false,false><<<gm4,512,0,stream>>>(bufB, W1T, nullptr, bufA, TN);
  k_esd<<<gagg,256,0,stream>>>(bufA, as1, ad1, e_s, e_d, TN);
  k_agg<<<dim3((N+3)/4, T),256,0,stream>>>(bufA, e_s, e_d, rowptr, colidx, b1, embs, N);
  // node-mean numerators for temporal attention
  k_colsum<<<256,256,0,stream>>>(embs, sume, N);

  // temporal attention weights, combine, fused V-projection
  k_attn<<<1,256,0,stream>>>(sume, Wq, bq, Wk, bk, aw, N);
  k_combine<<<(N*32+255)/256,256,0,stream>>>(embs, aw, bufB, N);
  k_gemm_p256<256,true,true><<<gmN,512,0,stream>>>(bufB, WvT, bv, out, N);
}

// Round 7
// 457.400 us; speedup vs baseline: 3.8541x; 1.2265x over previous
//
#include <hip/hip_runtime.h>
#include <math.h>

#define NEG_SLOPE 0.2f

typedef __attribute__((ext_vector_type(8))) short short8;
typedef __attribute__((ext_vector_type(4))) float f32x4;

__device__ inline unsigned short f2bf(float f){
  union { float f; unsigned u; } v; v.f = f;
  unsigned r = v.u + 0x7fffu + ((v.u >> 16) & 1u);
  return (unsigned short)(r >> 16);
}
__device__ inline float bf2f(unsigned u){
  union { unsigned u; float f; } v; v.u = u << 16; return v.f;
}

// ---------------- CSR build ----------------
__global__ __launch_bounds__(256) void k_deg_count(const int* __restrict__ dst, int E, int* __restrict__ deg){
  int i = blockIdx.x*256 + threadIdx.x;
  if (i < E) atomicAdd(&deg[dst[i]], 1);
}
// 3-phase scan; deg[i]+1 accounts for the self-loop (deg itself is memset to 0)
__global__ __launch_bounds__(256) void k_scan_blk(const int* __restrict__ deg, int* __restrict__ rowptr,
                                                  int* __restrict__ bsum, int N){
  __shared__ int ws[4];
  int tid = threadIdx.x;
  int i = blockIdx.x*256 + tid;
  int v = (i < N) ? deg[i]+1 : 0;
  int lane = tid & 63, w = tid >> 6;
  int s = v;
  #pragma unroll
  for (int off=1; off<64; off<<=1){
    int u = __shfl_up(s, off);
    if (lane >= off) s += u;
  }
  if (lane == 63) ws[w] = s;
  __syncthreads();
  int woff = 0;
  #pragma unroll
  for (int k=0;k<4;k++) if (k < w) woff += ws[k];
  int incl = s + woff;
  if (i < N) rowptr[i] = incl - v;      // exclusive within block
  if (tid == 255) bsum[blockIdx.x] = incl;
}
__global__ __launch_bounds__(256) void k_scan_top(int* __restrict__ bsum, int nb, int* __restrict__ rowptrN){
  __shared__ int buf[256];
  int tid = threadIdx.x;
  int v = (tid < nb) ? bsum[tid] : 0;
  buf[tid] = v;
  __syncthreads();
  for (int off=1; off<256; off<<=1){
    int add = (tid >= off) ? buf[tid-off] : 0;
    __syncthreads();
    buf[tid] += add;
    __syncthreads();
  }
  if (tid < nb) bsum[tid] = buf[tid] - v;   // exclusive block offsets
  if (tid == 0) rowptrN[0] = buf[255];      // grand total
}
// add block offsets + write self-loop + init pos (fused)
__global__ __launch_bounds__(256) void k_scan_fix(int* __restrict__ rowptr, const int* __restrict__ bsum,
                                                  int* __restrict__ pos, int* __restrict__ colidx, int N){
  int i = blockIdx.x*256 + threadIdx.x;
  if (i < N){
    int r = rowptr[i] + bsum[blockIdx.x];
    rowptr[i] = r;
    colidx[r] = i;
    pos[i] = r + 1;
  }
}
__global__ __launch_bounds__(256) void k_fill_edges(const int* __restrict__ src, const int* __restrict__ dst,
                                                    int E, int* __restrict__ pos, int* __restrict__ colidx){
  int i = blockIdx.x*256 + threadIdx.x;
  if (i < E){
    int d = dst[i];
    colidx[atomicAdd(&pos[d],1)] = src[i];
  }
}

// ---------------- all weight prep in one launch ----------------
__global__ __launch_bounds__(256) void k_prep(const float* __restrict__ Wp, const float* __restrict__ W0,
                                              const float* __restrict__ W1, const float* __restrict__ Wv,
                                              const float* __restrict__ as0, const float* __restrict__ ad0,
                                              unsigned short* __restrict__ WpT, unsigned short* __restrict__ W0T4,
                                              unsigned short* __restrict__ W1T, unsigned short* __restrict__ WvT,
                                              float* __restrict__ ahs, float* __restrict__ ahd){
  int idx = blockIdx.x*256 + threadIdx.x;
  if (idx < 16384){
    int k = idx >> 6, p = idx & 63;
    WpT[p*256 + k] = f2bf(Wp[idx]);
  } else if (idx < 32768){
    int i = idx - 16384;
    int h = i >> 12, r = i & 4095, p = r >> 6, k = r & 63;
    W0T4[i] = f2bf(W0[k*256 + h*64 + p]);
  } else if (idx < 98304){
    int i = idx - 32768; int k = i >> 8, p = i & 255;
    W1T[p*256 + k] = f2bf(W1[i]);
  } else if (idx < 163840){
    int i = idx - 98304; int k = i >> 8, p = i & 255;
    WvT[p*256 + k] = f2bf(Wv[i]);
  } else if (idx < 164096){
    int i = idx - 163840;
    int h = i >> 6, d = i & 63;
    float ss = 0.f, sd = 0.f;
    for (int j=0;j<64;j++){
      float w = W0[d*256 + h*64 + j];
      ss += w * as0[h*64 + j];
      sd += w * ad0[h*64 + j];
    }
    ahs[i] = ss; ahd[i] = sd;
  }
}

// ---------------- h0 = x @ Wp + bp : direct-fragment MFMA GEMM ----------------
__global__ __launch_bounds__(256) void k_h0(const float* __restrict__ A,
                                            const unsigned short* __restrict__ Bt,
                                            const float* __restrict__ bias,
                                            unsigned short* __restrict__ C, int M, int Nn){
  int wid = blockIdx.x*4 + (threadIdx.x >> 6);
  int m0 = wid * 64;
  if (m0 >= M) return;
  int lane = threadIdx.x & 63;
  int lr = lane & 15, g = lane >> 4, lk = g*8;
  const float* Arow[4];
  #pragma unroll
  for (int m=0;m<4;m++){
    int row = m0 + m*16 + lr;
    if (row > M-1) row = M-1;
    Arow[m] = A + (size_t)row*256 + lk;
  }
  const unsigned short* Bb = Bt + (size_t)lr*256 + lk;
  f32x4 acc[4][4];
  #pragma unroll
  for (int m=0;m<4;m++)
    #pragma unroll
    for (int n=0;n<4;n++)
      #pragma unroll
      for (int j=0;j<4;j++) acc[m][n][j] = 0.f;

  #pragma unroll 2
  for (int ks=0; ks<8; ks++){
    int k0 = ks*32;
    short8 bfr[4];
    #pragma unroll
    for (int n=0;n<4;n++)
      bfr[n] = *(const short8*)(Bb + (size_t)n*16*256 + k0);
    short8 afr[4];
    #pragma unroll
    for (int m=0;m<4;m++){
      float4 u = *(const float4*)(Arow[m] + k0);
      float4 w = *(const float4*)(Arow[m] + k0 + 4);
      afr[m][0]=(short)f2bf(u.x); afr[m][1]=(short)f2bf(u.y);
      afr[m][2]=(short)f2bf(u.z); afr[m][3]=(short)f2bf(u.w);
      afr[m][4]=(short)f2bf(w.x); afr[m][5]=(short)f2bf(w.y);
      afr[m][6]=(short)f2bf(w.z); afr[m][7]=(short)f2bf(w.w);
    }
    #pragma unroll
    for (int m=0;m<4;m++)
      #pragma unroll
      for (int n=0;n<4;n++)
        acc[m][n] = __builtin_amdgcn_mfma_f32_16x16x32_bf16(afr[m], bfr[n], acc[m][n], 0,0,0);
  }
  #pragma unroll
  for (int n=0;n<4;n++){
    int col = n*16 + lr;
    float bcol = bias[col];
    #pragma unroll
    for (int m=0;m<4;m++){
      #pragma unroll
      for (int j=0;j<4;j++){
        int row = m0 + m*16 + g*4 + j;
        if (row < M){
          int t = row & 3, nn = row >> 2;
          C[(size_t)t*Nn*64 + (size_t)nn*64 + col] = f2bf(acc[m][n][j] + bcol);
        }
      }
    }
  }
}

// ---------------- layer-0 per-head GEMM: h1 = ELU(agg0 @ blockdiag(W0) + b0) ----------------
__global__ __launch_bounds__(256) void k_gat0(const unsigned short* __restrict__ A,
                                              const unsigned short* __restrict__ W0T4,
                                              const float* __restrict__ b0,
                                              unsigned short* __restrict__ C, int M){
  int h = blockIdx.y;
  int wid = blockIdx.x*4 + (threadIdx.x >> 6);
  int m0 = wid * 64;
  if (m0 >= M) return;
  int lane = threadIdx.x & 63;
  int lr = lane & 15, g = lane >> 4, lk = g*8;
  const unsigned short* Wh = W0T4 + (size_t)h*64*64;
  f32x4 acc[4][4];
  #pragma unroll
  for (int m=0;m<4;m++)
    #pragma unroll
    for (int n=0;n<4;n++)
      #pragma unroll
      for (int j=0;j<4;j++) acc[m][n][j] = 0.f;

  #pragma unroll
  for (int ks=0; ks<2; ks++){
    short8 bfr[4], afr[4];
    #pragma unroll
    for (int n=0;n<4;n++)
      bfr[n] = *(const short8*)(Wh + (size_t)(n*16+lr)*64 + ks*32 + lk);
    #pragma unroll
    for (int m=0;m<4;m++){
      int row = m0 + m*16 + lr;
      if (row > M-1) row = M-1;
      afr[m] = *(const short8*)(A + (size_t)row*256 + h*64 + ks*32 + lk);
    }
    #pragma unroll
    for (int m=0;m<4;m++)
      #pragma unroll
      for (int n=0;n<4;n++)
        acc[m][n] = __builtin_amdgcn_mfma_f32_16x16x32_bf16(afr[m], bfr[n], acc[m][n], 0,0,0);
  }
  #pragma unroll
  for (int n=0;n<4;n++){
    int col = h*64 + n*16 + lr;
    float bcol = b0[col];
    #pragma unroll
    for (int m=0;m<4;m++){
      #pragma unroll
      for (int j=0;j<4;j++){
        int row = m0 + m*16 + g*4 + j;
        if (row < M){
          float v = acc[m][n][j] + bcol;
          v = (v > 0.f) ? v : (__expf(v) - 1.f);
          C[(size_t)row*256 + col] = f2bf(v);
        }
      }
    }
  }
}

// ---------------- MFMA GEMM, P=256: 512 threads, BM=128, BN=256 ----------------
template<int K, bool BIAS, bool CF32>
__global__ __launch_bounds__(512) void k_gemm_p256(const unsigned short* __restrict__ A,
                                                   const unsigned short* __restrict__ Bt,
                                                   const float* __restrict__ bias,
                                                   void* __restrict__ Cv, int M){
  constexpr int BK = 64, PAD = 8;
  __shared__ unsigned short Als[128][BK+PAD];
  __shared__ unsigned short Bls[256][BK+PAD];
  int tid = threadIdx.x;
  int m0  = blockIdx.x * 128;
  int wave = tid >> 6, lane = tid & 63;
  int wr = wave & 3, wc = wave >> 2;
  int lr = lane & 15, lk = (lane >> 4) * 8;
  f32x4 acc[2][8];
  #pragma unroll
  for (int m=0;m<2;m++)
    #pragma unroll
    for (int n=0;n<8;n++)
      #pragma unroll
      for (int j=0;j<4;j++) acc[m][n][j] = 0.f;

  for (int k0 = 0; k0 < K; k0 += BK){
    #pragma unroll
    for (int i=0;i<2;i++){
      int idx = tid + i*512;
      int r = idx >> 3, ch = (idx & 7)*8;
      int row = m0 + r;
      uint4 v = make_uint4(0,0,0,0);
      if (row < M) v = *(const uint4*)(A + (size_t)row*K + k0 + ch);
      *(uint4*)(&Als[r][ch]) = v;
    }
    #pragma unroll
    for (int i=0;i<4;i++){
      int idx = tid + i*512;
      int r = idx >> 3, ch = (idx & 7)*8;
      *(uint4*)(&Bls[r][ch]) = *(const uint4*)(Bt + (size_t)r*K + k0 + ch);
    }
    __syncthreads();
    #pragma unroll
    for (int ks=0; ks<2; ks++){
      short8 afr[2], bfr[8];
      #pragma unroll
      for (int m=0;m<2;m++)
        afr[m] = *(const short8*)(&Als[wr*32 + m*16 + lr][ks*32 + lk]);
      #pragma unroll
      for (int n=0;n<8;n++)
        bfr[n] = *(const short8*)(&Bls[wc*128 + n*16 + lr][ks*32 + lk]);
      #pragma unroll
      for (int m=0;m<2;m++)
        #pragma unroll
        for (int n=0;n<8;n++)
          acc[m][n] = __builtin_amdgcn_mfma_f32_16x16x32_bf16(afr[m], bfr[n], acc[m][n], 0,0,0);
    }
    __syncthreads();
  }
  #pragma unroll
  for (int m=0;m<2;m++){
    #pragma unroll
    for (int n=0;n<8;n++){
      int col = wc*128 + n*16 + lr;
      float bcol = BIAS ? bias[col] : 0.f;
      #pragma unroll
      for (int j=0;j<4;j++){
        int row = m0 + wr*32 + m*16 + (lane>>4)*4 + j;
        if (row < M){
          float v = acc[m][n][j] + bcol;
          if (CF32) ((float*)Cv)[(size_t)row*256 + col] = v;
          else      ((unsigned short*)Cv)[(size_t)row*256 + col] = f2bf(v);
        }
      }
    }
  }
}

// ---------------- final GEMM with fused temporal combine in A-staging ----------------
__global__ __launch_bounds__(512) void k_gemm_fin(const unsigned short* __restrict__ embs,
                                                  const float* __restrict__ awp,
                                                  const unsigned short* __restrict__ Bt,
                                                  const float* __restrict__ bias,
                                                  float* __restrict__ C, int M){
  constexpr int K = 256, BK = 64, PAD = 8;
  __shared__ unsigned short Als[128][BK+PAD];
  __shared__ unsigned short Bls[256][BK+PAD];
  int tid = threadIdx.x;
  int m0  = blockIdx.x * 128;
  int wave = tid >> 6, lane = tid & 63;
  int wr = wave & 3, wc = wave >> 2;
  int lr = lane & 15, lk = (lane >> 4) * 8;
  float a0=awp[0], a1=awp[1], a2=awp[2], a3=awp[3];
  size_t sl = (size_t)M*256;
  f32x4 acc[2][8];
  #pragma unroll
  for (int m=0;m<2;m++)
    #pragma unroll
    for (int n=0;n<8;n++)
      #pragma unroll
      for (int j=0;j<4;j++) acc[m][n][j] = 0.f;

  for (int k0 = 0; k0 < K; k0 += BK){
    #pragma unroll
    for (int i=0;i<2;i++){
      int idx = tid + i*512;
      int r = idx >> 3, ch = (idx & 7)*8;
      int row = m0 + r;
      uint4 w = make_uint4(0,0,0,0);
      if (row < M){
        size_t o = (size_t)row*256 + k0 + ch;
        uint4 u0 = *(const uint4*)(embs + o);
        uint4 u1 = *(const uint4*)(embs + o + sl);
        uint4 u2 = *(const uint4*)(embs + o + 2*sl);
        uint4 u3 = *(const uint4*)(embs + o + 3*sl);
        const unsigned* p0=&u0.x; const unsigned* p1=&u1.x;
        const unsigned* p2=&u2.x; const unsigned* p3=&u3.x;
        unsigned* pw=&w.x;
        #pragma unroll
        for (int q=0;q<4;q++){
          float lo = a0*bf2f(p0[q]&0xffffu) + a1*bf2f(p1[q]&0xffffu) + a2*bf2f(p2[q]&0xffffu) + a3*bf2f(p3[q]&0xffffu);
          float hi = a0*bf2f(p0[q]>>16)     + a1*bf2f(p1[q]>>16)     + a2*bf2f(p2[q]>>16)     + a3*bf2f(p3[q]>>16);
          pw[q] = (unsigned)f2bf(lo) | ((unsigned)f2bf(hi) << 16);
        }
      }
      *(uint4*)(&Als[r][ch]) = w;
    }
    #pragma unroll
    for (int i=0;i<4;i++){
      int idx = tid + i*512;
      int r = idx >> 3, ch = (idx & 7)*8;
      *(uint4*)(&Bls[r][ch]) = *(const uint4*)(Bt + (size_t)r*K + k0 + ch);
    }
    __syncthreads();
    #pragma unroll
    for (int ks=0; ks<2; ks++){
      short8 afr[2], bfr[8];
      #pragma unroll
      for (int m=0;m<2;m++)
        afr[m] = *(const short8*)(&Als[wr*32 + m*16 + lr][ks*32 + lk]);
      #pragma unroll
      for (int n=0;n<8;n++)
        bfr[n] = *(const short8*)(&Bls[wc*128 + n*16 + lr][ks*32 + lk]);
      #pragma unroll
      for (int m=0;m<2;m++)
        #pragma unroll
        for (int n=0;n<8;n++)
          acc[m][n] = __builtin_amdgcn_mfma_f32_16x16x32_bf16(afr[m], bfr[n], acc[m][n], 0,0,0);
    }
    __syncthreads();
  }
  #pragma unroll
  for (int m=0;m<2;m++){
    #pragma unroll
    for (int n=0;n<8;n++){
      int col = wc*128 + n*16 + lr;
      float bcol = bias[col];
      #pragma unroll
      for (int j=0;j<4;j++){
        int row = m0 + wr*32 + m*16 + (lane>>4)*4 + j;
        if (row < M)
          C[(size_t)row*256 + col] = acc[m][n][j] + bcol;
      }
    }
  }
}

// ---------------- layer-0 logits ----------------
__global__ __launch_bounds__(256) void k_esd0(const unsigned short* __restrict__ h0,
                                              const float* __restrict__ ahs, const float* __restrict__ ahd,
                                              float* __restrict__ e_s, float* __restrict__ e_d, int M){
  int n = blockIdx.x*4 + (threadIdx.x >> 6);
  if (n >= M) return;
  int lane = threadIdx.x & 63;
  int h = lane >> 4, l4 = (lane & 15)*4;
  uint2 v = *(const uint2*)(h0 + (size_t)n*64 + l4);
  float v0 = bf2f(v.x & 0xffffu), v1 = bf2f(v.x >> 16);
  float v2 = bf2f(v.y & 0xffffu), v3 = bf2f(v.y >> 16);
  float4 as = *(const float4*)(ahs + h*64 + l4);
  float4 ad = *(const float4*)(ahd + h*64 + l4);
  float ps = v0*as.x + v1*as.y + v2*as.z + v3*as.w;
  float pd = v0*ad.x + v1*ad.y + v2*ad.z + v3*ad.w;
  #pragma unroll
  for (int off=1; off<16; off<<=1){ ps += __shfl_xor(ps,off); pd += __shfl_xor(pd,off); }
  if ((lane & 15) == 0){
    e_s[n*4+h] = ps; e_d[n*4+h] = pd;
  }
}

// ---------------- layer-0 aggregation, 4-deep unrolled edge loop ----------------
__global__ __launch_bounds__(256) void k_agg0(const unsigned short* __restrict__ h0all,
                                              const float* __restrict__ e_s, const float* __restrict__ e_d,
                                              const int* __restrict__ rowptr, const int* __restrict__ colidx,
                                              unsigned short* __restrict__ agg, int N){
  int n = blockIdx.x*4 + (threadIdx.x >> 6);
  if (n >= N) return;
  int t = blockIdx.y;
  int g = t*N + n;
  int lane = threadIdx.x & 63;
  int h = lane >> 4, l4 = (lane & 15)*4;
  int s0 = rowptr[n], s1 = rowptr[n+1];
  float ed = e_d[(size_t)g*4 + h];
  float z = 0.f;
  float a0=0.f, a1=0.f, a2=0.f, a3=0.f;
  const unsigned short* h0t = h0all + (size_t)t*N*64;
  const float* est = e_s + (size_t)t*N*4;
  int i = s0;
  for (; i+4 <= s1; i += 4){
    int sA = colidx[i], sB = colidx[i+1], sC = colidx[i+2], sD = colidx[i+3];
    uint2 vA = *(const uint2*)(h0t + (size_t)sA*64 + l4);
    uint2 vB = *(const uint2*)(h0t + (size_t)sB*64 + l4);
    uint2 vC = *(const uint2*)(h0t + (size_t)sC*64 + l4);
    uint2 vD = *(const uint2*)(h0t + (size_t)sD*64 + l4);
    float eA = est[sA*4+h] + ed, eB = est[sB*4+h] + ed, eC = est[sC*4+h] + ed, eD = est[sD*4+h] + ed;
    eA = (eA>0.f)?eA:NEG_SLOPE*eA; eB = (eB>0.f)?eB:NEG_SLOPE*eB;
    eC = (eC>0.f)?eC:NEG_SLOPE*eC; eD = (eD>0.f)?eD:NEG_SLOPE*eD;
    float wA = __expf(eA), wB = __expf(eB), wC = __expf(eC), wD = __expf(eD);
    z += (wA + wB) + (wC + wD);
    a0 += wA*bf2f(vA.x&0xffffu) + wB*bf2f(vB.x&0xffffu) + wC*bf2f(vC.x&0xffffu) + wD*bf2f(vD.x&0xffffu);
    a1 += wA*bf2f(vA.x>>16)     + wB*bf2f(vB.x>>16)     + wC*bf2f(vC.x>>16)     + wD*bf2f(vD.x>>16);
    a2 += wA*bf2f(vA.y&0xffffu) + wB*bf2f(vB.y&0xffffu) + wC*bf2f(vC.y&0xffffu) + wD*bf2f(vD.y&0xffffu);
    a3 += wA*bf2f(vA.y>>16)     + wB*bf2f(vB.y>>16)     + wC*bf2f(vC.y>>16)     + wD*bf2f(vD.y>>16);
  }
  for (; i < s1; ++i){
    int s = colidx[i];
    float e = est[s*4 + h] + ed;
    e = (e > 0.f) ? e : NEG_SLOPE*e;
    float w = __expf(e);
    z += w;
    uint2 v = *(const uint2*)(h0t + (size_t)s*64 + l4);
    a0 += w * bf2f(v.x & 0xffffu);
    a1 += w * bf2f(v.x >> 16);
    a2 += w * bf2f(v.y & 0xffffu);
    a3 += w * bf2f(v.y >> 16);
  }
  float inv = 1.f / (z + 1e-16f);
  unsigned lo = (unsigned)f2bf(a0*inv) | ((unsigned)f2bf(a1*inv) << 16);
  unsigned hi = (unsigned)f2bf(a2*inv) | ((unsigned)f2bf(a3*inv) << 16);
  *(uint2*)(agg + (size_t)g*256 + h*64 + l4) = make_uint2(lo, hi);
}

// ---------------- layer-1 logits ----------------
__global__ __launch_bounds__(256) void k_esd(const unsigned short* __restrict__ hp,
                                             const float* __restrict__ a_s, const float* __restrict__ a_d,
                                             float* __restrict__ e_s, float* __restrict__ e_d, int M){
  int n = blockIdx.x*4 + (threadIdx.x >> 6);
  if (n >= M) return;
  int lane = threadIdx.x & 63;
  uint2 v = *(const uint2*)(hp + (size_t)n*256 + lane*4);
  float v0 = bf2f(v.x & 0xffffu), v1 = bf2f(v.x >> 16);
  float v2 = bf2f(v.y & 0xffffu), v3 = bf2f(v.y >> 16);
  float4 as = *(const float4*)(a_s + lane*4);
  float4 ad = *(const float4*)(a_d + lane*4);
  float ps = v0*as.x + v1*as.y + v2*as.z + v3*as.w;
  float pd = v0*ad.x + v1*ad.y + v2*ad.z + v3*ad.w;
  #pragma unroll
  for (int off=1; off<16; off<<=1){ ps += __shfl_xor(ps,off); pd += __shfl_xor(pd,off); }
  if ((lane & 15) == 0){
    int h = lane >> 4;
    e_s[n*4+h] = ps; e_d[n*4+h] = pd;
  }
}

// ---------------- layer-1 aggregation, 4-deep unrolled + bias + ELU ----------------
__global__ __launch_bounds__(256) void k_agg(const unsigned short* __restrict__ hpall,
                                             const float* __restrict__ e_s, const float* __restrict__ e_d,
                                             const int* __restrict__ rowptr, const int* __restrict__ colidx,
                                             const float* __restrict__ bias, unsigned short* __restrict__ outb,
                                             int N){
  int n = blockIdx.x*4 + (threadIdx.x >> 6);
  if (n >= N) return;
  int t = blockIdx.y;
  int g = t*N + n;
  int lane = threadIdx.x & 63;
  int h = lane >> 4;
  int s0 = rowptr[n], s1 = rowptr[n+1];
  float ed = e_d[(size_t)g*4 + h];
  float z = 0.f;
  float a0=0.f, a1=0.f, a2=0.f, a3=0.f;
  const unsigned short* hpt = hpall + (size_t)t*N*256;
  const float* est = e_s + (size_t)t*N*4;
  int i = s0;
  for (; i+4 <= s1; i += 4){
    int sA = colidx[i], sB = colidx[i+1], sC = colidx[i+2], sD = colidx[i+3];
    uint2 vA = *(const uint2*)(hpt + (size_t)sA*256 + lane*4);
    uint2 vB = *(const uint2*)(hpt + (size_t)sB*256 + lane*4);
    uint2 vC = *(const uint2*)(hpt + (size_t)sC*256 + lane*4);
    uint2 vD = *(const uint2*)(hpt + (size_t)sD*256 + lane*4);
    float eA = est[sA*4+h] + ed, eB = est[sB*4+h] + ed, eC = est[sC*4+h] + ed, eD = est[sD*4+h] + ed;
    eA = (eA>0.f)?eA:NEG_SLOPE*eA; eB = (eB>0.f)?eB:NEG_SLOPE*eB;
    eC = (eC>0.f)?eC:NEG_SLOPE*eC; eD = (eD>0.f)?eD:NEG_SLOPE*eD;
    float wA = __expf(eA), wB = __expf(eB), wC = __expf(eC), wD = __expf(eD);
    z += (wA + wB) + (wC + wD);
    a0 += wA*bf2f(vA.x&0xffffu) + wB*bf2f(vB.x&0xffffu) + wC*bf2f(vC.x&0xffffu) + wD*bf2f(vD.x&0xffffu);
    a1 += wA*bf2f(vA.x>>16)     + wB*bf2f(vB.x>>16)     + wC*bf2f(vC.x>>16)     + wD*bf2f(vD.x>>16);
    a2 += wA*bf2f(vA.y&0xffffu) + wB*bf2f(vB.y&0xffffu) + wC*bf2f(vC.y&0xffffu) + wD*bf2f(vD.y&0xffffu);
    a3 += wA*bf2f(vA.y>>16)     + wB*bf2f(vB.y>>16)     + wC*bf2f(vC.y>>16)     + wD*bf2f(vD.y>>16);
  }
  for (; i < s1; ++i){
    int s = colidx[i];
    float e = est[s*4 + h] + ed;
    e = (e > 0.f) ? e : NEG_SLOPE*e;
    float w = __expf(e);
    z += w;
    uint2 v = *(const uint2*)(hpt + (size_t)s*256 + lane*4);
    a0 += w * bf2f(v.x & 0xffffu);
    a1 += w * bf2f(v.x >> 16);
    a2 += w * bf2f(v.y & 0xffffu);
    a3 += w * bf2f(v.y >> 16);
  }
  float inv = 1.f / (z + 1e-16f);
  float4 b = *(const float4*)(bias + lane*4);
  float o0 = a0*inv + b.x, o1 = a1*inv + b.y, o2 = a2*inv + b.z, o3 = a3*inv + b.w;
  o0 = (o0 > 0.f) ? o0 : (__expf(o0) - 1.f);
  o1 = (o1 > 0.f) ? o1 : (__expf(o1) - 1.f);
  o2 = (o2 > 0.f) ? o2 : (__expf(o2) - 1.f);
  o3 = (o3 > 0.f) ? o3 : (__expf(o3) - 1.f);
  unsigned lo = (unsigned)f2bf(o0) | ((unsigned)f2bf(o1) << 16);
  unsigned hi = (unsigned)f2bf(o2) | ((unsigned)f2bf(o3) << 16);
  *(uint2*)(outb + (size_t)g*256 + lane*4) = make_uint2(lo, hi);
}

// ---------------- column sums, batched: 64 chunks per t ----------------
__global__ __launch_bounds__(256) void k_colsum(const unsigned short* __restrict__ emb, float* __restrict__ sums, int N){
  __shared__ float red[8][256];
  int tid = threadIdx.x;
  int t = blockIdx.x >> 6, chunk = blockIdx.x & 63;
  int rows_per = (N + 63) / 64;
  int r0 = chunk * rows_per;
  int r1 = min(N, r0 + rows_per);
  const unsigned short* base = emb + (size_t)t*N*256;
  int c0 = (tid & 31)*8, rg = tid >> 5;
  float s[8] = {0,0,0,0,0,0,0,0};
  for (int r = r0 + rg; r < r1; r += 8){
    uint4 v = *(const uint4*)(base + (size_t)r*256 + c0);
    s[0] += bf2f(v.x & 0xffffu); s[1] += bf2f(v.x >> 16);
    s[2] += bf2f(v.y & 0xffffu); s[3] += bf2f(v.y >> 16);
    s[4] += bf2f(v.z & 0xffffu); s[5] += bf2f(v.z >> 16);
    s[6] += bf2f(v.w & 0xffffu); s[7] += bf2f(v.w >> 16);
  }
  #pragma unroll
  for (int j=0;j<8;j++) red[rg][c0+j] = s[j];
  __syncthreads();
  float tot = 0.f;
  #pragma unroll
  for (int g=0;g<8;g++) tot += red[g][tid];
  atomicAdd(&sums[t*256 + tid], tot);
}

// ---------------- temporal attention weights (tiny) ----------------
__global__ __launch_bounds__(256) void k_attn(const float* __restrict__ sum_emb,
                                              const float* __restrict__ Wq, const float* __restrict__ bq,
                                              const float* __restrict__ Wk, const float* __restrict__ bk,
                                              float* __restrict__ aw, int N){
  __shared__ float mean_s[4][256];
  __shared__ float red[256];
  __shared__ float scores_s[4];
  int j = threadIdx.x;
  float invN = 1.0f/(float)N;
  #pragma unroll
  for (int t=0;t<4;t++) mean_s[t][j] = sum_emb[t*256+j]*invN;
  __syncthreads();
  float q3 = bq[j];
  float kt0=bk[j], kt1=bk[j], kt2=bk[j], kt3=bk[j];
  for (int m=0;m<256;m++){
    float wq = Wq[m*256+j];
    float wk = Wk[m*256+j];
    float m0 = mean_s[0][m], m1 = mean_s[1][m], m2 = mean_s[2][m], m3 = mean_s[3][m];
    q3  += m3*wq;
    kt0 += m0*wk; kt1 += m1*wk; kt2 += m2*wk; kt3 += m3*wk;
  }
  float kts0=kt0, kts1=kt1, kts2=kt2, kts3=kt3;
  #pragma unroll
  for (int t=0;t<4;t++){
    float ktv = (t==0)?kts0:((t==1)?kts1:((t==2)?kts2:kts3));
    red[j] = q3*ktv;
    __syncthreads();
    for (int off=128; off>0; off>>=1){
      if (j < off) red[j] += red[j+off];
      __syncthreads();
    }
    if (j==0) scores_s[t] = red[0]*(1.0f/16.0f);
    __syncthreads();
  }
  if (j==0){
    float mx = fmaxf(fmaxf(scores_s[0],scores_s[1]),fmaxf(scores_s[2],scores_s[3]));
    float w0 = __expf(scores_s[0]-mx), w1 = __expf(scores_s[1]-mx),
          w2 = __expf(scores_s[2]-mx), w3 = __expf(scores_s[3]-mx);
    float s = w0+w1+w2+w3;
    aw[0]=w0/s; aw[1]=w1/s; aw[2]=w2/s; aw[3]=w3/s;
  }
}

extern "C" void kernel_launch(void* const* d_in, const int* in_sizes, int n_in,
                              void* d_out, int out_size, void* d_ws, size_t ws_size,
                              hipStream_t stream){
  (void)n_in; (void)out_size; (void)ws_size;
  const float* x   = (const float*)d_in[0];
  const int*   ei  = (const int*)d_in[1];
  const float* Wp  = (const float*)d_in[2];
  const float* bp  = (const float*)d_in[3];
  const float* W0  = (const float*)d_in[4];
  const float* as0 = (const float*)d_in[5];
  const float* ad0 = (const float*)d_in[6];
  const float* b0  = (const float*)d_in[7];
  const float* W1  = (const float*)d_in[8];
  const float* as1 = (const float*)d_in[9];
  const float* ad1 = (const float*)d_in[10];
  const float* b1  = (const float*)d_in[11];
  const float* Wq  = (const float*)d_in[12];
  const float* bq  = (const float*)d_in[13];
  const float* Wk  = (const float*)d_in[14];
  const float* bk  = (const float*)d_in[15];
  const float* Wv  = (const float*)d_in[16];
  const float* bv  = (const float*)d_in[17];
  float* out = (float*)d_out;

  const int T = 4, FIN = 256;
  const int N = in_sizes[0] / (T*FIN);
  const int E = in_sizes[1] / 2;
  const int TN = T*N;
  const int* src = ei;
  const int* dst = ei + E;

  char* ws = (char*)d_ws;
  size_t cur = 0;
  auto alloc = [&](size_t bytes)->void*{
    void* p = ws + cur;
    cur += (bytes + 255) & ~(size_t)255;
    return p;
  };
  unsigned short* h0all = (unsigned short*)alloc((size_t)TN*64*2);
  unsigned short* bufA  = (unsigned short*)alloc((size_t)TN*256*2);   // agg0_all, then hp_all
  unsigned short* bufB  = (unsigned short*)alloc((size_t)TN*256*2);   // h1_all
  unsigned short* embs  = (unsigned short*)alloc((size_t)TN*256*2);
  float* e_s    = (float*)alloc((size_t)TN*4*4);
  float* e_d    = (float*)alloc((size_t)TN*4*4);
  float* sume   = (float*)alloc(4*256*4);
  float* aw     = (float*)alloc(256);
  float* ah0s   = (float*)alloc(256*4);
  float* ah0d   = (float*)alloc(256*4);
  int*   rowptr = (int*)alloc((size_t)(N+1)*4);
  int*   deg    = (int*)alloc((size_t)N*4);
  int*   pos    = (int*)alloc((size_t)N*4);
  int*   bsum   = (int*)alloc((size_t)256*4);
  int*   colidx = (int*)alloc((size_t)(E+N)*4);
  unsigned short* WpT  = (unsigned short*)alloc((size_t)64*256*2);
  unsigned short* W0T4 = (unsigned short*)alloc((size_t)4*64*64*2);
  unsigned short* W1T  = (unsigned short*)alloc((size_t)256*256*2);
  unsigned short* WvT  = (unsigned short*)alloc((size_t)256*256*2);

  int nb256 = (N+255)/256;
  int nbE   = (E+255)/256;
  int gm4   = (TN+127)/128;
  int gmN   = (N+127)/128;
  int gagg  = (TN+3)/4;

  // CSR build (graph static across t and layers)
  hipMemsetAsync(deg, 0, (size_t)N*4, stream);
  k_deg_count<<<nbE,256,0,stream>>>(dst, E, deg);
  k_scan_blk<<<nb256,256,0,stream>>>(deg, rowptr, bsum, N);
  k_scan_top<<<1,256,0,stream>>>(bsum, nb256, rowptr + N);
  k_scan_fix<<<nb256,256,0,stream>>>(rowptr, bsum, pos, colidx, N);
  k_fill_edges<<<nbE,256,0,stream>>>(src, dst, E, pos, colidx);
  hipMemsetAsync(sume, 0, 4*256*4, stream);

  // all weight prep in one launch
  k_prep<<<641,256,0,stream>>>(Wp, W0, W1, Wv, as0, ad0, WpT, W0T4, W1T, WvT, ah0s, ah0d);

  // h0 for all 4 timesteps (direct-fragment GEMM)
  k_h0<<<(TN/64+3)/4 + 1,256,0,stream>>>(x, WpT, bp, h0all, TN, N);

  // GAT layer 0, batched over t
  k_esd0<<<gagg,256,0,stream>>>(h0all, ah0s, ah0d, e_s, e_d, TN);
  k_agg0<<<dim3((N+3)/4, T),256,0,stream>>>(h0all, e_s, e_d, rowptr, colidx, bufA, N);
  k_gat0<<<dim3((TN+255)/256, 4),256,0,stream>>>(bufA, W0T4, b0, bufB, TN);
  // GAT layer 1, batched
  k_gemm_p256<256,false,false><<<gm4,512,0,stream>>>(bufB, W1T, nullptr, bufA, TN);
  k_esd<<<gagg,256,0,stream>>>(bufA, as1, ad1, e_s, e_d, TN);
  k_agg<<<dim3((N+3)/4, T),256,0,stream>>>(bufA, e_s, e_d, rowptr, colidx, b1, embs, N);
  // node-mean numerators for temporal attention
  k_colsum<<<256,256,0,stream>>>(embs, sume, N);

  // temporal attention weights, then final GEMM with fused combine
  k_attn<<<1,256,0,stream>>>(sume, Wq, bq, Wk, bk, aw, N);
  k_gemm_fin<<<gmN,512,0,stream>>>(embs, aw, WvT, bv, out, N);
}

// Round 8
// 445.003 us; speedup vs baseline: 3.9615x; 1.0279x over previous
//
#include <hip/hip_runtime.h>
#include <math.h>

#define NEG_SLOPE 0.2f

typedef __attribute__((ext_vector_type(8))) short short8;
typedef __attribute__((ext_vector_type(4))) float f32x4;

__device__ inline unsigned short f2bf(float f){
  union { float f; unsigned u; } v; v.f = f;
  unsigned r = v.u + 0x7fffu + ((v.u >> 16) & 1u);
  return (unsigned short)(r >> 16);
}
__device__ inline float bf2f(unsigned u){
  union { unsigned u; float f; } v; v.u = u << 16; return v.f;
}

// ---------------- CSR build ----------------
__global__ __launch_bounds__(256) void k_deg_count(const int* __restrict__ dst, int E, int* __restrict__ deg){
  int i = blockIdx.x*256 + threadIdx.x;
  if (i < E) atomicAdd(&deg[dst[i]], 1);
}
__global__ __launch_bounds__(256) void k_scan_blk(const int* __restrict__ deg, int* __restrict__ rowptr,
                                                  int* __restrict__ bsum, int N){
  __shared__ int ws[4];
  int tid = threadIdx.x;
  int i = blockIdx.x*256 + tid;
  int v = (i < N) ? deg[i]+1 : 0;   // +1 self-loop
  int lane = tid & 63, w = tid >> 6;
  int s = v;
  #pragma unroll
  for (int off=1; off<64; off<<=1){
    int u = __shfl_up(s, off);
    if (lane >= off) s += u;
  }
  if (lane == 63) ws[w] = s;
  __syncthreads();
  int woff = 0;
  #pragma unroll
  for (int k=0;k<4;k++) if (k < w) woff += ws[k];
  int incl = s + woff;
  if (i < N) rowptr[i] = incl - v;
  if (tid == 255) bsum[blockIdx.x] = incl;
}
__global__ __launch_bounds__(256) void k_scan_top(int* __restrict__ bsum, int nb, int* __restrict__ rowptrN){
  __shared__ int buf[256];
  int tid = threadIdx.x;
  int v = (tid < nb) ? bsum[tid] : 0;
  buf[tid] = v;
  __syncthreads();
  for (int off=1; off<256; off<<=1){
    int add = (tid >= off) ? buf[tid-off] : 0;
    __syncthreads();
    buf[tid] += add;
    __syncthreads();
  }
  if (tid < nb) bsum[tid] = buf[tid] - v;
  if (tid == 0) rowptrN[0] = buf[255];
}
__global__ __launch_bounds__(256) void k_scan_fix(int* __restrict__ rowptr, const int* __restrict__ bsum,
                                                  int* __restrict__ pos, int* __restrict__ colidx, int N){
  int i = blockIdx.x*256 + threadIdx.x;
  if (i < N){
    int r = rowptr[i] + bsum[blockIdx.x];
    rowptr[i] = r;
    colidx[r] = i;
    pos[i] = r + 1;
  }
}
__global__ __launch_bounds__(256) void k_fill_edges(const int* __restrict__ src, const int* __restrict__ dst,
                                                    int E, int* __restrict__ pos, int* __restrict__ colidx){
  int i = blockIdx.x*256 + threadIdx.x;
  if (i < E){
    int d = dst[i];
    colidx[atomicAdd(&pos[d],1)] = src[i];
  }
}

// ---------------- all weight prep in one launch ----------------
__global__ __launch_bounds__(256) void k_prep(const float* __restrict__ Wp, const float* __restrict__ W0,
                                              const float* __restrict__ W1, const float* __restrict__ Wv,
                                              const float* __restrict__ as0, const float* __restrict__ ad0,
                                              unsigned short* __restrict__ WpT, unsigned short* __restrict__ W0T4,
                                              unsigned short* __restrict__ W1T, unsigned short* __restrict__ WvT,
                                              float* __restrict__ ahs, float* __restrict__ ahd){
  int idx = blockIdx.x*256 + threadIdx.x;
  if (idx < 16384){
    int k = idx >> 6, p = idx & 63;
    WpT[p*256 + k] = f2bf(Wp[idx]);
  } else if (idx < 32768){
    int i = idx - 16384;
    int h = i >> 12, r = i & 4095, p = r >> 6, k = r & 63;
    W0T4[i] = f2bf(W0[k*256 + h*64 + p]);
  } else if (idx < 98304){
    int i = idx - 32768; int k = i >> 8, p = i & 255;
    W1T[p*256 + k] = f2bf(W1[i]);
  } else if (idx < 163840){
    int i = idx - 98304; int k = i >> 8, p = i & 255;
    WvT[p*256 + k] = f2bf(Wv[i]);
  } else if (idx < 164096){
    int i = idx - 163840;
    int h = i >> 6, d = i & 63;
    float ss = 0.f, sd = 0.f;
    for (int j=0;j<64;j++){
      float w = W0[d*256 + h*64 + j];
      ss += w * as0[h*64 + j];
      sd += w * ad0[h*64 + j];
    }
    ahs[i] = ss; ahd[i] = sd;
  }
}

// ---------------- h0 = x @ Wp + bp : direct-fragment MFMA GEMM ----------------
__global__ __launch_bounds__(256) void k_h0(const float* __restrict__ A,
                                            const unsigned short* __restrict__ Bt,
                                            const float* __restrict__ bias,
                                            unsigned short* __restrict__ C, int M, int Nn){
  int wid = blockIdx.x*4 + (threadIdx.x >> 6);
  int m0 = wid * 64;
  if (m0 >= M) return;
  int lane = threadIdx.x & 63;
  int lr = lane & 15, g = lane >> 4, lk = g*8;
  const float* Arow[4];
  #pragma unroll
  for (int m=0;m<4;m++){
    int row = m0 + m*16 + lr;
    if (row > M-1) row = M-1;
    Arow[m] = A + (size_t)row*256 + lk;
  }
  const unsigned short* Bb = Bt + (size_t)lr*256 + lk;
  f32x4 acc[4][4];
  #pragma unroll
  for (int m=0;m<4;m++)
    #pragma unroll
    for (int n=0;n<4;n++)
      #pragma unroll
      for (int j=0;j<4;j++) acc[m][n][j] = 0.f;

  #pragma unroll 2
  for (int ks=0; ks<8; ks++){
    int k0 = ks*32;
    short8 bfr[4];
    #pragma unroll
    for (int n=0;n<4;n++)
      bfr[n] = *(const short8*)(Bb + (size_t)n*16*256 + k0);
    short8 afr[4];
    #pragma unroll
    for (int m=0;m<4;m++){
      float4 u = *(const float4*)(Arow[m] + k0);
      float4 w = *(const float4*)(Arow[m] + k0 + 4);
      afr[m][0]=(short)f2bf(u.x); afr[m][1]=(short)f2bf(u.y);
      afr[m][2]=(short)f2bf(u.z); afr[m][3]=(short)f2bf(u.w);
      afr[m][4]=(short)f2bf(w.x); afr[m][5]=(short)f2bf(w.y);
      afr[m][6]=(short)f2bf(w.z); afr[m][7]=(short)f2bf(w.w);
    }
    #pragma unroll
    for (int m=0;m<4;m++)
      #pragma unroll
      for (int n=0;n<4;n++)
        acc[m][n] = __builtin_amdgcn_mfma_f32_16x16x32_bf16(afr[m], bfr[n], acc[m][n], 0,0,0);
  }
  #pragma unroll
  for (int n=0;n<4;n++){
    int col = n*16 + lr;
    float bcol = bias[col];
    #pragma unroll
    for (int m=0;m<4;m++){
      #pragma unroll
      for (int j=0;j<4;j++){
        int row = m0 + m*16 + g*4 + j;
        if (row < M){
          int t = row & 3, nn = row >> 2;
          C[(size_t)t*Nn*64 + (size_t)nn*64 + col] = f2bf(acc[m][n][j] + bcol);
        }
      }
    }
  }
}

// ---------------- fused layer-0 GEMMs: hp = ELU(agg0 @ blockdiag(W0) + b0) @ W1 ----------------
// 256 threads = 4 waves; BM=64 rows; each wave computes 16 rows x 256 cols.
__global__ __launch_bounds__(256) void k_gat01(const unsigned short* __restrict__ A,    // agg0 [M][256]
                                               const unsigned short* __restrict__ W0T4, // [4][64p][64k]
                                               const float* __restrict__ b0,
                                               const unsigned short* __restrict__ W1T,  // [256p][256k]
                                               unsigned short* __restrict__ hp, int M){
  __shared__ unsigned short H1[64][264];
  __shared__ unsigned short Bls[256][72];
  int tid = threadIdx.x;
  int m0 = blockIdx.x * 64;
  int wave = tid >> 6, lane = tid & 63;
  int lr = lane & 15, g4 = lane >> 4, lk = g4*8;
  int rbase = m0 + wave*16;

  // phase 1: h1 tile (per-head K=64 GEMM, direct fragments) -> LDS
  f32x4 acc1[16];
  #pragma unroll
  for (int q=0;q<16;q++)
    #pragma unroll
    for (int j=0;j<4;j++) acc1[q][j] = 0.f;
  int arow = rbase + lr; if (arow > M-1) arow = M-1;
  #pragma unroll
  for (int h=0;h<4;h++){
    short8 afr[2];
    #pragma unroll
    for (int ks=0;ks<2;ks++)
      afr[ks] = *(const short8*)(A + (size_t)arow*256 + h*64 + ks*32 + lk);
    #pragma unroll
    for (int nn=0;nn<4;nn++){
      #pragma unroll
      for (int ks=0;ks<2;ks++){
        short8 bfr = *(const short8*)(W0T4 + ((size_t)h*64 + nn*16 + lr)*64 + ks*32 + lk);
        acc1[h*4+nn] = __builtin_amdgcn_mfma_f32_16x16x32_bf16(afr[ks], bfr, acc1[h*4+nn], 0,0,0);
      }
    }
  }
  #pragma unroll
  for (int q=0;q<16;q++){
    int col = q*16 + lr;
    float bcol = b0[col];
    #pragma unroll
    for (int j=0;j<4;j++){
      float v = acc1[q][j] + bcol;
      v = (v > 0.f) ? v : (__expf(v) - 1.f);
      H1[wave*16 + g4*4 + j][col] = f2bf(v);
    }
  }
  __syncthreads();

  // phase 2: hp tile = H1 @ W1 (K=256), W1 slice staged per step
  f32x4 acc2[16];
  #pragma unroll
  for (int q=0;q<16;q++)
    #pragma unroll
    for (int j=0;j<4;j++) acc2[q][j] = 0.f;
  for (int k0=0;k0<256;k0+=64){
    #pragma unroll
    for (int it=0; it<8; it++){
      int idx = tid + it*256;
      int p = idx >> 3, ch = (idx & 7)*8;
      *(uint4*)(&Bls[p][ch]) = *(const uint4*)(W1T + (size_t)p*256 + k0 + ch);
    }
    __syncthreads();
    #pragma unroll
    for (int ks=0;ks<2;ks++){
      short8 afr = *(const short8*)(&H1[wave*16 + lr][k0 + ks*32 + lk]);
      #pragma unroll
      for (int q=0;q<16;q++){
        short8 bfr = *(const short8*)(&Bls[q*16 + lr][ks*32 + lk]);
        acc2[q] = __builtin_amdgcn_mfma_f32_16x16x32_bf16(afr, bfr, acc2[q], 0,0,0);
      }
    }
    __syncthreads();
  }
  #pragma unroll
  for (int q=0;q<16;q++){
    int col = q*16 + lr;
    #pragma unroll
    for (int j=0;j<4;j++){
      int row = m0 + wave*16 + g4*4 + j;
      if (row < M)
        hp[(size_t)row*256 + col] = f2bf(acc2[q][j]);
    }
  }
}

// ---------------- final GEMM with fused temporal combine in A-staging ----------------
__global__ __launch_bounds__(512) void k_gemm_fin(const unsigned short* __restrict__ embs,
                                                  const float* __restrict__ awp,
                                                  const unsigned short* __restrict__ Bt,
                                                  const float* __restrict__ bias,
                                                  float* __restrict__ C, int M){
  constexpr int K = 256, BK = 64, PAD = 8;
  __shared__ unsigned short Als[128][BK+PAD];
  __shared__ unsigned short Bls[256][BK+PAD];
  int tid = threadIdx.x;
  int m0  = blockIdx.x * 128;
  int wave = tid >> 6, lane = tid & 63;
  int wr = wave & 3, wc = wave >> 2;
  int lr = lane & 15, lk = (lane >> 4) * 8;
  float a0=awp[0], a1=awp[1], a2=awp[2], a3=awp[3];
  size_t sl = (size_t)M*256;
  f32x4 acc[2][8];
  #pragma unroll
  for (int m=0;m<2;m++)
    #pragma unroll
    for (int n=0;n<8;n++)
      #pragma unroll
      for (int j=0;j<4;j++) acc[m][n][j] = 0.f;

  for (int k0 = 0; k0 < K; k0 += BK){
    #pragma unroll
    for (int i=0;i<2;i++){
      int idx = tid + i*512;
      int r = idx >> 3, ch = (idx & 7)*8;
      int row = m0 + r;
      uint4 w = make_uint4(0,0,0,0);
      if (row < M){
        size_t o = (size_t)row*256 + k0 + ch;
        uint4 u0 = *(const uint4*)(embs + o);
        uint4 u1 = *(const uint4*)(embs + o + sl);
        uint4 u2 = *(const uint4*)(embs + o + 2*sl);
        uint4 u3 = *(const uint4*)(embs + o + 3*sl);
        const unsigned* p0=&u0.x; const unsigned* p1=&u1.x;
        const unsigned* p2=&u2.x; const unsigned* p3=&u3.x;
        unsigned* pw=&w.x;
        #pragma unroll
        for (int q=0;q<4;q++){
          float lo = a0*bf2f(p0[q]&0xffffu) + a1*bf2f(p1[q]&0xffffu) + a2*bf2f(p2[q]&0xffffu) + a3*bf2f(p3[q]&0xffffu);
          float hi = a0*bf2f(p0[q]>>16)     + a1*bf2f(p1[q]>>16)     + a2*bf2f(p2[q]>>16)     + a3*bf2f(p3[q]>>16);
          pw[q] = (unsigned)f2bf(lo) | ((unsigned)f2bf(hi) << 16);
        }
      }
      *(uint4*)(&Als[r][ch]) = w;
    }
    #pragma unroll
    for (int i=0;i<4;i++){
      int idx = tid + i*512;
      int r = idx >> 3, ch = (idx & 7)*8;
      *(uint4*)(&Bls[r][ch]) = *(const uint4*)(Bt + (size_t)r*K + k0 + ch);
    }
    __syncthreads();
    #pragma unroll
    for (int ks=0; ks<2; ks++){
      short8 afr[2], bfr[8];
      #pragma unroll
      for (int m=0;m<2;m++)
        afr[m] = *(const short8*)(&Als[wr*32 + m*16 + lr][ks*32 + lk]);
      #pragma unroll
      for (int n=0;n<8;n++)
        bfr[n] = *(const short8*)(&Bls[wc*128 + n*16 + lr][ks*32 + lk]);
      #pragma unroll
      for (int m=0;m<2;m++)
        #pragma unroll
        for (int n=0;n<8;n++)
          acc[m][n] = __builtin_amdgcn_mfma_f32_16x16x32_bf16(afr[m], bfr[n], acc[m][n], 0,0,0);
    }
    __syncthreads();
  }
  #pragma unroll
  for (int m=0;m<2;m++){
    #pragma unroll
    for (int n=0;n<8;n++){
      int col = wc*128 + n*16 + lr;
      float bcol = bias[col];
      #pragma unroll
      for (int j=0;j<4;j++){
        int row = m0 + wr*32 + m*16 + (lane>>4)*4 + j;
        if (row < M)
          C[(size_t)row*256 + col] = acc[m][n][j] + bcol;
      }
    }
  }
}

// ---------------- layer-0 logits ----------------
__global__ __launch_bounds__(256) void k_esd0(const unsigned short* __restrict__ h0,
                                              const float* __restrict__ ahs, const float* __restrict__ ahd,
                                              float* __restrict__ e_s, float* __restrict__ e_d, int M){
  int n = blockIdx.x*4 + (threadIdx.x >> 6);
  if (n >= M) return;
  int lane = threadIdx.x & 63;
  int h = lane >> 4, l4 = (lane & 15)*4;
  uint2 v = *(const uint2*)(h0 + (size_t)n*64 + l4);
  float v0 = bf2f(v.x & 0xffffu), v1 = bf2f(v.x >> 16);
  float v2 = bf2f(v.y & 0xffffu), v3 = bf2f(v.y >> 16);
  float4 as = *(const float4*)(ahs + h*64 + l4);
  float4 ad = *(const float4*)(ahd + h*64 + l4);
  float ps = v0*as.x + v1*as.y + v2*as.z + v3*as.w;
  float pd = v0*ad.x + v1*ad.y + v2*ad.z + v3*ad.w;
  #pragma unroll
  for (int off=1; off<16; off<<=1){ ps += __shfl_xor(ps,off); pd += __shfl_xor(pd,off); }
  if ((lane & 15) == 0){
    e_s[n*4+h] = ps; e_d[n*4+h] = pd;
  }
}

// ---------------- layer-0 aggregation: 2 edges per wave, 8 dims/lane ----------------
__global__ __launch_bounds__(256) void k_agg0(const unsigned short* __restrict__ h0all,
                                              const float* __restrict__ e_s, const float* __restrict__ e_d,
                                              const int* __restrict__ rowptr, const int* __restrict__ colidx,
                                              unsigned short* __restrict__ agg, int N){
  int n = blockIdx.x*4 + (threadIdx.x >> 6);
  if (n >= N) return;
  int t = blockIdx.y;
  int g = t*N + n;
  int lane = threadIdx.x & 63;
  int half = lane >> 5, l = lane & 31;
  int h = l >> 3, di = (l & 7)*8;
  int s0 = rowptr[n], s1 = rowptr[n+1];
  float ed = e_d[(size_t)g*4 + h];
  const unsigned short* h0t = h0all + (size_t)t*N*64;
  const float* est = e_s + (size_t)t*N*4;
  float z = 0.f;
  float a[8] = {0,0,0,0,0,0,0,0};
  int i = s0;
  for (; i+2 <= s1; i += 2){
    int s = colidx[i + half];
    uint4 v = *(const uint4*)(h0t + (size_t)s*64 + di);
    float e = est[s*4 + h] + ed;
    e = fmaxf(e, NEG_SLOPE*e);
    float w = __expf(e);
    z += w;
    a[0] += w*bf2f(v.x&0xffffu); a[1] += w*bf2f(v.x>>16);
    a[2] += w*bf2f(v.y&0xffffu); a[3] += w*bf2f(v.y>>16);
    a[4] += w*bf2f(v.z&0xffffu); a[5] += w*bf2f(v.z>>16);
    a[6] += w*bf2f(v.w&0xffffu); a[7] += w*bf2f(v.w>>16);
  }
  if (i < s1 && half == 0){
    int s = colidx[i];
    uint4 v = *(const uint4*)(h0t + (size_t)s*64 + di);
    float e = est[s*4 + h] + ed;
    e = fmaxf(e, NEG_SLOPE*e);
    float w = __expf(e);
    z += w;
    a[0] += w*bf2f(v.x&0xffffu); a[1] += w*bf2f(v.x>>16);
    a[2] += w*bf2f(v.y&0xffffu); a[3] += w*bf2f(v.y>>16);
    a[4] += w*bf2f(v.z&0xffffu); a[5] += w*bf2f(v.z>>16);
    a[6] += w*bf2f(v.w&0xffffu); a[7] += w*bf2f(v.w>>16);
  }
  z += __shfl_xor(z, 32);
  #pragma unroll
  for (int q=0;q<8;q++) a[q] += __shfl_xor(a[q], 32);
  if (half == 0){
    float inv = 1.f / (z + 1e-16f);
    uint4 r;
    r.x = (unsigned)f2bf(a[0]*inv) | ((unsigned)f2bf(a[1]*inv) << 16);
    r.y = (unsigned)f2bf(a[2]*inv) | ((unsigned)f2bf(a[3]*inv) << 16);
    r.z = (unsigned)f2bf(a[4]*inv) | ((unsigned)f2bf(a[5]*inv) << 16);
    r.w = (unsigned)f2bf(a[6]*inv) | ((unsigned)f2bf(a[7]*inv) << 16);
    *(uint4*)(agg + (size_t)g*256 + l*8) = r;   // l*8 == h*64 + di
  }
}

// ---------------- layer-1 logits ----------------
__global__ __launch_bounds__(256) void k_esd(const unsigned short* __restrict__ hp,
                                             const float* __restrict__ a_s, const float* __restrict__ a_d,
                                             float* __restrict__ e_s, float* __restrict__ e_d, int M){
  int n = blockIdx.x*4 + (threadIdx.x >> 6);
  if (n >= M) return;
  int lane = threadIdx.x & 63;
  uint2 v = *(const uint2*)(hp + (size_t)n*256 + lane*4);
  float v0 = bf2f(v.x & 0xffffu), v1 = bf2f(v.x >> 16);
  float v2 = bf2f(v.y & 0xffffu), v3 = bf2f(v.y >> 16);
  float4 as = *(const float4*)(a_s + lane*4);
  float4 ad = *(const float4*)(a_d + lane*4);
  float ps = v0*as.x + v1*as.y + v2*as.z + v3*as.w;
  float pd = v0*ad.x + v1*ad.y + v2*ad.z + v3*ad.w;
  #pragma unroll
  for (int off=1; off<16; off<<=1){ ps += __shfl_xor(ps,off); pd += __shfl_xor(pd,off); }
  if ((lane & 15) == 0){
    int h = lane >> 4;
    e_s[n*4+h] = ps; e_d[n*4+h] = pd;
  }
}

// ---------------- layer-1 aggregation: 2 edges per wave, 8 dims/lane + bias + ELU ----------------
__global__ __launch_bounds__(256) void k_agg(const unsigned short* __restrict__ hpall,
                                             const float* __restrict__ e_s, const float* __restrict__ e_d,
                                             const int* __restrict__ rowptr, const int* __restrict__ colidx,
                                             const float* __restrict__ bias, unsigned short* __restrict__ outb,
                                             int N){
  int n = blockIdx.x*4 + (threadIdx.x >> 6);
  if (n >= N) return;
  int t = blockIdx.y;
  int g = t*N + n;
  int lane = threadIdx.x & 63;
  int half = lane >> 5, l = lane & 31;
  int h = l >> 3, d0 = l*8;
  int s0 = rowptr[n], s1 = rowptr[n+1];
  float ed = e_d[(size_t)g*4 + h];
  const unsigned short* hpt = hpall + (size_t)t*N*256;
  const float* est = e_s + (size_t)t*N*4;
  float z = 0.f;
  float a[8] = {0,0,0,0,0,0,0,0};
  int i = s0;
  for (; i+2 <= s1; i += 2){
    int s = colidx[i + half];
    uint4 v = *(const uint4*)(hpt + (size_t)s*256 + d0);
    float e = est[s*4 + h] + ed;
    e = fmaxf(e, NEG_SLOPE*e);
    float w = __expf(e);
    z += w;
    a[0] += w*bf2f(v.x&0xffffu); a[1] += w*bf2f(v.x>>16);
    a[2] += w*bf2f(v.y&0xffffu); a[3] += w*bf2f(v.y>>16);
    a[4] += w*bf2f(v.z&0xffffu); a[5] += w*bf2f(v.z>>16);
    a[6] += w*bf2f(v.w&0xffffu); a[7] += w*bf2f(v.w>>16);
  }
  if (i < s1 && half == 0){
    int s = colidx[i];
    uint4 v = *(const uint4*)(hpt + (size_t)s*256 + d0);
    float e = est[s*4 + h] + ed;
    e = fmaxf(e, NEG_SLOPE*e);
    float w = __expf(e);
    z += w;
    a[0] += w*bf2f(v.x&0xffffu); a[1] += w*bf2f(v.x>>16);
    a[2] += w*bf2f(v.y&0xffffu); a[3] += w*bf2f(v.y>>16);
    a[4] += w*bf2f(v.z&0xffffu); a[5] += w*bf2f(v.z>>16);
    a[6] += w*bf2f(v.w&0xffffu); a[7] += w*bf2f(v.w>>16);
  }
  z += __shfl_xor(z, 32);
  #pragma unroll
  for (int q=0;q<8;q++) a[q] += __shfl_xor(a[q], 32);
  if (half == 0){
    float inv = 1.f / (z + 1e-16f);
    float4 bA = *(const float4*)(bias + d0);
    float4 bB = *(const float4*)(bias + d0 + 4);
    float o[8];
    o[0]=a[0]*inv+bA.x; o[1]=a[1]*inv+bA.y; o[2]=a[2]*inv+bA.z; o[3]=a[3]*inv+bA.w;
    o[4]=a[4]*inv+bB.x; o[5]=a[5]*inv+bB.y; o[6]=a[6]*inv+bB.z; o[7]=a[7]*inv+bB.w;
    #pragma unroll
    for (int q=0;q<8;q++) o[q] = (o[q] > 0.f) ? o[q] : (__expf(o[q]) - 1.f);
    uint4 r;
    r.x = (unsigned)f2bf(o[0]) | ((unsigned)f2bf(o[1]) << 16);
    r.y = (unsigned)f2bf(o[2]) | ((unsigned)f2bf(o[3]) << 16);
    r.z = (unsigned)f2bf(o[4]) | ((unsigned)f2bf(o[5]) << 16);
    r.w = (unsigned)f2bf(o[6]) | ((unsigned)f2bf(o[7]) << 16);
    *(uint4*)(outb + (size_t)g*256 + d0) = r;
  }
}

// ---------------- column sums, batched: 64 chunks per t ----------------
__global__ __launch_bounds__(256) void k_colsum(const unsigned short* __restrict__ emb, float* __restrict__ sums, int N){
  __shared__ float red[8][256];
  int tid = threadIdx.x;
  int t = blockIdx.x >> 6, chunk = blockIdx.x & 63;
  int rows_per = (N + 63) / 64;
  int r0 = chunk * rows_per;
  int r1 = min(N, r0 + rows_per);
  const unsigned short* base = emb + (size_t)t*N*256;
  int c0 = (tid & 31)*8, rg = tid >> 5;
  float s[8] = {0,0,0,0,0,0,0,0};
  for (int r = r0 + rg; r < r1; r += 8){
    uint4 v = *(const uint4*)(base + (size_t)r*256 + c0);
    s[0] += bf2f(v.x & 0xffffu); s[1] += bf2f(v.x >> 16);
    s[2] += bf2f(v.y & 0xffffu); s[3] += bf2f(v.y >> 16);
    s[4] += bf2f(v.z & 0xffffu); s[5] += bf2f(v.z >> 16);
    s[6] += bf2f(v.w & 0xffffu); s[7] += bf2f(v.w >> 16);
  }
  #pragma unroll
  for (int j=0;j<8;j++) red[rg][c0+j] = s[j];
  __syncthreads();
  float tot = 0.f;
  #pragma unroll
  for (int g=0;g<8;g++) tot += red[g][tid];
  atomicAdd(&sums[t*256 + tid], tot);
}

// ---------------- temporal attention weights (tiny) ----------------
__global__ __launch_bounds__(256) void k_attn(const float* __restrict__ sum_emb,
                                              const float* __restrict__ Wq, const float* __restrict__ bq,
                                              const float* __restrict__ Wk, const float* __restrict__ bk,
                                              float* __restrict__ aw, int N){
  __shared__ float mean_s[4][256];
  __shared__ float red[256];
  __shared__ float scores_s[4];
  int j = threadIdx.x;
  float invN = 1.0f/(float)N;
  #pragma unroll
  for (int t=0;t<4;t++) mean_s[t][j] = sum_emb[t*256+j]*invN;
  __syncthreads();
  float q3 = bq[j];
  float kt0=bk[j], kt1=bk[j], kt2=bk[j], kt3=bk[j];
  for (int m=0;m<256;m++){
    float wq = Wq[m*256+j];
    float wk = Wk[m*256+j];
    float m0 = mean_s[0][m], m1 = mean_s[1][m], m2 = mean_s[2][m], m3 = mean_s[3][m];
    q3  += m3*wq;
    kt0 += m0*wk; kt1 += m1*wk; kt2 += m2*wk; kt3 += m3*wk;
  }
  float kts0=kt0, kts1=kt1, kts2=kt2, kts3=kt3;
  #pragma unroll
  for (int t=0;t<4;t++){
    float ktv = (t==0)?kts0:((t==1)?kts1:((t==2)?kts2:kts3));
    red[j] = q3*ktv;
    __syncthreads();
    for (int off=128; off>0; off>>=1){
      if (j < off) red[j] += red[j+off];
      __syncthreads();
    }
    if (j==0) scores_s[t] = red[0]*(1.0f/16.0f);
    __syncthreads();
  }
  if (j==0){
    float mx = fmaxf(fmaxf(scores_s[0],scores_s[1]),fmaxf(scores_s[2],scores_s[3]));
    float w0 = __expf(scores_s[0]-mx), w1 = __expf(scores_s[1]-mx),
          w2 = __expf(scores_s[2]-mx), w3 = __expf(scores_s[3]-mx);
    float s = w0+w1+w2+w3;
    aw[0]=w0/s; aw[1]=w1/s; aw[2]=w2/s; aw[3]=w3/s;
  }
}

extern "C" void kernel_launch(void* const* d_in, const int* in_sizes, int n_in,
                              void* d_out, int out_size, void* d_ws, size_t ws_size,
                              hipStream_t stream){
  (void)n_in; (void)out_size; (void)ws_size;
  const float* x   = (const float*)d_in[0];
  const int*   ei  = (const int*)d_in[1];
  const float* Wp  = (const float*)d_in[2];
  const float* bp  = (const float*)d_in[3];
  const float* W0  = (const float*)d_in[4];
  const float* as0 = (const float*)d_in[5];
  const float* ad0 = (const float*)d_in[6];
  const float* b0  = (const float*)d_in[7];
  const float* W1  = (const float*)d_in[8];
  const float* as1 = (const float*)d_in[9];
  const float* ad1 = (const float*)d_in[10];
  const float* b1  = (const float*)d_in[11];
  const float* Wq  = (const float*)d_in[12];
  const float* bq  = (const float*)d_in[13];
  const float* Wk  = (const float*)d_in[14];
  const float* bk  = (const float*)d_in[15];
  const float* Wv  = (const float*)d_in[16];
  const float* bv  = (const float*)d_in[17];
  float* out = (float*)d_out;

  const int T = 4, FIN = 256;
  const int N = in_sizes[0] / (T*FIN);
  const int E = in_sizes[1] / 2;
  const int TN = T*N;
  const int* src = ei;
  const int* dst = ei + E;

  char* ws = (char*)d_ws;
  size_t cur = 0;
  auto alloc = [&](size_t bytes)->void*{
    void* p = ws + cur;
    cur += (bytes + 255) & ~(size_t)255;
    return p;
  };
  unsigned short* h0all = (unsigned short*)alloc((size_t)TN*64*2);
  unsigned short* bufA  = (unsigned short*)alloc((size_t)TN*256*2);   // agg0_all
  unsigned short* bufB  = (unsigned short*)alloc((size_t)TN*256*2);   // hp_all
  unsigned short* embs  = (unsigned short*)alloc((size_t)TN*256*2);
  float* e_s    = (float*)alloc((size_t)TN*4*4);
  float* e_d    = (float*)alloc((size_t)TN*4*4);
  float* sume   = (float*)alloc(4*256*4);
  float* aw     = (float*)alloc(256);
  float* ah0s   = (float*)alloc(256*4);
  float* ah0d   = (float*)alloc(256*4);
  int*   rowptr = (int*)alloc((size_t)(N+1)*4);
  int*   deg    = (int*)alloc((size_t)N*4);
  int*   pos    = (int*)alloc((size_t)N*4);
  int*   bsum   = (int*)alloc((size_t)256*4);
  int*   colidx = (int*)alloc((size_t)(E+N)*4);
  unsigned short* WpT  = (unsigned short*)alloc((size_t)64*256*2);
  unsigned short* W0T4 = (unsigned short*)alloc((size_t)4*64*64*2);
  unsigned short* W1T  = (unsigned short*)alloc((size_t)256*256*2);
  unsigned short* WvT  = (unsigned short*)alloc((size_t)256*256*2);

  int nb256 = (N+255)/256;
  int nbE   = (E+255)/256;
  int gmN   = (N+127)/128;
  int gagg  = (TN+3)/4;

  // CSR build (graph static across t and layers)
  hipMemsetAsync(deg, 0, (size_t)N*4, stream);
  k_deg_count<<<nbE,256,0,stream>>>(dst, E, deg);
  k_scan_blk<<<nb256,256,0,stream>>>(deg, rowptr, bsum, N);
  k_scan_top<<<1,256,0,stream>>>(bsum, nb256, rowptr + N);
  k_scan_fix<<<nb256,256,0,stream>>>(rowptr, bsum, pos, colidx, N);
  k_fill_edges<<<nbE,256,0,stream>>>(src, dst, E, pos, colidx);
  hipMemsetAsync(sume, 0, 4*256*4, stream);

  // weight prep
  k_prep<<<641,256,0,stream>>>(Wp, W0, W1, Wv, as0, ad0, WpT, W0T4, W1T, WvT, ah0s, ah0d);

  // h0 for all 4 timesteps
  k_h0<<<(TN/64+3)/4 + 1,256,0,stream>>>(x, WpT, bp, h0all, TN, N);

  // GAT layer 0 (batched over t): logits, gather-agg, fused blockdiag(W0)+W1 GEMM
  k_esd0<<<gagg,256,0,stream>>>(h0all, ah0s, ah0d, e_s, e_d, TN);
  k_agg0<<<dim3((N+3)/4, T),256,0,stream>>>(h0all, e_s, e_d, rowptr, colidx, bufA, N);
  k_gat01<<<(TN+63)/64,256,0,stream>>>(bufA, W0T4, b0, W1T, bufB, TN);
  // GAT layer 1
  k_esd<<<gagg,256,0,stream>>>(bufB, as1, ad1, e_s, e_d, TN);
  k_agg<<<dim3((N+3)/4, T),256,0,stream>>>(bufB, e_s, e_d, rowptr, colidx, b1, embs, N);
  // node-mean numerators for temporal attention
  k_colsum<<<256,256,0,stream>>>(embs, sume, N);

  // temporal attention weights, then final GEMM with fused combine
  k_attn<<<1,256,0,stream>>>(sume, Wq, bq, Wk, bk, aw, N);
  k_gemm_fin<<<gmN,512,0,stream>>>(embs, aw, WvT, bv, out, N);
}

// Round 9
// 422.127 us; speedup vs baseline: 4.1762x; 1.0542x over previous
//
#include <hip/hip_runtime.h>
#include <math.h>

#define NEG_SLOPE 0.2f

typedef __attribute__((ext_vector_type(8))) short short8;
typedef __attribute__((ext_vector_type(4))) float f32x4;

__device__ inline unsigned short f2bf(float f){
  union { float f; unsigned u; } v; v.f = f;
  unsigned r = v.u + 0x7fffu + ((v.u >> 16) & 1u);
  return (unsigned short)(r >> 16);
}
__device__ inline float bf2f(unsigned u){
  union { unsigned u; float f; } v; v.u = u << 16; return v.f;
}

// ---------------- CSR build ----------------
__global__ __launch_bounds__(256) void k_deg_count(const int* __restrict__ dst, int E, int* __restrict__ deg){
  int i = blockIdx.x*256 + threadIdx.x;
  if (i < E) atomicAdd(&deg[dst[i]], 1);
}
__global__ __launch_bounds__(256) void k_scan_blk(const int* __restrict__ deg, int* __restrict__ rowptr,
                                                  int* __restrict__ bsum, int N){
  __shared__ int ws[4];
  int tid = threadIdx.x;
  int i = blockIdx.x*256 + tid;
  int v = (i < N) ? deg[i]+1 : 0;   // +1 self-loop
  int lane = tid & 63, w = tid >> 6;
  int s = v;
  #pragma unroll
  for (int off=1; off<64; off<<=1){
    int u = __shfl_up(s, off);
    if (lane >= off) s += u;
  }
  if (lane == 63) ws[w] = s;
  __syncthreads();
  int woff = 0;
  #pragma unroll
  for (int k=0;k<4;k++) if (k < w) woff += ws[k];
  int incl = s + woff;
  if (i < N) rowptr[i] = incl - v;
  if (tid == 255) bsum[blockIdx.x] = incl;
}
__global__ __launch_bounds__(256) void k_scan_top(int* __restrict__ bsum, int nb, int* __restrict__ rowptrN){
  __shared__ int buf[256];
  int tid = threadIdx.x;
  int v = (tid < nb) ? bsum[tid] : 0;
  buf[tid] = v;
  __syncthreads();
  for (int off=1; off<256; off<<=1){
    int add = (tid >= off) ? buf[tid-off] : 0;
    __syncthreads();
    buf[tid] += add;
    __syncthreads();
  }
  if (tid < nb) bsum[tid] = buf[tid] - v;
  if (tid == 0) rowptrN[0] = buf[255];
}
__global__ __launch_bounds__(256) void k_scan_fix(int* __restrict__ rowptr, const int* __restrict__ bsum,
                                                  int* __restrict__ pos, int* __restrict__ colidx, int N){
  int i = blockIdx.x*256 + threadIdx.x;
  if (i < N){
    int r = rowptr[i] + bsum[blockIdx.x];
    rowptr[i] = r;
    colidx[r] = i;
    pos[i] = r + 1;
  }
}
__global__ __launch_bounds__(256) void k_fill_edges(const int* __restrict__ src, const int* __restrict__ dst,
                                                    int E, int* __restrict__ pos, int* __restrict__ colidx){
  int i = blockIdx.x*256 + threadIdx.x;
  if (i < E){
    int d = dst[i];
    colidx[atomicAdd(&pos[d],1)] = src[i];
  }
}

// ---------------- all weight prep in one launch ----------------
__global__ __launch_bounds__(256) void k_prep(const float* __restrict__ Wp, const float* __restrict__ W0,
                                              const float* __restrict__ W1, const float* __restrict__ Wv,
                                              const float* __restrict__ as0, const float* __restrict__ ad0,
                                              unsigned short* __restrict__ WpT, unsigned short* __restrict__ W0T4,
                                              unsigned short* __restrict__ W1T, unsigned short* __restrict__ WvT,
                                              float* __restrict__ ahs, float* __restrict__ ahd){
  int idx = blockIdx.x*256 + threadIdx.x;
  if (idx < 16384){
    int k = idx >> 6, p = idx & 63;
    WpT[p*256 + k] = f2bf(Wp[idx]);
  } else if (idx < 32768){
    int i = idx - 16384;
    int h = i >> 12, r = i & 4095, p = r >> 6, k = r & 63;
    W0T4[i] = f2bf(W0[k*256 + h*64 + p]);
  } else if (idx < 98304){
    int i = idx - 32768; int k = i >> 8, p = i & 255;
    W1T[p*256 + k] = f2bf(W1[i]);
  } else if (idx < 163840){
    int i = idx - 98304; int k = i >> 8, p = i & 255;
    WvT[p*256 + k] = f2bf(Wv[i]);
  } else if (idx < 164096){
    int i = idx - 163840;
    int h = i >> 6, d = i & 63;
    float ss = 0.f, sd = 0.f;
    for (int j=0;j<64;j++){
      float w = W0[d*256 + h*64 + j];
      ss += w * as0[h*64 + j];
      sd += w * ad0[h*64 + j];
    }
    ahs[i] = ss; ahd[i] = sd;
  }
}

// ---------------- h0 = x @ Wp + bp : direct-fragment MFMA GEMM ----------------
__global__ __launch_bounds__(256) void k_h0(const float* __restrict__ A,
                                            const unsigned short* __restrict__ Bt,
                                            const float* __restrict__ bias,
                                            unsigned short* __restrict__ C, int M, int Nn){
  int wid = blockIdx.x*4 + (threadIdx.x >> 6);
  int m0 = wid * 64;
  if (m0 >= M) return;
  int lane = threadIdx.x & 63;
  int lr = lane & 15, g = lane >> 4, lk = g*8;
  const float* Arow[4];
  #pragma unroll
  for (int m=0;m<4;m++){
    int row = m0 + m*16 + lr;
    if (row > M-1) row = M-1;
    Arow[m] = A + (size_t)row*256 + lk;
  }
  const unsigned short* Bb = Bt + (size_t)lr*256 + lk;
  f32x4 acc[4][4];
  #pragma unroll
  for (int m=0;m<4;m++)
    #pragma unroll
    for (int n=0;n<4;n++)
      #pragma unroll
      for (int j=0;j<4;j++) acc[m][n][j] = 0.f;

  #pragma unroll 2
  for (int ks=0; ks<8; ks++){
    int k0 = ks*32;
    short8 bfr[4];
    #pragma unroll
    for (int n=0;n<4;n++)
      bfr[n] = *(const short8*)(Bb + (size_t)n*16*256 + k0);
    short8 afr[4];
    #pragma unroll
    for (int m=0;m<4;m++){
      float4 u = *(const float4*)(Arow[m] + k0);
      float4 w = *(const float4*)(Arow[m] + k0 + 4);
      afr[m][0]=(short)f2bf(u.x); afr[m][1]=(short)f2bf(u.y);
      afr[m][2]=(short)f2bf(u.z); afr[m][3]=(short)f2bf(u.w);
      afr[m][4]=(short)f2bf(w.x); afr[m][5]=(short)f2bf(w.y);
      afr[m][6]=(short)f2bf(w.z); afr[m][7]=(short)f2bf(w.w);
    }
    #pragma unroll
    for (int m=0;m<4;m++)
      #pragma unroll
      for (int n=0;n<4;n++)
        acc[m][n] = __builtin_amdgcn_mfma_f32_16x16x32_bf16(afr[m], bfr[n], acc[m][n], 0,0,0);
  }
  #pragma unroll
  for (int n=0;n<4;n++){
    int col = n*16 + lr;
    float bcol = bias[col];
    #pragma unroll
    for (int m=0;m<4;m++){
      #pragma unroll
      for (int j=0;j<4;j++){
        int row = m0 + m*16 + g*4 + j;
        if (row < M){
          int t = row & 3, nn = row >> 2;
          C[(size_t)t*Nn*64 + (size_t)nn*64 + col] = f2bf(acc[m][n][j] + bcol);
        }
      }
    }
  }
}

// ---------------- fused layer-0 GEMMs: hp = ELU(agg0 @ blockdiag(W0) + b0) @ W1 ----------------
__global__ __launch_bounds__(256) void k_gat01(const unsigned short* __restrict__ A,
                                               const unsigned short* __restrict__ W0T4,
                                               const float* __restrict__ b0,
                                               const unsigned short* __restrict__ W1T,
                                               unsigned short* __restrict__ hp, int M){
  __shared__ unsigned short H1[64][264];
  __shared__ unsigned short Bls[256][72];
  int tid = threadIdx.x;
  int m0 = blockIdx.x * 64;
  int wave = tid >> 6, lane = tid & 63;
  int lr = lane & 15, g4 = lane >> 4, lk = g4*8;
  int rbase = m0 + wave*16;

  f32x4 acc1[16];
  #pragma unroll
  for (int q=0;q<16;q++)
    #pragma unroll
    for (int j=0;j<4;j++) acc1[q][j] = 0.f;
  int arow = rbase + lr; if (arow > M-1) arow = M-1;
  #pragma unroll
  for (int h=0;h<4;h++){
    short8 afr[2];
    #pragma unroll
    for (int ks=0;ks<2;ks++)
      afr[ks] = *(const short8*)(A + (size_t)arow*256 + h*64 + ks*32 + lk);
    #pragma unroll
    for (int nn=0;nn<4;nn++){
      #pragma unroll
      for (int ks=0;ks<2;ks++){
        short8 bfr = *(const short8*)(W0T4 + ((size_t)h*64 + nn*16 + lr)*64 + ks*32 + lk);
        acc1[h*4+nn] = __builtin_amdgcn_mfma_f32_16x16x32_bf16(afr[ks], bfr, acc1[h*4+nn], 0,0,0);
      }
    }
  }
  #pragma unroll
  for (int q=0;q<16;q++){
    int col = q*16 + lr;
    float bcol = b0[col];
    #pragma unroll
    for (int j=0;j<4;j++){
      float v = acc1[q][j] + bcol;
      v = (v > 0.f) ? v : (__expf(v) - 1.f);
      H1[wave*16 + g4*4 + j][col] = f2bf(v);
    }
  }
  __syncthreads();

  f32x4 acc2[16];
  #pragma unroll
  for (int q=0;q<16;q++)
    #pragma unroll
    for (int j=0;j<4;j++) acc2[q][j] = 0.f;
  for (int k0=0;k0<256;k0+=64){
    #pragma unroll
    for (int it=0; it<8; it++){
      int idx = tid + it*256;
      int p = idx >> 3, ch = (idx & 7)*8;
      *(uint4*)(&Bls[p][ch]) = *(const uint4*)(W1T + (size_t)p*256 + k0 + ch);
    }
    __syncthreads();
    #pragma unroll
    for (int ks=0;ks<2;ks++){
      short8 afr = *(const short8*)(&H1[wave*16 + lr][k0 + ks*32 + lk]);
      #pragma unroll
      for (int q=0;q<16;q++){
        short8 bfr = *(const short8*)(&Bls[q*16 + lr][ks*32 + lk]);
        acc2[q] = __builtin_amdgcn_mfma_f32_16x16x32_bf16(afr, bfr, acc2[q], 0,0,0);
      }
    }
    __syncthreads();
  }
  #pragma unroll
  for (int q=0;q<16;q++){
    int col = q*16 + lr;
    #pragma unroll
    for (int j=0;j<4;j++){
      int row = m0 + wave*16 + g4*4 + j;
      if (row < M)
        hp[(size_t)row*256 + col] = f2bf(acc2[q][j]);
    }
  }
}

// ---------------- final GEMM with fused temporal combine in A-staging ----------------
__global__ __launch_bounds__(512) void k_gemm_fin(const unsigned short* __restrict__ embs,
                                                  const float* __restrict__ awp,
                                                  const unsigned short* __restrict__ Bt,
                                                  const float* __restrict__ bias,
                                                  float* __restrict__ C, int M){
  constexpr int K = 256, BK = 64, PAD = 8;
  __shared__ unsigned short Als[128][BK+PAD];
  __shared__ unsigned short Bls[256][BK+PAD];
  int tid = threadIdx.x;
  int m0  = blockIdx.x * 128;
  int wave = tid >> 6, lane = tid & 63;
  int wr = wave & 3, wc = wave >> 2;
  int lr = lane & 15, lk = (lane >> 4) * 8;
  float a0=awp[0], a1=awp[1], a2=awp[2], a3=awp[3];
  size_t sl = (size_t)M*256;
  f32x4 acc[2][8];
  #pragma unroll
  for (int m=0;m<2;m++)
    #pragma unroll
    for (int n=0;n<8;n++)
      #pragma unroll
      for (int j=0;j<4;j++) acc[m][n][j] = 0.f;

  for (int k0 = 0; k0 < K; k0 += BK){
    #pragma unroll
    for (int i=0;i<2;i++){
      int idx = tid + i*512;
      int r = idx >> 3, ch = (idx & 7)*8;
      int row = m0 + r;
      uint4 w = make_uint4(0,0,0,0);
      if (row < M){
        size_t o = (size_t)row*256 + k0 + ch;
        uint4 u0 = *(const uint4*)(embs + o);
        uint4 u1 = *(const uint4*)(embs + o + sl);
        uint4 u2 = *(const uint4*)(embs + o + 2*sl);
        uint4 u3 = *(const uint4*)(embs + o + 3*sl);
        const unsigned* p0=&u0.x; const unsigned* p1=&u1.x;
        const unsigned* p2=&u2.x; const unsigned* p3=&u3.x;
        unsigned* pw=&w.x;
        #pragma unroll
        for (int q=0;q<4;q++){
          float lo = a0*bf2f(p0[q]&0xffffu) + a1*bf2f(p1[q]&0xffffu) + a2*bf2f(p2[q]&0xffffu) + a3*bf2f(p3[q]&0xffffu);
          float hi = a0*bf2f(p0[q]>>16)     + a1*bf2f(p1[q]>>16)     + a2*bf2f(p2[q]>>16)     + a3*bf2f(p3[q]>>16);
          pw[q] = (unsigned)f2bf(lo) | ((unsigned)f2bf(hi) << 16);
        }
      }
      *(uint4*)(&Als[r][ch]) = w;
    }
    #pragma unroll
    for (int i=0;i<4;i++){
      int idx = tid + i*512;
      int r = idx >> 3, ch = (idx & 7)*8;
      *(uint4*)(&Bls[r][ch]) = *(const uint4*)(Bt + (size_t)r*K + k0 + ch);
    }
    __syncthreads();
    #pragma unroll
    for (int ks=0; ks<2; ks++){
      short8 afr[2], bfr[8];
      #pragma unroll
      for (int m=0;m<2;m++)
        afr[m] = *(const short8*)(&Als[wr*32 + m*16 + lr][ks*32 + lk]);
      #pragma unroll
      for (int n=0;n<8;n++)
        bfr[n] = *(const short8*)(&Bls[wc*128 + n*16 + lr][ks*32 + lk]);
      #pragma unroll
      for (int m=0;m<2;m++)
        #pragma unroll
        for (int n=0;n<8;n++)
          acc[m][n] = __builtin_amdgcn_mfma_f32_16x16x32_bf16(afr[m], bfr[n], acc[m][n], 0,0,0);
    }
    __syncthreads();
  }
  #pragma unroll
  for (int m=0;m<2;m++){
    #pragma unroll
    for (int n=0;n<8;n++){
      int col = wc*128 + n*16 + lr;
      float bcol = bias[col];
      #pragma unroll
      for (int j=0;j<4;j++){
        int row = m0 + wr*32 + m*16 + (lane>>4)*4 + j;
        if (row < M)
          C[(size_t)row*256 + col] = acc[m][n][j] + bcol;
      }
    }
  }
}

// ---------------- layer-0 logits ----------------
__global__ __launch_bounds__(256) void k_esd0(const unsigned short* __restrict__ h0,
                                              const float* __restrict__ ahs, const float* __restrict__ ahd,
                                              float* __restrict__ e_s, float* __restrict__ e_d, int M){
  int n = blockIdx.x*4 + (threadIdx.x >> 6);
  if (n >= M) return;
  int lane = threadIdx.x & 63;
  int h = lane >> 4, l4 = (lane & 15)*4;
  uint2 v = *(const uint2*)(h0 + (size_t)n*64 + l4);
  float v0 = bf2f(v.x & 0xffffu), v1 = bf2f(v.x >> 16);
  float v2 = bf2f(v.y & 0xffffu), v3 = bf2f(v.y >> 16);
  float4 as = *(const float4*)(ahs + h*64 + l4);
  float4 ad = *(const float4*)(ahd + h*64 + l4);
  float ps = v0*as.x + v1*as.y + v2*as.z + v3*as.w;
  float pd = v0*ad.x + v1*ad.y + v2*ad.z + v3*ad.w;
  #pragma unroll
  for (int off=1; off<16; off<<=1){ ps += __shfl_xor(ps,off); pd += __shfl_xor(pd,off); }
  if ((lane & 15) == 0){
    e_s[n*4+h] = ps; e_d[n*4+h] = pd;
  }
}

// ---------------- layer-0 aggregation: 2 edges/wave, 2-deep pair unroll (4 rows in flight) ----------------
__global__ __launch_bounds__(256) void k_agg0(const unsigned short* __restrict__ h0all,
                                              const float* __restrict__ e_s, const float* __restrict__ e_d,
                                              const int* __restrict__ rowptr, const int* __restrict__ colidx,
                                              unsigned short* __restrict__ agg, int N){
  int n = blockIdx.x*4 + (threadIdx.x >> 6);
  if (n >= N) return;
  int t = blockIdx.y;
  int g = t*N + n;
  int lane = threadIdx.x & 63;
  int half = lane >> 5, l = lane & 31;
  int h = l >> 3, di = (l & 7)*8;
  int s0 = rowptr[n], s1 = rowptr[n+1];
  float ed = e_d[(size_t)g*4 + h];
  const unsigned short* h0t = h0all + (size_t)t*N*64;
  const float* est = e_s + (size_t)t*N*4;
  float z = 0.f;
  float a[8] = {0,0,0,0,0,0,0,0};
  int i = s0;
  for (; i+4 <= s1; i += 4){
    int sA = colidx[i + half];
    int sB = colidx[i + 2 + half];
    uint4 vA = *(const uint4*)(h0t + (size_t)sA*64 + di);
    uint4 vB = *(const uint4*)(h0t + (size_t)sB*64 + di);
    float eA = est[sA*4 + h] + ed;
    float eB = est[sB*4 + h] + ed;
    eA = fmaxf(eA, NEG_SLOPE*eA); eB = fmaxf(eB, NEG_SLOPE*eB);
    float wA = __expf(eA), wB = __expf(eB);
    z += wA + wB;
    a[0] += wA*bf2f(vA.x&0xffffu) + wB*bf2f(vB.x&0xffffu);
    a[1] += wA*bf2f(vA.x>>16)     + wB*bf2f(vB.x>>16);
    a[2] += wA*bf2f(vA.y&0xffffu) + wB*bf2f(vB.y&0xffffu);
    a[3] += wA*bf2f(vA.y>>16)     + wB*bf2f(vB.y>>16);
    a[4] += wA*bf2f(vA.z&0xffffu) + wB*bf2f(vB.z&0xffffu);
    a[5] += wA*bf2f(vA.z>>16)     + wB*bf2f(vB.z>>16);
    a[6] += wA*bf2f(vA.w&0xffffu) + wB*bf2f(vB.w&0xffffu);
    a[7] += wA*bf2f(vA.w>>16)     + wB*bf2f(vB.w>>16);
  }
  for (; i+2 <= s1; i += 2){
    int s = colidx[i + half];
    uint4 v = *(const uint4*)(h0t + (size_t)s*64 + di);
    float e = est[s*4 + h] + ed;
    e = fmaxf(e, NEG_SLOPE*e);
    float w = __expf(e);
    z += w;
    a[0] += w*bf2f(v.x&0xffffu); a[1] += w*bf2f(v.x>>16);
    a[2] += w*bf2f(v.y&0xffffu); a[3] += w*bf2f(v.y>>16);
    a[4] += w*bf2f(v.z&0xffffu); a[5] += w*bf2f(v.z>>16);
    a[6] += w*bf2f(v.w&0xffffu); a[7] += w*bf2f(v.w>>16);
  }
  if (i < s1 && half == 0){
    int s = colidx[i];
    uint4 v = *(const uint4*)(h0t + (size_t)s*64 + di);
    float e = est[s*4 + h] + ed;
    e = fmaxf(e, NEG_SLOPE*e);
    float w = __expf(e);
    z += w;
    a[0] += w*bf2f(v.x&0xffffu); a[1] += w*bf2f(v.x>>16);
    a[2] += w*bf2f(v.y&0xffffu); a[3] += w*bf2f(v.y>>16);
    a[4] += w*bf2f(v.z&0xffffu); a[5] += w*bf2f(v.z>>16);
    a[6] += w*bf2f(v.w&0xffffu); a[7] += w*bf2f(v.w>>16);
  }
  z += __shfl_xor(z, 32);
  #pragma unroll
  for (int q=0;q<8;q++) a[q] += __shfl_xor(a[q], 32);
  if (half == 0){
    float inv = 1.f / (z + 1e-16f);
    uint4 r;
    r.x = (unsigned)f2bf(a[0]*inv) | ((unsigned)f2bf(a[1]*inv) << 16);
    r.y = (unsigned)f2bf(a[2]*inv) | ((unsigned)f2bf(a[3]*inv) << 16);
    r.z = (unsigned)f2bf(a[4]*inv) | ((unsigned)f2bf(a[5]*inv) << 16);
    r.w = (unsigned)f2bf(a[6]*inv) | ((unsigned)f2bf(a[7]*inv) << 16);
    *(uint4*)(agg + (size_t)g*256 + l*8) = r;
  }
}

// ---------------- layer-1 logits ----------------
__global__ __launch_bounds__(256) void k_esd(const unsigned short* __restrict__ hp,
                                             const float* __restrict__ a_s, const float* __restrict__ a_d,
                                             float* __restrict__ e_s, float* __restrict__ e_d, int M){
  int n = blockIdx.x*4 + (threadIdx.x >> 6);
  if (n >= M) return;
  int lane = threadIdx.x & 63;
  uint2 v = *(const uint2*)(hp + (size_t)n*256 + lane*4);
  float v0 = bf2f(v.x & 0xffffu), v1 = bf2f(v.x >> 16);
  float v2 = bf2f(v.y & 0xffffu), v3 = bf2f(v.y >> 16);
  float4 as = *(const float4*)(a_s + lane*4);
  float4 ad = *(const float4*)(a_d + lane*4);
  float ps = v0*as.x + v1*as.y + v2*as.z + v3*as.w;
  float pd = v0*ad.x + v1*ad.y + v2*ad.z + v3*ad.w;
  #pragma unroll
  for (int off=1; off<16; off<<=1){ ps += __shfl_xor(ps,off); pd += __shfl_xor(pd,off); }
  if ((lane & 15) == 0){
    int h = lane >> 4;
    e_s[n*4+h] = ps; e_d[n*4+h] = pd;
  }
}

// ---------------- layer-1 aggregation: 2 edges/wave, 2-deep pair unroll + bias + ELU ----------------
__global__ __launch_bounds__(256) void k_agg(const unsigned short* __restrict__ hpall,
                                             const float* __restrict__ e_s, const float* __restrict__ e_d,
                                             const int* __restrict__ rowptr, const int* __restrict__ colidx,
                                             const float* __restrict__ bias, unsigned short* __restrict__ outb,
                                             int N){
  int n = blockIdx.x*4 + (threadIdx.x >> 6);
  if (n >= N) return;
  int t = blockIdx.y;
  int g = t*N + n;
  int lane = threadIdx.x & 63;
  int half = lane >> 5, l = lane & 31;
  int h = l >> 3, d0 = l*8;
  int s0 = rowptr[n], s1 = rowptr[n+1];
  float ed = e_d[(size_t)g*4 + h];
  const unsigned short* hpt = hpall + (size_t)t*N*256;
  const float* est = e_s + (size_t)t*N*4;
  float z = 0.f;
  float a[8] = {0,0,0,0,0,0,0,0};
  int i = s0;
  for (; i+4 <= s1; i += 4){
    int sA = colidx[i + half];
    int sB = colidx[i + 2 + half];
    uint4 vA = *(const uint4*)(hpt + (size_t)sA*256 + d0);
    uint4 vB = *(const uint4*)(hpt + (size_t)sB*256 + d0);
    float eA = est[sA*4 + h] + ed;
    float eB = est[sB*4 + h] + ed;
    eA = fmaxf(eA, NEG_SLOPE*eA); eB = fmaxf(eB, NEG_SLOPE*eB);
    float wA = __expf(eA), wB = __expf(eB);
    z += wA + wB;
    a[0] += wA*bf2f(vA.x&0xffffu) + wB*bf2f(vB.x&0xffffu);
    a[1] += wA*bf2f(vA.x>>16)     + wB*bf2f(vB.x>>16);
    a[2] += wA*bf2f(vA.y&0xffffu) + wB*bf2f(vB.y&0xffffu);
    a[3] += wA*bf2f(vA.y>>16)     + wB*bf2f(vB.y>>16);
    a[4] += wA*bf2f(vA.z&0xffffu) + wB*bf2f(vB.z&0xffffu);
    a[5] += wA*bf2f(vA.z>>16)     + wB*bf2f(vB.z>>16);
    a[6] += wA*bf2f(vA.w&0xffffu) + wB*bf2f(vB.w&0xffffu);
    a[7] += wA*bf2f(vA.w>>16)     + wB*bf2f(vB.w>>16);
  }
  for (; i+2 <= s1; i += 2){
    int s = colidx[i + half];
    uint4 v = *(const uint4*)(hpt + (size_t)s*256 + d0);
    float e = est[s*4 + h] + ed;
    e = fmaxf(e, NEG_SLOPE*e);
    float w = __expf(e);
    z += w;
    a[0] += w*bf2f(v.x&0xffffu); a[1] += w*bf2f(v.x>>16);
    a[2] += w*bf2f(v.y&0xffffu); a[3] += w*bf2f(v.y>>16);
    a[4] += w*bf2f(v.z&0xffffu); a[5] += w*bf2f(v.z>>16);
    a[6] += w*bf2f(v.w&0xffffu); a[7] += w*bf2f(v.w>>16);
  }
  if (i < s1 && half == 0){
    int s = colidx[i];
    uint4 v = *(const uint4*)(hpt + (size_t)s*256 + d0);
    float e = est[s*4 + h] + ed;
    e = fmaxf(e, NEG_SLOPE*e);
    float w = __expf(e);
    z += w;
    a[0] += w*bf2f(v.x&0xffffu); a[1] += w*bf2f(v.x>>16);
    a[2] += w*bf2f(v.y&0xffffu); a[3] += w*bf2f(v.y>>16);
    a[4] += w*bf2f(v.z&0xffffu); a[5] += w*bf2f(v.z>>16);
    a[6] += w*bf2f(v.w&0xffffu); a[7] += w*bf2f(v.w>>16);
  }
  z += __shfl_xor(z, 32);
  #pragma unroll
  for (int q=0;q<8;q++) a[q] += __shfl_xor(a[q], 32);
  if (half == 0){
    float inv = 1.f / (z + 1e-16f);
    float4 bA = *(const float4*)(bias + d0);
    float4 bB = *(const float4*)(bias + d0 + 4);
    float o[8];
    o[0]=a[0]*inv+bA.x; o[1]=a[1]*inv+bA.y; o[2]=a[2]*inv+bA.z; o[3]=a[3]*inv+bA.w;
    o[4]=a[4]*inv+bB.x; o[5]=a[5]*inv+bB.y; o[6]=a[6]*inv+bB.z; o[7]=a[7]*inv+bB.w;
    #pragma unroll
    for (int q=0;q<8;q++) o[q] = (o[q] > 0.f) ? o[q] : (__expf(o[q]) - 1.f);
    uint4 r;
    r.x = (unsigned)f2bf(o[0]) | ((unsigned)f2bf(o[1]) << 16);
    r.y = (unsigned)f2bf(o[2]) | ((unsigned)f2bf(o[3]) << 16);
    r.z = (unsigned)f2bf(o[4]) | ((unsigned)f2bf(o[5]) << 16);
    r.w = (unsigned)f2bf(o[6]) | ((unsigned)f2bf(o[7]) << 16);
    *(uint4*)(outb + (size_t)g*256 + d0) = r;
  }
}

// ---------------- column sums, batched: 64 chunks per t ----------------
__global__ __launch_bounds__(256) void k_colsum(const unsigned short* __restrict__ emb, float* __restrict__ sums, int N){
  __shared__ float red[8][256];
  int tid = threadIdx.x;
  int t = blockIdx.x >> 6, chunk = blockIdx.x & 63;
  int rows_per = (N + 63) / 64;
  int r0 = chunk * rows_per;
  int r1 = min(N, r0 + rows_per);
  const unsigned short* base = emb + (size_t)t*N*256;
  int c0 = (tid & 31)*8, rg = tid >> 5;
  float s[8] = {0,0,0,0,0,0,0,0};
  for (int r = r0 + rg; r < r1; r += 8){
    uint4 v = *(const uint4*)(base + (size_t)r*256 + c0);
    s[0] += bf2f(v.x & 0xffffu); s[1] += bf2f(v.x >> 16);
    s[2] += bf2f(v.y & 0xffffu); s[3] += bf2f(v.y >> 16);
    s[4] += bf2f(v.z & 0xffffu); s[5] += bf2f(v.z >> 16);
    s[6] += bf2f(v.w & 0xffffu); s[7] += bf2f(v.w >> 16);
  }
  #pragma unroll
  for (int j=0;j<8;j++) red[rg][c0+j] = s[j];
  __syncthreads();
  float tot = 0.f;
  #pragma unroll
  for (int g=0;g<8;g++) tot += red[g][tid];
  atomicAdd(&sums[t*256 + tid], tot);
}

// ---------------- temporal attention weights (tiny) ----------------
__global__ __launch_bounds__(256) void k_attn(const float* __restrict__ sum_emb,
                                              const float* __restrict__ Wq, const float* __restrict__ bq,
                                              const float* __restrict__ Wk, const float* __restrict__ bk,
                                              float* __restrict__ aw, int N){
  __shared__ float mean_s[4][256];
  __shared__ float red[256];
  __shared__ float scores_s[4];
  int j = threadIdx.x;
  float invN = 1.0f/(float)N;
  #pragma unroll
  for (int t=0;t<4;t++) mean_s[t][j] = sum_emb[t*256+j]*invN;
  __syncthreads();
  float q3 = bq[j];
  float kt0=bk[j], kt1=bk[j], kt2=bk[j], kt3=bk[j];
  for (int m=0;m<256;m++){
    float wq = Wq[m*256+j];
    float wk = Wk[m*256+j];
    float m0 = mean_s[0][m], m1 = mean_s[1][m], m2 = mean_s[2][m], m3 = mean_s[3][m];
    q3  += m3*wq;
    kt0 += m0*wk; kt1 += m1*wk; kt2 += m2*wk; kt3 += m3*wk;
  }
  float kts0=kt0, kts1=kt1, kts2=kt2, kts3=kt3;
  #pragma unroll
  for (int t=0;t<4;t++){
    float ktv = (t==0)?kts0:((t==1)?kts1:((t==2)?kts2:kts3));
    red[j] = q3*ktv;
    __syncthreads();
    for (int off=128; off>0; off>>=1){
      if (j < off) red[j] += red[j+off];
      __syncthreads();
    }
    if (j==0) scores_s[t] = red[0]*(1.0f/16.0f);
    __syncthreads();
  }
  if (j==0){
    float mx = fmaxf(fmaxf(scores_s[0],scores_s[1]),fmaxf(scores_s[2],scores_s[3]));
    float w0 = __expf(scores_s[0]-mx), w1 = __expf(scores_s[1]-mx),
          w2 = __expf(scores_s[2]-mx), w3 = __expf(scores_s[3]-mx);
    float s = w0+w1+w2+w3;
    aw[0]=w0/s; aw[1]=w1/s; aw[2]=w2/s; aw[3]=w3/s;
  }
}

extern "C" void kernel_launch(void* const* d_in, const int* in_sizes, int n_in,
                              void* d_out, int out_size, void* d_ws, size_t ws_size,
                              hipStream_t stream){
  (void)n_in; (void)out_size; (void)ws_size;
  const float* x   = (const float*)d_in[0];
  const int*   ei  = (const int*)d_in[1];
  const float* Wp  = (const float*)d_in[2];
  const float* bp  = (const float*)d_in[3];
  const float* W0  = (const float*)d_in[4];
  const float* as0 = (const float*)d_in[5];
  const float* ad0 = (const float*)d_in[6];
  const float* b0  = (const float*)d_in[7];
  const float* W1  = (const float*)d_in[8];
  const float* as1 = (const float*)d_in[9];
  const float* ad1 = (const float*)d_in[10];
  const float* b1  = (const float*)d_in[11];
  const float* Wq  = (const float*)d_in[12];
  const float* bq  = (const float*)d_in[13];
  const float* Wk  = (const float*)d_in[14];
  const float* bk  = (const float*)d_in[15];
  const float* Wv  = (const float*)d_in[16];
  const float* bv  = (const float*)d_in[17];
  float* out = (float*)d_out;

  const int T = 4, FIN = 256;
  const int N = in_sizes[0] / (T*FIN);
  const int E = in_sizes[1] / 2;
  const int TN = T*N;
  const int* src = ei;
  const int* dst = ei + E;

  char* ws = (char*)d_ws;
  size_t cur = 0;
  auto alloc = [&](size_t bytes)->void*{
    void* p = ws + cur;
    cur += (bytes + 255) & ~(size_t)255;
    return p;
  };
  unsigned short* h0all = (unsigned short*)alloc((size_t)TN*64*2);
  unsigned short* bufA  = (unsigned short*)alloc((size_t)TN*256*2);   // agg0_all
  unsigned short* bufB  = (unsigned short*)alloc((size_t)TN*256*2);   // hp_all
  unsigned short* embs  = (unsigned short*)alloc((size_t)TN*256*2);
  float* e_s    = (float*)alloc((size_t)TN*4*4);
  float* e_d    = (float*)alloc((size_t)TN*4*4);
  float* sume   = (float*)alloc(4*256*4);
  float* aw     = (float*)alloc(256);
  float* ah0s   = (float*)alloc(256*4);
  float* ah0d   = (float*)alloc(256*4);
  int*   rowptr = (int*)alloc((size_t)(N+1)*4);
  int*   deg    = (int*)alloc((size_t)N*4);
  int*   pos    = (int*)alloc((size_t)N*4);
  int*   bsum   = (int*)alloc((size_t)256*4);
  int*   colidx = (int*)alloc((size_t)(E+N)*4);
  unsigned short* WpT  = (unsigned short*)alloc((size_t)64*256*2);
  unsigned short* W0T4 = (unsigned short*)alloc((size_t)4*64*64*2);
  unsigned short* W1T  = (unsigned short*)alloc((size_t)256*256*2);
  unsigned short* WvT  = (unsigned short*)alloc((size_t)256*256*2);

  int nb256 = (N+255)/256;
  int nbE   = (E+255)/256;
  int gmN   = (N+127)/128;
  int gagg  = (TN+3)/4;

  // CSR build (graph static across t and layers)
  hipMemsetAsync(deg, 0, (size_t)N*4, stream);
  k_deg_count<<<nbE,256,0,stream>>>(dst, E, deg);
  k_scan_blk<<<nb256,256,0,stream>>>(deg, rowptr, bsum, N);
  k_scan_top<<<1,256,0,stream>>>(bsum, nb256, rowptr + N);
  k_scan_fix<<<nb256,256,0,stream>>>(rowptr, bsum, pos, colidx, N);
  k_fill_edges<<<nbE,256,0,stream>>>(src, dst, E, pos, colidx);
  hipMemsetAsync(sume, 0, 4*256*4, stream);

  // weight prep
  k_prep<<<641,256,0,stream>>>(Wp, W0, W1, Wv, as0, ad0, WpT, W0T4, W1T, WvT, ah0s, ah0d);

  // h0 for all 4 timesteps
  k_h0<<<(TN/64+3)/4 + 1,256,0,stream>>>(x, WpT, bp, h0all, TN, N);

  // GAT layer 0 (batched over t): logits, gather-agg, fused blockdiag(W0)+W1 GEMM
  k_esd0<<<gagg,256,0,stream>>>(h0all, ah0s, ah0d, e_s, e_d, TN);
  k_agg0<<<dim3((N+3)/4, T),256,0,stream>>>(h0all, e_s, e_d, rowptr, colidx, bufA, N);
  k_gat01<<<(TN+63)/64,256,0,stream>>>(bufA, W0T4, b0, W1T, bufB, TN);
  // GAT layer 1
  k_esd<<<gagg,256,0,stream>>>(bufB, as1, ad1, e_s, e_d, TN);
  k_agg<<<dim3((N+3)/4, T),256,0,stream>>>(bufB, e_s, e_d, rowptr, colidx, b1, embs, N);
  // node-mean numerators for temporal attention
  k_colsum<<<256,256,0,stream>>>(embs, sume, N);

  // temporal attention weights, then final GEMM with fused combine
  k_attn<<<1,256,0,stream>>>(sume, Wq, bq, Wk, bk, aw, N);
  k_gemm_fin<<<gmN,512,0,stream>>>(embs, aw, WvT, bv, out, N);
}